// Round 1
// baseline (1780.108 us; speedup 1.0000x reference)
//
#include <hip/hip_runtime.h>
#include <hip/hip_bf16.h>
#include <math.h>

namespace {

constexpr int kH     = 512;
constexpr int kL     = 1024;
constexpr int kB     = 64;
constexpr int kHalf  = 256;
constexpr int kV     = 32000;
constexpr int kTok   = kB * kL;     // 65536

using f32x4 = __attribute__((ext_vector_type(4))) float;
using f16x8 = __attribute__((ext_vector_type(8))) _Float16;

__device__ inline void fsplit(float v, _Float16& h, _Float16& l) {
  h = (_Float16)v;
  l = (_Float16)(v - (float)h);
}

// swizzled index helpers (16B-granule XOR swizzles)
__device__ inline int gmidx(int r, int c) { return r * 64 + (c ^ ((r & 7) << 2)); }  // float arr [64][64]
__device__ inline int six(int j, int c)   { return j * 64 + (c ^ ((j & 7) << 3)); }  // half arr [64][64]

// ---------------- positional weights
__global__ void pos_kernel(const float* __restrict__ pos_emb,
                           const float* __restrict__ pos_w,
                           const float* __restrict__ pos_b,
                           float* __restrict__ wts)
{
  int t = blockIdx.x * blockDim.x + threadIdx.x;
  if (t >= kL) return;
  float z = pos_b[0];
#pragma unroll
  for (int p = 0; p < 16; ++p) z += pos_emb[t * 16 + p] * pos_w[p];
  wts[t] = 1.f / (1.f + expf(-z));
}

// ---------------- transpose + hi/lo fp16 split: W[K][N] fp32 -> Th/Tl[N][K]
__global__ __launch_bounds__(256) void transpose_split(
    const float* __restrict__ W, _Float16* __restrict__ Th,
    _Float16* __restrict__ Tl, int N, int kshift)
{
  const int idx = blockIdx.x * 256 + threadIdx.x;
  const int K = 1 << kshift;
  const int k = idx & (K - 1);
  const int n = idx >> kshift;
  const float w = W[(size_t)k * N + n];
  const _Float16 h = (_Float16)w;
  Th[idx] = h;
  Tl[idx] = (_Float16)(w - (float)h);
}

// ---------------- split-fp16 MFMA GEMM: C[M,N] = A[M,K] @ (Bh+Bl)[N,K]^T
template <int EPI>
__global__ __launch_bounds__(256) void hgemm(
    const int* __restrict__ seq, const float* __restrict__ embed,
    const _Float16* __restrict__ Ah, const _Float16* __restrict__ Al,
    const _Float16* __restrict__ Bh, const _Float16* __restrict__ Bl,
    const float* __restrict__ bias, const float* __restrict__ bias2,
    float* __restrict__ Xout, _Float16* __restrict__ Oh, _Float16* __restrict__ Ol,
    float* __restrict__ ks, float* __restrict__ ke,
    int K, int N, int tok0c)
{
  __shared__ _Float16 lds[4][128][40];   // Ahi, Alo, Bhi, Blo; +8 pad (80B stride)
  const int tid  = threadIdx.x;
  const int lane = tid & 63;
  const int wv   = tid >> 6;
  const int wm   = (wv >> 1) * 64;
  const int wn   = (wv & 1) * 64;
  const int bm0  = blockIdx.y * 128;
  const int bn0  = blockIdx.x * 128;

  f32x4 acc[4][4];
#pragma unroll
  for (int i = 0; i < 4; ++i)
#pragma unroll
    for (int j = 0; j < 4; ++j) acc[i][j] = {0.f, 0.f, 0.f, 0.f};

  const int sr = tid >> 1;            // staging row 0..127
  const int sc = (tid & 1) << 4;      // 0 or 16 (halves)
  const _Float16* gBh = Bh + (size_t)(bn0 + sr) * K + sc;
  const _Float16* gBl = Bl + (size_t)(bn0 + sr) * K + sc;
  const _Float16* gAh = nullptr;
  const _Float16* gAl = nullptr;
  const float*    gAe = nullptr;
  if constexpr (EPI == 0) {
    const int tokrow = seq[tok0c + bm0 + sr];
    gAe = embed + (size_t)tokrow * kH + sc;
  } else {
    gAh = Ah + (size_t)(bm0 + sr) * K + sc;
    gAl = Al + (size_t)(bm0 + sr) * K + sc;
  }

  const int lrow = lane & 15;
  const int lk   = (lane >> 4) * 8;

  for (int k0 = 0; k0 < K; k0 += 32) {
    const uint4 vC0 = *(const uint4*)(gBh + k0);
    const uint4 vC1 = *(const uint4*)(gBh + k0 + 8);
    const uint4 vD0 = *(const uint4*)(gBl + k0);
    const uint4 vD1 = *(const uint4*)(gBl + k0 + 8);
    if constexpr (EPI == 0) {
      const float4 a0 = *(const float4*)(gAe + k0);
      const float4 a1 = *(const float4*)(gAe + k0 + 4);
      const float4 a2 = *(const float4*)(gAe + k0 + 8);
      const float4 a3 = *(const float4*)(gAe + k0 + 12);
      const float vv[16] = {a0.x,a0.y,a0.z,a0.w, a1.x,a1.y,a1.z,a1.w,
                            a2.x,a2.y,a2.z,a2.w, a3.x,a3.y,a3.z,a3.w};
      union { _Float16 h[16]; uint4 u[2]; } ph, pl;
#pragma unroll
      for (int i = 0; i < 16; ++i) fsplit(vv[i], ph.h[i], pl.h[i]);
      __syncthreads();
      *(uint4*)&lds[0][sr][sc]     = ph.u[0];
      *(uint4*)&lds[0][sr][sc + 8] = ph.u[1];
      *(uint4*)&lds[1][sr][sc]     = pl.u[0];
      *(uint4*)&lds[1][sr][sc + 8] = pl.u[1];
    } else {
      const uint4 vA0 = *(const uint4*)(gAh + k0);
      const uint4 vA1 = *(const uint4*)(gAh + k0 + 8);
      const uint4 vB0 = *(const uint4*)(gAl + k0);
      const uint4 vB1 = *(const uint4*)(gAl + k0 + 8);
      __syncthreads();
      *(uint4*)&lds[0][sr][sc]     = vA0;
      *(uint4*)&lds[0][sr][sc + 8] = vA1;
      *(uint4*)&lds[1][sr][sc]     = vB0;
      *(uint4*)&lds[1][sr][sc + 8] = vB1;
    }
    *(uint4*)&lds[2][sr][sc]     = vC0;
    *(uint4*)&lds[2][sr][sc + 8] = vC1;
    *(uint4*)&lds[3][sr][sc]     = vD0;
    *(uint4*)&lds[3][sr][sc + 8] = vD1;
    __syncthreads();

    f16x8 fBh[4], fBl[4];
#pragma unroll
    for (int ni = 0; ni < 4; ++ni) {
      fBh[ni] = *(const f16x8*)&lds[2][wn + ni * 16 + lrow][lk];
      fBl[ni] = *(const f16x8*)&lds[3][wn + ni * 16 + lrow][lk];
    }
#pragma unroll
    for (int mi = 0; mi < 4; ++mi) {
      const f16x8 ah = *(const f16x8*)&lds[0][wm + mi * 16 + lrow][lk];
      const f16x8 al = *(const f16x8*)&lds[1][wm + mi * 16 + lrow][lk];
#pragma unroll
      for (int ni = 0; ni < 4; ++ni) {
        acc[mi][ni] = __builtin_amdgcn_mfma_f32_16x16x32_f16(ah, fBh[ni], acc[mi][ni], 0, 0, 0);
        acc[mi][ni] = __builtin_amdgcn_mfma_f32_16x16x32_f16(ah, fBl[ni], acc[mi][ni], 0, 0, 0);
        acc[mi][ni] = __builtin_amdgcn_mfma_f32_16x16x32_f16(al, fBh[ni], acc[mi][ni], 0, 0, 0);
      }
    }
  }

  const int erow0 = (lane >> 4) * 4;
  if constexpr (EPI == 0) {
#pragma unroll
    for (int mi = 0; mi < 4; ++mi)
#pragma unroll
      for (int ni = 0; ni < 4; ++ni) {
        const int gn = bn0 + wn + ni * 16 + (lane & 15);
        const float bv = bias[gn];
#pragma unroll
        for (int r = 0; r < 4; ++r) {
          const int gm = bm0 + wm + mi * 16 + erow0 + r;
          float v = fmaxf(acc[mi][ni][r] + bv, 0.f);
          const _Float16 h = (_Float16)v;
          Oh[(size_t)gm * N + gn] = h;
          Ol[(size_t)gm * N + gn] = (_Float16)(v - (float)h);
        }
      }
  } else if constexpr (EPI == 1) {
#pragma unroll
    for (int mi = 0; mi < 4; ++mi)
#pragma unroll
      for (int r = 0; r < 4; ++r) {
        const int gm = bm0 + wm + mi * 16 + erow0 + r;
        const int tok = seq[tok0c + gm];
        const float* er = embed + (size_t)tok * kH;
#pragma unroll
        for (int ni = 0; ni < 4; ++ni) {
          const int gn = bn0 + wn + ni * 16 + (lane & 15);
          Xout[(size_t)gm * N + gn] = acc[mi][ni][r] + bias[gn] + er[gn];
        }
      }
  } else {
    // EPI==2: write K as fp16 hi/lo pairs. ks=(Kh_s), ke=(Kh_e), Oh=(Kl_s), Ol=(Kl_e)
    _Float16* kh_s = (_Float16*)ks;
    _Float16* kh_e = (_Float16*)ke;
#pragma unroll
    for (int mi = 0; mi < 4; ++mi)
#pragma unroll
      for (int ni = 0; ni < 4; ++ni) {
        const int gn = bn0 + wn + ni * 16 + (lane & 15);
        const float bv = (gn < 256) ? bias[gn] : bias2[gn - 256];
        _Float16* Dh = (gn < 256) ? kh_s : kh_e;
        _Float16* Dl = (gn < 256) ? Oh : Ol;
        const int col = gn & 255;
#pragma unroll
        for (int r = 0; r < 4; ++r) {
          const int gm = bm0 + wm + mi * 16 + erow0 + r;
          const float v = acc[mi][ni][r] + bv;
          _Float16 h, l;
          fsplit(v, h, l);
          Dh[(size_t)(tok0c + gm) * 256 + col] = h;
          Dl[(size_t)(tok0c + gm) * 256 + col] = l;
        }
      }
  }
}

// ---------------- LayerNorm: x fp32 -> hi/lo fp16
__global__ __launch_bounds__(256) void ln_split(
    const float* __restrict__ x, const float* __restrict__ g,
    const float* __restrict__ bta, _Float16* __restrict__ hh,
    _Float16* __restrict__ hl)
{
  const int wid  = threadIdx.x >> 6;
  const int lane = threadIdx.x & 63;
  const int ltok = blockIdx.x * 4 + wid;
  const float* xp = x + (size_t)ltok * kH;
  const float4 v0 = *(const float4*)(xp + lane * 8);
  const float4 v1 = *(const float4*)(xp + lane * 8 + 4);
  float s  = v0.x + v0.y + v0.z + v0.w + v1.x + v1.y + v1.z + v1.w;
  float ss = v0.x * v0.x + v0.y * v0.y + v0.z * v0.z + v0.w * v0.w +
             v1.x * v1.x + v1.y * v1.y + v1.z * v1.z + v1.w * v1.w;
#pragma unroll
  for (int m = 1; m < 64; m <<= 1) { s += __shfl_xor(s, m); ss += __shfl_xor(ss, m); }
  const float mu  = s * (1.f / kH);
  const float var = ss * (1.f / kH) - mu * mu;
  const float rs  = 1.f / sqrtf(var + 1e-5f);
  const float4 g0 = *(const float4*)(g + lane * 8);
  const float4 g1 = *(const float4*)(g + lane * 8 + 4);
  const float4 b0 = *(const float4*)(bta + lane * 8);
  const float4 b1 = *(const float4*)(bta + lane * 8 + 4);
  const float vv[8] = {v0.x, v0.y, v0.z, v0.w, v1.x, v1.y, v1.z, v1.w};
  const float gg[8] = {g0.x, g0.y, g0.z, g0.w, g1.x, g1.y, g1.z, g1.w};
  const float bb[8] = {b0.x, b0.y, b0.z, b0.w, b1.x, b1.y, b1.z, b1.w};
  union { _Float16 h[8]; uint4 u; } ph, pl;
#pragma unroll
  for (int i = 0; i < 8; ++i) {
    const float o = (vv[i] - mu) * rs * gg[i] + bb[i];
    fsplit(o, ph.h[i], pl.h[i]);
  }
  *(uint4*)(hh + (size_t)ltok * kH + lane * 8) = ph.u;
  *(uint4*)(hl + (size_t)ltok * kH + lane * 8) = pl.u;
}

// ---------------- chunked WY delta-rule scan (v5).
// v5: K never staged through LDS for the Q/G phase (fp16 hi/lo read straight
// from global Kh/Kl, L1/L2-resident); S-row ownership redistributed
// (wave wv owns rows p*64+wv*16+.. of every panel) so the S-update consumes
// K^T panel-by-panel from a small double-buffered conflict-free subtiled LDS
// tile; S^T/U/G tiles XOR-swizzled. Kills the 1.5e8 LDS bank-conflict cycles
// and all staging fsplit VALU of v4.
union RegA {
  struct { _Float16 h[2][4096], l[2][4096]; } s;   // S^T panels, dbuf (32768 B)
  struct { float m[64][66]; } r;                   // Rr residual (16896 B)
  struct { _Float16 h[4608], l[4608]; } kt[2];     // K^T panel subtiles, dbuf (36864 B)
};

__global__ __launch_bounds__(256, 2) void scan_chunked(
    const _Float16* __restrict__ khs, const _Float16* __restrict__ kls,
    const _Float16* __restrict__ khe, const _Float16* __restrict__ kle,
    const float* __restrict__ wts, float* __restrict__ c_out)
{
  __shared__ RegA A;
  __shared__ union { float Gm[64 * 64]; float cred[4][64]; } Bu;
  __shared__ _Float16 Uh[64 * 64], Ul[64 * 64];
  __shared__ float aS[64], wS[64];

  const int tid  = threadIdx.x;
  const int lane = tid & 63;
  const int wv   = tid >> 6;
  const int l15  = lane & 15;
  const int quad = lane >> 4;
  const int wg   = blockIdx.x;
  const int b    = wg >> 3;
  const int mat  = (wg >> 2) & 1;
  const int q    = wg & 3;
  const int j0   = q * 64;
  const _Float16* Kh = (mat ? khe : khs) + (size_t)b * (1024 * 256);
  const _Float16* Kl = (mat ? kle : kls) + (size_t)b * (1024 * 256);

  // S[p*4+nt]: rows p*64 + wv*16 + quad*4 + r ; cols nt*16 + l15 (WG-local j)
  f32x4 S[16];
#pragma unroll
  for (int i = 0; i < 16; ++i) S[i] = {0.f, 0.f, 0.f, 0.f};

  for (int ck = 0; ck < 16; ++ck) {
    const int tok0 = ck * 64;

    __syncthreads();   // B0: prev chunk's kt/Uh readers done (RegA rewrite), aS readers done

    // ---- ssq / aS / wS (global reads)
    {
      const int stk = tid >> 2;
      const int dg  = (tid & 3) * 16;
      const _Float16* ph = Kh + (size_t)(tok0 + stk) * 256 + dg;
      const _Float16* pl = Kl + (size_t)(tok0 + stk) * 256 + dg;
      float ssq = 0.f;
#pragma unroll
      for (int p = 0; p < 4; ++p) {
        const f16x8 h0 = *(const f16x8*)(ph + p * 64);
        const f16x8 h1 = *(const f16x8*)(ph + p * 64 + 8);
        const f16x8 l0 = *(const f16x8*)(pl + p * 64);
        const f16x8 l1 = *(const f16x8*)(pl + p * 64 + 8);
#pragma unroll
        for (int i = 0; i < 8; ++i) {
          const float va = (float)h0[i] + (float)l0[i];
          const float vb = (float)h1[i] + (float)l1[i];
          ssq = fmaf(va, va, ssq);
          ssq = fmaf(vb, vb, ssq);
        }
      }
      ssq += __shfl_xor(ssq, 1);
      ssq += __shfl_xor(ssq, 2);
      if ((tid & 3) == 0) {
        const float w = mat ? wts[tok0 + stk] : 1.f;
        wS[stk] = w;
        aS[stk] = w / (ssq + 1e-6f);
      }
    }

    // ---- stage S^T panel 0 into buf 0 (every wave writes its own rows)
#pragma unroll
    for (int nt = 0; nt < 4; ++nt) {
      const f32x4 v = S[0 * 4 + nt];
      union { _Float16 h[4]; uint2 u; } qh, ql;
#pragma unroll
      for (int r = 0; r < 4; ++r) fsplit(v[r], qh.h[r], ql.h[r]);
      const int ix = six(nt * 16 + l15, wv * 16 + quad * 4);
      *(uint2*)&A.s.h[0][ix] = qh.u;
      *(uint2*)&A.s.l[0][ix] = ql.u;
    }
    __syncthreads();   // B1

    f32x4 Qa[4], Ga[4];
#pragma unroll
    for (int i = 0; i < 4; ++i) { Qa[i] = {0.f,0.f,0.f,0.f}; Ga[i] = {0.f,0.f,0.f,0.f}; }

    // global K fragment base pointers (fp16 hi/lo, no LDS staging)
    const _Float16* arow_h = Kh + (size_t)(tok0 + wv * 16 + l15) * 256 + quad * 8;
    const _Float16* arow_l = Kl + (size_t)(tok0 + wv * 16 + l15) * 256 + quad * 8;
    const _Float16* brow_h[4];
    const _Float16* brow_l[4];
#pragma unroll
    for (int nt = 0; nt < 4; ++nt) {
      brow_h[nt] = Kh + (size_t)(tok0 + nt * 16 + l15) * 256 + quad * 8;
      brow_l[nt] = Kl + (size_t)(tok0 + nt * 16 + l15) * 256 + quad * 8;
    }

#pragma unroll
    for (int p = 0; p < 4; ++p) {
      const int cur = p & 1;
      if (p < 3) {   // stage S^T panel p+1 into the other buffer
#pragma unroll
        for (int nt = 0; nt < 4; ++nt) {
          const f32x4 v = S[(p + 1) * 4 + nt];
          union { _Float16 h[4]; uint2 u; } qh, ql;
#pragma unroll
          for (int r = 0; r < 4; ++r) fsplit(v[r], qh.h[r], ql.h[r]);
          const int ix = six(nt * 16 + l15, wv * 16 + quad * 4);
          *(uint2*)&A.s.h[1 - cur][ix] = qh.u;
          *(uint2*)&A.s.l[1 - cur][ix] = ql.u;
        }
      }
#pragma unroll
      for (int kit = 0; kit < 2; ++kit) {
        const int ko = kit * 32 + quad * 8;
        const f16x8 ah = *(const f16x8*)(arow_h + p * 64 + kit * 32);
        const f16x8 al = *(const f16x8*)(arow_l + p * 64 + kit * 32);
#pragma unroll
        for (int nt = 0; nt < 4; ++nt) {
          const int ix = six(nt * 16 + l15, ko);
          const f16x8 bh = *(const f16x8*)&A.s.h[cur][ix];
          const f16x8 bl = *(const f16x8*)&A.s.l[cur][ix];
          Qa[nt] = __builtin_amdgcn_mfma_f32_16x16x32_f16(ah, bh, Qa[nt], 0, 0, 0);
          Qa[nt] = __builtin_amdgcn_mfma_f32_16x16x32_f16(ah, bl, Qa[nt], 0, 0, 0);
          Qa[nt] = __builtin_amdgcn_mfma_f32_16x16x32_f16(al, bh, Qa[nt], 0, 0, 0);
        }
#pragma unroll
        for (int nt = 0; nt < 4; ++nt) {
          const f16x8 gb = *(const f16x8*)(brow_h[nt] + p * 64 + kit * 32);
          const f16x8 gl = *(const f16x8*)(brow_l[nt] + p * 64 + kit * 32);
          Ga[nt] = __builtin_amdgcn_mfma_f32_16x16x32_f16(ah, gb, Ga[nt], 0, 0, 0);
          Ga[nt] = __builtin_amdgcn_mfma_f32_16x16x32_f16(ah, gl, Ga[nt], 0, 0, 0);
          Ga[nt] = __builtin_amdgcn_mfma_f32_16x16x32_f16(al, gb, Ga[nt], 0, 0, 0);
        }
      }
      __syncthreads();   // Bp: buf[1-cur] staged visible; buf[cur] reads done
    }

    // ---- writeback: Q -> Rr[t][j] (aliases S^T region), G -> Gm (swizzled)
#pragma unroll
    for (int nt = 0; nt < 4; ++nt) {
#pragma unroll
      for (int r = 0; r < 4; ++r)
        A.r.m[wv * 16 + quad * 4 + r][nt * 16 + l15] = Qa[nt][r];
      *(float4*)&Bu.Gm[gmidx(nt * 16 + l15, wv * 16 + quad * 4)] = *(const float4*)&Ga[nt];
    }
    __syncthreads();   // B4: Rr/Gm/aS/wS visible

    // ---- barrier-free triangular solve: thread j owns col j
    if (tid < 64) {
      const int j = tid;
      const int keyU = (j & 7) << 3;
      for (int blk = 0; blk < 8; ++blk) {
        const int t0 = blk * 8;
        float rl[8], kv[8], ub[8];
#pragma unroll
        for (int i = 0; i < 8; ++i) rl[i] = A.r.m[t0 + i][j];
#pragma unroll
        for (int i = 0; i < 8; ++i) {
          const size_t go = (size_t)(tok0 + t0 + i) * 256 + j0 + j;
          kv[i] = (float)Kh[go] + (float)Kl[go];
        }
#pragma unroll
        for (int i = 0; i < 8; ++i) {
          const int t = t0 + i;
          float u = wS[t] * kv[i] - aS[t] * rl[i];
          if (ck == 15 && t == 63) u = 0.f;   // token L-1 is the query only
          ub[i] = u;
#pragma unroll
          for (int i2 = i + 1; i2 < 8; ++i2)
            rl[i2] += Bu.Gm[gmidx(t0 + i2, t)] * u;
        }
        union { _Float16 h[8]; uint4 u4; } uh, ul;
#pragma unroll
        for (int i = 0; i < 8; ++i) fsplit(ub[i], uh.h[i], ul.h[i]);
        *(uint4*)&Uh[j * 64 + (t0 ^ keyU)] = uh.u4;
        *(uint4*)&Ul[j * 64 + (t0 ^ keyU)] = ul.u4;
        for (int t2 = t0 + 8; t2 < 64; ++t2) {
          const float4 g0 = *(const float4*)&Bu.Gm[gmidx(t2, t0)];
          const float4 g1 = *(const float4*)&Bu.Gm[gmidx(t2, t0 + 4)];
          A.r.m[t2][j] += g0.x*ub[0] + g0.y*ub[1] + g0.z*ub[2] + g0.w*ub[3]
                        + g1.x*ub[4] + g1.y*ub[5] + g1.z*ub[6] + g1.w*ub[7];
        }
      }
    }

    // pre-issue K^T panel-0 staging loads (land while waiting on the solve)
    const _Float16* ktsrc_h = Kh + (size_t)(tok0 + lane) * 256 + wv * 16;
    const _Float16* ktsrc_l = Kl + (size_t)(tok0 + lane) * 256 + wv * 16;
    const f16x8 s0h = *(const f16x8*)(ktsrc_h);
    const f16x8 s1h = *(const f16x8*)(ktsrc_h + 8);
    const f16x8 s0l = *(const f16x8*)(ktsrc_l);
    const f16x8 s1l = *(const f16x8*)(ktsrc_l + 8);
    __syncthreads();   // B5: Uh/Ul visible; Rr/Gm dead
    const int wix = (wv * 16 + (lane >> 2)) * 72 + (lane & 3) * 16;
    *(f16x8*)&A.kt[0].h[wix]     = s0h;
    *(f16x8*)&A.kt[0].h[wix + 8] = s1h;
    *(f16x8*)&A.kt[0].l[wix]     = s0l;
    *(f16x8*)&A.kt[0].l[wix + 8] = s1l;
    __syncthreads();   // Bu0

    // ---- S += K^T U, panel by panel (conflict-free subtiled LDS transpose)
#pragma unroll
    for (int p = 0; p < 4; ++p) {
      const int cur = p & 1;
      f16x8 n0h, n1h, n0l, n1l;
      if (p < 3) {   // issue next-panel loads early (T14 split)
        n0h = *(const f16x8*)(ktsrc_h + (p + 1) * 64);
        n1h = *(const f16x8*)(ktsrc_h + (p + 1) * 64 + 8);
        n0l = *(const f16x8*)(ktsrc_l + (p + 1) * 64);
        n1l = *(const f16x8*)(ktsrc_l + (p + 1) * 64 + 8);
      }
      union { _Float16 e[8]; f16x8 v; } uah[2], ual[2];
#pragma unroll
      for (int kit = 0; kit < 2; ++kit) {
        const int base = (wv * 16 + 8 * kit + 2 * quad) * 72 + l15;
#pragma unroll
        for (int jj = 0; jj < 8; ++jj) {
          const int off = (jj >> 2) * 72 + (jj & 3) * 16;
          uah[kit].e[jj] = A.kt[cur].h[base + off];
          ual[kit].e[jj] = A.kt[cur].l[base + off];
        }
      }
#pragma unroll
      for (int kit = 0; kit < 2; ++kit) {
        const int ko = kit * 32 + quad * 8;
#pragma unroll
        for (int nt = 0; nt < 4; ++nt) {
          const int ix = six(nt * 16 + l15, ko);
          const f16x8 bh = *(const f16x8*)&Uh[ix];
          const f16x8 bl = *(const f16x8*)&Ul[ix];
          f32x4 s = S[p * 4 + nt];
          s = __builtin_amdgcn_mfma_f32_16x16x32_f16(uah[kit].v, bh, s, 0, 0, 0);
          s = __builtin_amdgcn_mfma_f32_16x16x32_f16(uah[kit].v, bl, s, 0, 0, 0);
          s = __builtin_amdgcn_mfma_f32_16x16x32_f16(ual[kit].v, bh, s, 0, 0, 0);
          S[p * 4 + nt] = s;
        }
      }
      if (p < 3) {   // write next panel (buf safe: its readers done at Bp-1)
        *(f16x8*)&A.kt[1 - cur].h[wix]     = n0h;
        *(f16x8*)&A.kt[1 - cur].h[wix + 8] = n1h;
        *(f16x8*)&A.kt[1 - cur].l[wix]     = n0l;
        *(f16x8*)&A.kt[1 - cur].l[wix + 8] = n1l;
        __syncthreads();   // Bup
      }
    }
    // p=3 reads finish before next chunk's B0 rewrites RegA
  }

  // ---- readout: c[col] = sum_rows S[row][col] * k_last[row]
  float part[4] = {0.f, 0.f, 0.f, 0.f};
  const size_t lastoff = (size_t)(kL - 1) * 256;
#pragma unroll
  for (int p = 0; p < 4; ++p) {
    float klr[4];
#pragma unroll
    for (int r = 0; r < 4; ++r) {
      const int row = p * 64 + wv * 16 + quad * 4 + r;
      klr[r] = (float)Kh[lastoff + row] + (float)Kl[lastoff + row];
    }
#pragma unroll
    for (int nt = 0; nt < 4; ++nt)
#pragma unroll
      for (int r = 0; r < 4; ++r) part[nt] += S[p * 4 + nt][r] * klr[r];
  }
#pragma unroll
  for (int nt = 0; nt < 4; ++nt) {
    part[nt] += __shfl_xor(part[nt], 16);
    part[nt] += __shfl_xor(part[nt], 32);
  }
  __syncthreads();   // all prior LDS reads done before cred aliases Gm
  if (lane < 16) {
#pragma unroll
    for (int nt = 0; nt < 4; ++nt) Bu.cred[wv][nt * 16 + l15] = part[nt];
  }
  __syncthreads();
  if (tid < 64) {
    const float c = Bu.cred[0][tid] + Bu.cred[1][tid] + Bu.cred[2][tid] + Bu.cred[3][tid];
    c_out[(size_t)b * 512 + mat * 256 + j0 + tid] = c;
  }
}

// ---------------- output GEMM: (64 x 512) @ (512 x 32000) + out_b -> fp32
__global__ __launch_bounds__(256) void out_gemm(
    const float* __restrict__ A, const float* __restrict__ Bm,
    const float* __restrict__ bias, float* __restrict__ C)
{
  __shared__ float As[16][64];
  __shared__ float Bs[16][128];
  const int tid = threadIdx.x;
  const int bn0 = blockIdx.x * 128;
  const int tm = tid >> 4, tn = tid & 15;
  float acc[4][8];
#pragma unroll
  for (int i = 0; i < 4; ++i)
#pragma unroll
    for (int j = 0; j < 8; ++j) acc[i][j] = 0.f;

  const int am  = tid & 63;
  const int ak  = (tid >> 6) * 4;
  const int bkr = tid >> 5;
  const int bcg = (tid & 31) * 4;

  for (int k0 = 0; k0 < kH; k0 += 16) {
    const float4 a0 = *(const float4*)(A + (size_t)am * kH + k0 + ak);
    const float4 b0 = *(const float4*)(Bm + (size_t)(k0 + bkr) * kV + bn0 + bcg);
    const float4 b1 = *(const float4*)(Bm + (size_t)(k0 + bkr + 8) * kV + bn0 + bcg);
    __syncthreads();
    As[ak + 0][am] = a0.x; As[ak + 1][am] = a0.y;
    As[ak + 2][am] = a0.z; As[ak + 3][am] = a0.w;
    *(float4*)&Bs[bkr][bcg]     = b0;
    *(float4*)&Bs[bkr + 8][bcg] = b1;
    __syncthreads();
#pragma unroll
    for (int kk = 0; kk < 16; ++kk) {
      const float4 aA = *(const float4*)&As[kk][tm * 4];
      const float4 bA = *(const float4*)&Bs[kk][tn * 4];
      const float4 bB = *(const float4*)&Bs[kk][64 + tn * 4];
      const float av[4] = {aA.x, aA.y, aA.z, aA.w};
      const float bv[8] = {bA.x, bA.y, bA.z, bA.w, bB.x, bB.y, bB.z, bB.w};
#pragma unroll
      for (int i = 0; i < 4; ++i)
#pragma unroll
        for (int j = 0; j < 8; ++j) acc[i][j] += av[i] * bv[j];
    }
  }

#pragma unroll
  for (int i = 0; i < 4; ++i) {
    const int row = tm * 4 + i;
#pragma unroll
    for (int hh = 0; hh < 2; ++hh) {
      const int n0 = bn0 + tn * 4 + hh * 64;
      const float4 bb = *(const float4*)(bias + n0);
      float4 o;
      o.x = acc[i][hh * 4 + 0] + bb.x;
      o.y = acc[i][hh * 4 + 1] + bb.y;
      o.z = acc[i][hh * 4 + 2] + bb.z;
      o.w = acc[i][hh * 4 + 3] + bb.w;
      *(float4*)(C + (size_t)row * kV + n0) = o;
    }
  }
}

}  // namespace

extern "C" void kernel_launch(void* const* d_in, const int* in_sizes, int n_in,
                              void* d_out, int out_size, void* d_ws, size_t ws_size,
                              hipStream_t stream)
{
  const int*   seq     = (const int*)  d_in[0];
  const float* embed   = (const float*)d_in[1];
  const float* w1      = (const float*)d_in[2];
  const float* b1      = (const float*)d_in[3];
  const float* w2      = (const float*)d_in[4];
  const float* b2      = (const float*)d_in[5];
  const float* ln_g    = (const float*)d_in[6];
  const float* ln_b    = (const float*)d_in[7];
  const float* sem_w   = (const float*)d_in[8];
  const float* sem_b   = (const float*)d_in[9];
  const float* epi_w   = (const float*)d_in[10];
  const float* epi_b   = (const float*)d_in[11];
  const float* out_w   = (const float*)d_in[12];
  const float* out_b   = (const float*)d_in[13];
  const float* pos_emb = (const float*)d_in[14];
  const float* pos_w   = (const float*)d_in[15];
  const float* pos_b   = (const float*)d_in[16];
  float* out = (float*)d_out;

  // chunk size: 16384 needs 240.3 MB of ws; fall back to 8192 if tight.
  // ws_size is constant per process -> deterministic, graph-capture-safe.
  const int chunkN = (ws_size >= (size_t)240500000) ? 16384 : 8192;
  const int nch    = kTok / chunkN;

  char* p = (char*)d_ws;
  _Float16* w1th = (_Float16*)p; p += (size_t)1024 * 512 * 2;
  _Float16* w1tl = (_Float16*)p; p += (size_t)1024 * 512 * 2;
  _Float16* w2th = (_Float16*)p; p += (size_t)512 * 1024 * 2;
  _Float16* w2tl = (_Float16*)p; p += (size_t)512 * 1024 * 2;
  _Float16* wseh = (_Float16*)p; p += (size_t)512 * 512 * 2;
  _Float16* wsel = (_Float16*)p; p += (size_t)512 * 512 * 2;
  _Float16* t1h  = (_Float16*)p; p += (size_t)chunkN * 1024 * 2;
  _Float16* t1l  = (_Float16*)p; p += (size_t)chunkN * 1024 * 2;
  float*    x    = (float*)p;    p += (size_t)chunkN * kH * 4;
  _Float16* khs  = (_Float16*)p; p += (size_t)kTok * kHalf * 2;   // K hi/lo fp16 (same
  _Float16* kls  = (_Float16*)p; p += (size_t)kTok * kHalf * 2;   //  128MB footprint as
  _Float16* khe  = (_Float16*)p; p += (size_t)kTok * kHalf * 2;   //  the old fp32 ks/ke)
  _Float16* kle  = (_Float16*)p; p += (size_t)kTok * kHalf * 2;
  float*    wts  = (float*)p;    p += (size_t)kL * 4;
  float*    cout_= (float*)p;    p += (size_t)kB * 512 * 4;
  _Float16* hh   = t1h;          // alias: t1 dead once x is written
  _Float16* hl   = t1l;

  pos_kernel<<<dim3((kL + 255) / 256), dim3(256), 0, stream>>>(pos_emb, pos_w, pos_b, wts);
  transpose_split<<<dim3(1024 * 512 / 256), dim3(256), 0, stream>>>(w1, w1th, w1tl, 1024, 9);
  transpose_split<<<dim3(512 * 1024 / 256), dim3(256), 0, stream>>>(w2, w2th, w2tl, 512, 10);
  transpose_split<<<dim3(256 * 512 / 256), dim3(256), 0, stream>>>(sem_w, wseh, wsel, 256, 9);
  transpose_split<<<dim3(256 * 512 / 256), dim3(256), 0, stream>>>(
      epi_w, wseh + (size_t)256 * 512, wsel + (size_t)256 * 512, 256, 9);

  for (int c = 0; c < nch; ++c) {
    const int tok0 = c * chunkN;
    hgemm<0><<<dim3(1024 / 128, chunkN / 128), dim3(256), 0, stream>>>(
        seq, embed, nullptr, nullptr, w1th, w1tl, b1, nullptr,
        nullptr, t1h, t1l, nullptr, nullptr, 512, 1024, tok0);
    hgemm<1><<<dim3(512 / 128, chunkN / 128), dim3(256), 0, stream>>>(
        seq, embed, t1h, t1l, w2th, w2tl, b2, nullptr,
        x, nullptr, nullptr, nullptr, nullptr, 1024, 512, tok0);
    ln_split<<<dim3(chunkN / 4), dim3(256), 0, stream>>>(x, ln_g, ln_b, hh, hl);
    hgemm<2><<<dim3(512 / 128, chunkN / 128), dim3(256), 0, stream>>>(
        seq, embed, hh, hl, wseh, wsel, sem_b, epi_b,
        nullptr, kls, kle, (float*)khs, (float*)khe,
        512, 512, tok0);
  }

  scan_chunked<<<dim3(512), dim3(256), 0, stream>>>(khs, kls, khe, kle, wts, cout_);
  out_gemm<<<dim3(kV / 128), dim3(256), 0, stream>>>(cout_, out_w, out_b, out);

  (void)in_sizes; (void)n_in; (void)out_size;
}

// Round 2
// 1625.468 us; speedup vs baseline: 1.0951x; 1.0951x over previous
//
#include <hip/hip_runtime.h>
#include <hip/hip_bf16.h>
#include <math.h>

namespace {

constexpr int kH     = 512;
constexpr int kL     = 1024;
constexpr int kB     = 64;
constexpr int kHalf  = 256;
constexpr int kV     = 32000;
constexpr int kTok   = kB * kL;     // 65536

using f32x4 = __attribute__((ext_vector_type(4))) float;
using f16x8 = __attribute__((ext_vector_type(8))) _Float16;

__device__ inline void fsplit(float v, _Float16& h, _Float16& l) {
  h = (_Float16)v;
  l = (_Float16)(v - (float)h);
}

// swizzled index helpers (16B-granule XOR swizzles)
__device__ inline int gmidx(int r, int c) { return r * 64 + (c ^ ((r & 7) << 2)); }  // float arr [64][64]
__device__ inline int six(int j, int c)   { return j * 64 + (c ^ ((j & 7) << 3)); }  // half arr [64][64]

// ---------------- positional weights
__global__ void pos_kernel(const float* __restrict__ pos_emb,
                           const float* __restrict__ pos_w,
                           const float* __restrict__ pos_b,
                           float* __restrict__ wts)
{
  int t = blockIdx.x * blockDim.x + threadIdx.x;
  if (t >= kL) return;
  float z = pos_b[0];
#pragma unroll
  for (int p = 0; p < 16; ++p) z += pos_emb[t * 16 + p] * pos_w[p];
  wts[t] = 1.f / (1.f + expf(-z));
}

// ---------------- transpose + hi/lo fp16 split: W[K][N] fp32 -> Th/Tl[N][K]
__global__ __launch_bounds__(256) void transpose_split(
    const float* __restrict__ W, _Float16* __restrict__ Th,
    _Float16* __restrict__ Tl, int N, int kshift)
{
  const int idx = blockIdx.x * 256 + threadIdx.x;
  const int K = 1 << kshift;
  const int k = idx & (K - 1);
  const int n = idx >> kshift;
  const float w = W[(size_t)k * N + n];
  const _Float16 h = (_Float16)w;
  Th[idx] = h;
  Tl[idx] = (_Float16)(w - (float)h);
}

// ---------------- split-fp16 MFMA GEMM: C[M,N] = A[M,K] @ (Bh+Bl)[N,K]^T
template <int EPI>
__global__ __launch_bounds__(256) void hgemm(
    const int* __restrict__ seq, const float* __restrict__ embed,
    const _Float16* __restrict__ Ah, const _Float16* __restrict__ Al,
    const _Float16* __restrict__ Bh, const _Float16* __restrict__ Bl,
    const float* __restrict__ bias, const float* __restrict__ bias2,
    float* __restrict__ Xout, _Float16* __restrict__ Oh, _Float16* __restrict__ Ol,
    float* __restrict__ ks, float* __restrict__ ke,
    int K, int N, int tok0c)
{
  __shared__ _Float16 lds[4][128][40];   // Ahi, Alo, Bhi, Blo; +8 pad (80B stride)
  const int tid  = threadIdx.x;
  const int lane = tid & 63;
  const int wv   = tid >> 6;
  const int wm   = (wv >> 1) * 64;
  const int wn   = (wv & 1) * 64;
  const int bm0  = blockIdx.y * 128;
  const int bn0  = blockIdx.x * 128;

  f32x4 acc[4][4];
#pragma unroll
  for (int i = 0; i < 4; ++i)
#pragma unroll
    for (int j = 0; j < 4; ++j) acc[i][j] = {0.f, 0.f, 0.f, 0.f};

  const int sr = tid >> 1;            // staging row 0..127
  const int sc = (tid & 1) << 4;      // 0 or 16 (halves)
  const _Float16* gBh = Bh + (size_t)(bn0 + sr) * K + sc;
  const _Float16* gBl = Bl + (size_t)(bn0 + sr) * K + sc;
  const _Float16* gAh = nullptr;
  const _Float16* gAl = nullptr;
  const float*    gAe = nullptr;
  if constexpr (EPI == 0) {
    const int tokrow = seq[tok0c + bm0 + sr];
    gAe = embed + (size_t)tokrow * kH + sc;
  } else {
    gAh = Ah + (size_t)(bm0 + sr) * K + sc;
    gAl = Al + (size_t)(bm0 + sr) * K + sc;
  }

  const int lrow = lane & 15;
  const int lk   = (lane >> 4) * 8;

  for (int k0 = 0; k0 < K; k0 += 32) {
    const uint4 vC0 = *(const uint4*)(gBh + k0);
    const uint4 vC1 = *(const uint4*)(gBh + k0 + 8);
    const uint4 vD0 = *(const uint4*)(gBl + k0);
    const uint4 vD1 = *(const uint4*)(gBl + k0 + 8);
    if constexpr (EPI == 0) {
      const float4 a0 = *(const float4*)(gAe + k0);
      const float4 a1 = *(const float4*)(gAe + k0 + 4);
      const float4 a2 = *(const float4*)(gAe + k0 + 8);
      const float4 a3 = *(const float4*)(gAe + k0 + 12);
      const float vv[16] = {a0.x,a0.y,a0.z,a0.w, a1.x,a1.y,a1.z,a1.w,
                            a2.x,a2.y,a2.z,a2.w, a3.x,a3.y,a3.z,a3.w};
      union { _Float16 h[16]; uint4 u[2]; } ph, pl;
#pragma unroll
      for (int i = 0; i < 16; ++i) fsplit(vv[i], ph.h[i], pl.h[i]);
      __syncthreads();
      *(uint4*)&lds[0][sr][sc]     = ph.u[0];
      *(uint4*)&lds[0][sr][sc + 8] = ph.u[1];
      *(uint4*)&lds[1][sr][sc]     = pl.u[0];
      *(uint4*)&lds[1][sr][sc + 8] = pl.u[1];
    } else {
      const uint4 vA0 = *(const uint4*)(gAh + k0);
      const uint4 vA1 = *(const uint4*)(gAh + k0 + 8);
      const uint4 vB0 = *(const uint4*)(gAl + k0);
      const uint4 vB1 = *(const uint4*)(gAl + k0 + 8);
      __syncthreads();
      *(uint4*)&lds[0][sr][sc]     = vA0;
      *(uint4*)&lds[0][sr][sc + 8] = vA1;
      *(uint4*)&lds[1][sr][sc]     = vB0;
      *(uint4*)&lds[1][sr][sc + 8] = vB1;
    }
    *(uint4*)&lds[2][sr][sc]     = vC0;
    *(uint4*)&lds[2][sr][sc + 8] = vC1;
    *(uint4*)&lds[3][sr][sc]     = vD0;
    *(uint4*)&lds[3][sr][sc + 8] = vD1;
    __syncthreads();

    f16x8 fBh[4], fBl[4];
#pragma unroll
    for (int ni = 0; ni < 4; ++ni) {
      fBh[ni] = *(const f16x8*)&lds[2][wn + ni * 16 + lrow][lk];
      fBl[ni] = *(const f16x8*)&lds[3][wn + ni * 16 + lrow][lk];
    }
#pragma unroll
    for (int mi = 0; mi < 4; ++mi) {
      const f16x8 ah = *(const f16x8*)&lds[0][wm + mi * 16 + lrow][lk];
      const f16x8 al = *(const f16x8*)&lds[1][wm + mi * 16 + lrow][lk];
#pragma unroll
      for (int ni = 0; ni < 4; ++ni) {
        acc[mi][ni] = __builtin_amdgcn_mfma_f32_16x16x32_f16(ah, fBh[ni], acc[mi][ni], 0, 0, 0);
        acc[mi][ni] = __builtin_amdgcn_mfma_f32_16x16x32_f16(ah, fBl[ni], acc[mi][ni], 0, 0, 0);
        acc[mi][ni] = __builtin_amdgcn_mfma_f32_16x16x32_f16(al, fBh[ni], acc[mi][ni], 0, 0, 0);
      }
    }
  }

  const int erow0 = (lane >> 4) * 4;
  if constexpr (EPI == 0) {
#pragma unroll
    for (int mi = 0; mi < 4; ++mi)
#pragma unroll
      for (int ni = 0; ni < 4; ++ni) {
        const int gn = bn0 + wn + ni * 16 + (lane & 15);
        const float bv = bias[gn];
#pragma unroll
        for (int r = 0; r < 4; ++r) {
          const int gm = bm0 + wm + mi * 16 + erow0 + r;
          float v = fmaxf(acc[mi][ni][r] + bv, 0.f);
          const _Float16 h = (_Float16)v;
          Oh[(size_t)gm * N + gn] = h;
          Ol[(size_t)gm * N + gn] = (_Float16)(v - (float)h);
        }
      }
  } else if constexpr (EPI == 1) {
#pragma unroll
    for (int mi = 0; mi < 4; ++mi)
#pragma unroll
      for (int r = 0; r < 4; ++r) {
        const int gm = bm0 + wm + mi * 16 + erow0 + r;
        const int tok = seq[tok0c + gm];
        const float* er = embed + (size_t)tok * kH;
#pragma unroll
        for (int ni = 0; ni < 4; ++ni) {
          const int gn = bn0 + wn + ni * 16 + (lane & 15);
          Xout[(size_t)gm * N + gn] = acc[mi][ni][r] + bias[gn] + er[gn];
        }
      }
  } else {
    // EPI==2: write K as fp16 hi/lo pairs + per-quarter ssq partials (Xout).
    _Float16* kh_s = (_Float16*)ks;
    _Float16* kh_e = (_Float16*)ke;
    float s2[4][4];
#pragma unroll
    for (int mi = 0; mi < 4; ++mi)
#pragma unroll
      for (int r = 0; r < 4; ++r) s2[mi][r] = 0.f;
#pragma unroll
    for (int mi = 0; mi < 4; ++mi)
#pragma unroll
      for (int ni = 0; ni < 4; ++ni) {
        const int gn = bn0 + wn + ni * 16 + (lane & 15);
        const float bv = (gn < 256) ? bias[gn] : bias2[gn - 256];
        _Float16* Dh = (gn < 256) ? kh_s : kh_e;
        _Float16* Dl = (gn < 256) ? Oh : Ol;
        const int col = gn & 255;
#pragma unroll
        for (int r = 0; r < 4; ++r) {
          const int gm = bm0 + wm + mi * 16 + erow0 + r;
          const float v = acc[mi][ni][r] + bv;
          s2[mi][r] += v * v;
          _Float16 h, l;
          fsplit(v, h, l);
          Dh[(size_t)(tok0c + gm) * 256 + col] = h;
          Dl[(size_t)(tok0c + gm) * 256 + col] = l;
        }
      }
    // deterministic per-quarter partial sums: ssqPart[mat][tok][half*2 + (wv&1)]
    const int matq  = bn0 >> 8;
    const int halfq = (bn0 >> 7) & 1;
#pragma unroll
    for (int mi = 0; mi < 4; ++mi)
#pragma unroll
      for (int r = 0; r < 4; ++r) {
        float s2v = s2[mi][r];
        s2v += __shfl_xor(s2v, 1);
        s2v += __shfl_xor(s2v, 2);
        s2v += __shfl_xor(s2v, 4);
        s2v += __shfl_xor(s2v, 8);
        if ((lane & 15) == 0) {
          const int gm = bm0 + wm + mi * 16 + erow0 + r;
          Xout[((size_t)matq * kTok + (size_t)(tok0c + gm)) * 4 + halfq * 2 + (wv & 1)] = s2v;
        }
      }
  }
}

// ---------------- LayerNorm: x fp32 -> hi/lo fp16
__global__ __launch_bounds__(256) void ln_split(
    const float* __restrict__ x, const float* __restrict__ g,
    const float* __restrict__ bta, _Float16* __restrict__ hh,
    _Float16* __restrict__ hl)
{
  const int wid  = threadIdx.x >> 6;
  const int lane = threadIdx.x & 63;
  const int ltok = blockIdx.x * 4 + wid;
  const float* xp = x + (size_t)ltok * kH;
  const float4 v0 = *(const float4*)(xp + lane * 8);
  const float4 v1 = *(const float4*)(xp + lane * 8 + 4);
  float s  = v0.x + v0.y + v0.z + v0.w + v1.x + v1.y + v1.z + v1.w;
  float ss = v0.x * v0.x + v0.y * v0.y + v0.z * v0.z + v0.w * v0.w +
             v1.x * v1.x + v1.y * v1.y + v1.z * v1.z + v1.w * v1.w;
#pragma unroll
  for (int m = 1; m < 64; m <<= 1) { s += __shfl_xor(s, m); ss += __shfl_xor(ss, m); }
  const float mu  = s * (1.f / kH);
  const float var = ss * (1.f / kH) - mu * mu;
  const float rs  = 1.f / sqrtf(var + 1e-5f);
  const float4 g0 = *(const float4*)(g + lane * 8);
  const float4 g1 = *(const float4*)(g + lane * 8 + 4);
  const float4 b0 = *(const float4*)(bta + lane * 8);
  const float4 b1 = *(const float4*)(bta + lane * 8 + 4);
  const float vv[8] = {v0.x, v0.y, v0.z, v0.w, v1.x, v1.y, v1.z, v1.w};
  const float gg[8] = {g0.x, g0.y, g0.z, g0.w, g1.x, g1.y, g1.z, g1.w};
  const float bb[8] = {b0.x, b0.y, b0.z, b0.w, b1.x, b1.y, b1.z, b1.w};
  union { _Float16 h[8]; uint4 u; } ph, pl;
#pragma unroll
  for (int i = 0; i < 8; ++i) {
    const float o = (vv[i] - mu) * rs * gg[i] + bb[i];
    fsplit(o, ph.h[i], pl.h[i]);
  }
  *(uint4*)(hh + (size_t)ltok * kH + lane * 8) = ph.u;
  *(uint4*)(hl + (size_t)ltok * kH + lane * 8) = pl.u;
}

// ---------------- chunked WY delta-rule scan (v6).
// v6: K read from HBM ~2x per chunk (ring staging + kt staging) instead of
// v5's ~5x; Q AND G fragments consumed from a swizzled conflict-free LDS
// panel ring; ssq precomputed in hgemm<2> epilogue (phase deleted); solve kv
// loads software-pipelined; solve wave runs at setprio(1). LDS layout aliased
// to stay at 70144 B (2 blocks/CU).
union Reg1 {
  struct { _Float16 h[2][4096], l[2][4096]; } ring;      // K panels, dbuf (32768 B)
  struct { float m[64][66]; } r;                          // Rr residual (16896 B)
  struct { _Float16 h[4608], l[4608]; } kt[2];            // K^T subtiles, dbuf (36864 B)
};
struct STile { _Float16 h[4096], l[4096]; };              // 16384 B
union Reg2 { STile s; float Gm[64 * 64]; float cred[4][64]; };
union Reg3 { STile s; struct { _Float16 Uh[4096], Ul[4096]; } u; };

__global__ __launch_bounds__(256, 2) void scan_chunked(
    const _Float16* __restrict__ khs, const _Float16* __restrict__ kls,
    const _Float16* __restrict__ khe, const _Float16* __restrict__ kle,
    const float* __restrict__ ssqP, const float* __restrict__ wts,
    float* __restrict__ c_out)
{
  __shared__ Reg1 R1;
  __shared__ Reg2 R2;
  __shared__ Reg3 R3;
  __shared__ float aS[64], wS[64];

  const int tid  = threadIdx.x;
  const int lane = tid & 63;
  const int wv   = tid >> 6;
  const int l15  = lane & 15;
  const int quad = lane >> 4;
  const int wg   = blockIdx.x;
  const int b    = wg >> 3;
  const int mat  = (wg >> 2) & 1;
  const int q    = wg & 3;
  const int j0   = q * 64;
  const _Float16* Kh = (mat ? khe : khs) + (size_t)b * (1024 * 256);
  const _Float16* Kl = (mat ? kle : kls) + (size_t)b * (1024 * 256);

  // S[p*4+nt]: rows p*64 + wv*16 + quad*4 + r ; cols nt*16 + l15 (WG-local j)
  f32x4 S[16];
#pragma unroll
  for (int i = 0; i < 16; ++i) S[i] = {0.f, 0.f, 0.f, 0.f};

  // staging thread mapping (ring): row stk, 16-half group dg, XOR swizzle
  const int stk = tid >> 2;          // 0..63
  const int dg  = (tid & 3) << 4;    // 0,16,32,48
  const int swz = (stk & 7) << 3;
  const int c0  = dg ^ swz;
  const int c1  = (dg + 8) ^ swz;

  for (int ck = 0; ck < 16; ++ck) {
    const int tok0 = ck * 64;

    __syncthreads();   // B0: prev chunk kt/U/Gm readers done; regions writable

    // aS/wS from precomputed ssq partials (tiny)
    if (tid < 64) {
      const float4 sq = *(const float4*)(
          ssqP + ((size_t)mat * kTok + (size_t)b * 1024 + tok0 + tid) * 4);
      const float w = mat ? wts[tok0 + tid] : 1.f;
      wS[tid] = w;
      aS[tid] = w / (sq.x + sq.y + sq.z + sq.w + 1e-6f);
    }

    // issue K panel-0 staging loads
    const _Float16* gh = Kh + (size_t)(tok0 + stk) * 256 + dg;
    const _Float16* gl = Kl + (size_t)(tok0 + stk) * 256 + dg;
    uint4 ph0 = *(const uint4*)(gh);
    uint4 ph1 = *(const uint4*)(gh + 8);
    uint4 pl0 = *(const uint4*)(gl);
    uint4 pl1 = *(const uint4*)(gl + 8);

    // stage S^T panel 0 into R2 (even buffer)
#pragma unroll
    for (int nt = 0; nt < 4; ++nt) {
      const f32x4 v = S[0 * 4 + nt];
      union { _Float16 h[4]; uint2 u; } qh, ql;
#pragma unroll
      for (int r = 0; r < 4; ++r) fsplit(v[r], qh.h[r], ql.h[r]);
      const int ix = six(nt * 16 + l15, wv * 16 + quad * 4);
      *(uint2*)&R2.s.h[ix] = qh.u;
      *(uint2*)&R2.s.l[ix] = ql.u;
    }
    // write ring buf 0
    *(uint4*)&R1.ring.h[0][(stk << 6) + c0] = ph0;
    *(uint4*)&R1.ring.h[0][(stk << 6) + c1] = ph1;
    *(uint4*)&R1.ring.l[0][(stk << 6) + c0] = pl0;
    *(uint4*)&R1.ring.l[0][(stk << 6) + c1] = pl1;
    __syncthreads();   // B1

    f32x4 Qa[4], Ga[4];
#pragma unroll
    for (int i = 0; i < 4; ++i) { Qa[i] = {0.f,0.f,0.f,0.f}; Ga[i] = {0.f,0.f,0.f,0.f}; }

#pragma unroll
    for (int p = 0; p < 4; ++p) {
      const int cur = p & 1;
      const _Float16* sh = cur ? R3.s.h : R2.s.h;
      const _Float16* sl = cur ? R3.s.l : R2.s.l;
      _Float16* nh = cur ? R2.s.h : R3.s.h;
      _Float16* nl = cur ? R2.s.l : R3.s.l;

      uint4 qh0, qh1, ql0, ql1;
      if (p < 3) {
        // issue next K panel loads early
        qh0 = *(const uint4*)(gh + (p + 1) * 64);
        qh1 = *(const uint4*)(gh + (p + 1) * 64 + 8);
        ql0 = *(const uint4*)(gl + (p + 1) * 64);
        ql1 = *(const uint4*)(gl + (p + 1) * 64 + 8);
        // stage next S^T panel (buffer's readers finished at previous barrier)
#pragma unroll
        for (int nt = 0; nt < 4; ++nt) {
          const f32x4 v = S[(p + 1) * 4 + nt];
          union { _Float16 h[4]; uint2 u; } sqh, sql;
#pragma unroll
          for (int r = 0; r < 4; ++r) fsplit(v[r], sqh.h[r], sql.h[r]);
          const int ix = six(nt * 16 + l15, wv * 16 + quad * 4);
          *(uint2*)&nh[ix] = sqh.u;
          *(uint2*)&nl[ix] = sql.u;
        }
      }

#pragma unroll
      for (int kit = 0; kit < 2; ++kit) {
        const int dim = kit * 32 + quad * 8;
        const int dsw = (l15 & 7) << 3;
        const f16x8 ah = *(const f16x8*)&R1.ring.h[cur][((wv * 16 + l15) << 6) + (dim ^ dsw)];
        const f16x8 al = *(const f16x8*)&R1.ring.l[cur][((wv * 16 + l15) << 6) + (dim ^ dsw)];
#pragma unroll
        for (int nt = 0; nt < 4; ++nt) {
          const int ix = six(nt * 16 + l15, dim);
          const f16x8 bh = *(const f16x8*)&sh[ix];
          const f16x8 bl = *(const f16x8*)&sl[ix];
          Qa[nt] = __builtin_amdgcn_mfma_f32_16x16x32_f16(ah, bh, Qa[nt], 0, 0, 0);
          Qa[nt] = __builtin_amdgcn_mfma_f32_16x16x32_f16(ah, bl, Qa[nt], 0, 0, 0);
          Qa[nt] = __builtin_amdgcn_mfma_f32_16x16x32_f16(al, bh, Qa[nt], 0, 0, 0);
        }
#pragma unroll
        for (int nt = 0; nt < 4; ++nt) {
          const f16x8 gb = *(const f16x8*)&R1.ring.h[cur][((nt * 16 + l15) << 6) + (dim ^ dsw)];
          const f16x8 gl2 = *(const f16x8*)&R1.ring.l[cur][((nt * 16 + l15) << 6) + (dim ^ dsw)];
          Ga[nt] = __builtin_amdgcn_mfma_f32_16x16x32_f16(ah, gb, Ga[nt], 0, 0, 0);
          Ga[nt] = __builtin_amdgcn_mfma_f32_16x16x32_f16(ah, gl2, Ga[nt], 0, 0, 0);
          Ga[nt] = __builtin_amdgcn_mfma_f32_16x16x32_f16(al, gb, Ga[nt], 0, 0, 0);
        }
      }
      if (p < 3) {   // write next K panel into other ring buf (readers done at prev barrier)
        *(uint4*)&R1.ring.h[1 - cur][(stk << 6) + c0] = qh0;
        *(uint4*)&R1.ring.h[1 - cur][(stk << 6) + c1] = qh1;
        *(uint4*)&R1.ring.l[1 - cur][(stk << 6) + c0] = ql0;
        *(uint4*)&R1.ring.l[1 - cur][(stk << 6) + c1] = ql1;
      }
      __syncthreads();   // end of panel p: staged data visible, reads done
    }

    // ---- writeback: Q -> Rr[t][j] (aliases ring), G -> Gm (aliases S^T even)
#pragma unroll
    for (int nt = 0; nt < 4; ++nt) {
#pragma unroll
      for (int r = 0; r < 4; ++r)
        R1.r.m[wv * 16 + quad * 4 + r][nt * 16 + l15] = Qa[nt][r];
      *(float4*)&R2.Gm[gmidx(nt * 16 + l15, wv * 16 + quad * 4)] = *(const float4*)&Ga[nt];
    }
    __syncthreads();   // B4: Rr/Gm/aS/wS visible

    // ---- barrier-free triangular solve: thread j owns col j
    if (tid < 64) {
      __builtin_amdgcn_s_setprio(1);
      const int j = tid;
      const int keyU = (j & 7) << 3;
      float kvh[8], kvl[8];
#pragma unroll
      for (int i = 0; i < 8; ++i) {
        const size_t go = (size_t)(tok0 + i) * 256 + j0 + j;
        kvh[i] = (float)Kh[go];
        kvl[i] = (float)Kl[go];
      }
      for (int blk = 0; blk < 8; ++blk) {
        const int t0 = blk * 8;
        float rl[8], kv[8], ub[8];
#pragma unroll
        for (int i = 0; i < 8; ++i) kv[i] = kvh[i] + kvl[i];
        if (blk < 7) {   // software-pipeline next block's kv loads
#pragma unroll
          for (int i = 0; i < 8; ++i) {
            const size_t go = (size_t)(tok0 + t0 + 8 + i) * 256 + j0 + j;
            kvh[i] = (float)Kh[go];
            kvl[i] = (float)Kl[go];
          }
        }
#pragma unroll
        for (int i = 0; i < 8; ++i) rl[i] = R1.r.m[t0 + i][j];
#pragma unroll
        for (int i = 0; i < 8; ++i) {
          const int t = t0 + i;
          float u = wS[t] * kv[i] - aS[t] * rl[i];
          if (ck == 15 && t == 63) u = 0.f;   // token L-1 is the query only
          ub[i] = u;
#pragma unroll
          for (int i2 = i + 1; i2 < 8; ++i2)
            rl[i2] += R2.Gm[gmidx(t0 + i2, t)] * u;
        }
        union { _Float16 h[8]; uint4 u4; } uh, ul;
#pragma unroll
        for (int i = 0; i < 8; ++i) fsplit(ub[i], uh.h[i], ul.h[i]);
        *(uint4*)&R3.u.Uh[j * 64 + (t0 ^ keyU)] = uh.u4;
        *(uint4*)&R3.u.Ul[j * 64 + (t0 ^ keyU)] = ul.u4;
        for (int t2 = t0 + 8; t2 < 64; ++t2) {
          const float4 g0 = *(const float4*)&R2.Gm[gmidx(t2, t0)];
          const float4 g1 = *(const float4*)&R2.Gm[gmidx(t2, t0 + 4)];
          R1.r.m[t2][j] += g0.x*ub[0] + g0.y*ub[1] + g0.z*ub[2] + g0.w*ub[3]
                         + g1.x*ub[4] + g1.y*ub[5] + g1.z*ub[6] + g1.w*ub[7];
        }
      }
      __builtin_amdgcn_s_setprio(0);
    }

    // pre-issue K^T panel-0 staging loads (land while waiting on the solve)
    const _Float16* ktsrc_h = Kh + (size_t)(tok0 + lane) * 256 + wv * 16;
    const _Float16* ktsrc_l = Kl + (size_t)(tok0 + lane) * 256 + wv * 16;
    const f16x8 s0h = *(const f16x8*)(ktsrc_h);
    const f16x8 s1h = *(const f16x8*)(ktsrc_h + 8);
    const f16x8 s0l = *(const f16x8*)(ktsrc_l);
    const f16x8 s1l = *(const f16x8*)(ktsrc_l + 8);
    __syncthreads();   // B5: Uh/Ul visible; Rr/ring dead
    const int wix = (wv * 16 + (lane >> 2)) * 72 + (lane & 3) * 16;
    *(f16x8*)&R1.kt[0].h[wix]     = s0h;
    *(f16x8*)&R1.kt[0].h[wix + 8] = s1h;
    *(f16x8*)&R1.kt[0].l[wix]     = s0l;
    *(f16x8*)&R1.kt[0].l[wix + 8] = s1l;
    __syncthreads();   // Bu0

    // ---- S += K^T U, panel by panel (conflict-free subtiled LDS transpose)
#pragma unroll
    for (int p = 0; p < 4; ++p) {
      const int cur = p & 1;
      f16x8 n0h, n1h, n0l, n1l;
      if (p < 3) {   // issue next-panel loads early (T14 split)
        n0h = *(const f16x8*)(ktsrc_h + (p + 1) * 64);
        n1h = *(const f16x8*)(ktsrc_h + (p + 1) * 64 + 8);
        n0l = *(const f16x8*)(ktsrc_l + (p + 1) * 64);
        n1l = *(const f16x8*)(ktsrc_l + (p + 1) * 64 + 8);
      }
      union { _Float16 e[8]; f16x8 v; } uah[2], ual[2];
#pragma unroll
      for (int kit = 0; kit < 2; ++kit) {
        const int base = (wv * 16 + 8 * kit + 2 * quad) * 72 + l15;
#pragma unroll
        for (int jj = 0; jj < 8; ++jj) {
          const int off = (jj >> 2) * 72 + (jj & 3) * 16;
          uah[kit].e[jj] = R1.kt[cur].h[base + off];
          ual[kit].e[jj] = R1.kt[cur].l[base + off];
        }
      }
#pragma unroll
      for (int kit = 0; kit < 2; ++kit) {
        const int ko = kit * 32 + quad * 8;
#pragma unroll
        for (int nt = 0; nt < 4; ++nt) {
          const int ix = six(nt * 16 + l15, ko);
          const f16x8 bh = *(const f16x8*)&R3.u.Uh[ix];
          const f16x8 bl = *(const f16x8*)&R3.u.Ul[ix];
          f32x4 s = S[p * 4 + nt];
          s = __builtin_amdgcn_mfma_f32_16x16x32_f16(uah[kit].v, bh, s, 0, 0, 0);
          s = __builtin_amdgcn_mfma_f32_16x16x32_f16(uah[kit].v, bl, s, 0, 0, 0);
          s = __builtin_amdgcn_mfma_f32_16x16x32_f16(ual[kit].v, bh, s, 0, 0, 0);
          S[p * 4 + nt] = s;
        }
      }
      if (p < 3) {   // write next panel (buf safe: its readers done at prev barrier)
        *(f16x8*)&R1.kt[1 - cur].h[wix]     = n0h;
        *(f16x8*)&R1.kt[1 - cur].h[wix + 8] = n1h;
        *(f16x8*)&R1.kt[1 - cur].l[wix]     = n0l;
        *(f16x8*)&R1.kt[1 - cur].l[wix + 8] = n1l;
        __syncthreads();   // Bup
      }
    }
    // p=3 reads finish before next chunk's B0 rewrites Reg1
  }

  // ---- readout: c[col] = sum_rows S[row][col] * k_last[row]
  float part[4] = {0.f, 0.f, 0.f, 0.f};
  const size_t lastoff = (size_t)(kL - 1) * 256;
#pragma unroll
  for (int p = 0; p < 4; ++p) {
    float klr[4];
#pragma unroll
    for (int r = 0; r < 4; ++r) {
      const int row = p * 64 + wv * 16 + quad * 4 + r;
      klr[r] = (float)Kh[lastoff + row] + (float)Kl[lastoff + row];
    }
#pragma unroll
    for (int nt = 0; nt < 4; ++nt)
#pragma unroll
      for (int r = 0; r < 4; ++r) part[nt] += S[p * 4 + nt][r] * klr[r];
  }
#pragma unroll
  for (int nt = 0; nt < 4; ++nt) {
    part[nt] += __shfl_xor(part[nt], 16);
    part[nt] += __shfl_xor(part[nt], 32);
  }
  __syncthreads();   // all prior LDS reads done before cred aliases Gm
  if (lane < 16) {
#pragma unroll
    for (int nt = 0; nt < 4; ++nt) R2.cred[wv][nt * 16 + l15] = part[nt];
  }
  __syncthreads();
  if (tid < 64) {
    const float c = R2.cred[0][tid] + R2.cred[1][tid] + R2.cred[2][tid] + R2.cred[3][tid];
    c_out[(size_t)b * 512 + mat * 256 + j0 + tid] = c;
  }
}

// ---------------- output GEMM: (64 x 512) @ (512 x 32000) + out_b -> fp32
__global__ __launch_bounds__(256) void out_gemm(
    const float* __restrict__ A, const float* __restrict__ Bm,
    const float* __restrict__ bias, float* __restrict__ C)
{
  __shared__ float As[16][64];
  __shared__ float Bs[16][128];
  const int tid = threadIdx.x;
  const int bn0 = blockIdx.x * 128;
  const int tm = tid >> 4, tn = tid & 15;
  float acc[4][8];
#pragma unroll
  for (int i = 0; i < 4; ++i)
#pragma unroll
    for (int j = 0; j < 8; ++j) acc[i][j] = 0.f;

  const int am  = tid & 63;
  const int ak  = (tid >> 6) * 4;
  const int bkr = tid >> 5;
  const int bcg = (tid & 31) * 4;

  for (int k0 = 0; k0 < kH; k0 += 16) {
    const float4 a0 = *(const float4*)(A + (size_t)am * kH + k0 + ak);
    const float4 b0 = *(const float4*)(Bm + (size_t)(k0 + bkr) * kV + bn0 + bcg);
    const float4 b1 = *(const float4*)(Bm + (size_t)(k0 + bkr + 8) * kV + bn0 + bcg);
    __syncthreads();
    As[ak + 0][am] = a0.x; As[ak + 1][am] = a0.y;
    As[ak + 2][am] = a0.z; As[ak + 3][am] = a0.w;
    *(float4*)&Bs[bkr][bcg]     = b0;
    *(float4*)&Bs[bkr + 8][bcg] = b1;
    __syncthreads();
#pragma unroll
    for (int kk = 0; kk < 16; ++kk) {
      const float4 aA = *(const float4*)&As[kk][tm * 4];
      const float4 bA = *(const float4*)&Bs[kk][tn * 4];
      const float4 bB = *(const float4*)&Bs[kk][64 + tn * 4];
      const float av[4] = {aA.x, aA.y, aA.z, aA.w};
      const float bv[8] = {bA.x, bA.y, bA.z, bA.w, bB.x, bB.y, bB.z, bB.w};
#pragma unroll
      for (int i = 0; i < 4; ++i)
#pragma unroll
        for (int j = 0; j < 8; ++j) acc[i][j] += av[i] * bv[j];
    }
  }

#pragma unroll
  for (int i = 0; i < 4; ++i) {
    const int row = tm * 4 + i;
#pragma unroll
    for (int hh = 0; hh < 2; ++hh) {
      const int n0 = bn0 + tn * 4 + hh * 64;
      const float4 bb = *(const float4*)(bias + n0);
      float4 o;
      o.x = acc[i][hh * 4 + 0] + bb.x;
      o.y = acc[i][hh * 4 + 1] + bb.y;
      o.z = acc[i][hh * 4 + 2] + bb.z;
      o.w = acc[i][hh * 4 + 3] + bb.w;
      *(float4*)(C + (size_t)row * kV + n0) = o;
    }
  }
}

}  // namespace

extern "C" void kernel_launch(void* const* d_in, const int* in_sizes, int n_in,
                              void* d_out, int out_size, void* d_ws, size_t ws_size,
                              hipStream_t stream)
{
  const int*   seq     = (const int*)  d_in[0];
  const float* embed   = (const float*)d_in[1];
  const float* w1      = (const float*)d_in[2];
  const float* b1      = (const float*)d_in[3];
  const float* w2      = (const float*)d_in[4];
  const float* b2      = (const float*)d_in[5];
  const float* ln_g    = (const float*)d_in[6];
  const float* ln_b    = (const float*)d_in[7];
  const float* sem_w   = (const float*)d_in[8];
  const float* sem_b   = (const float*)d_in[9];
  const float* epi_w   = (const float*)d_in[10];
  const float* epi_b   = (const float*)d_in[11];
  const float* out_w   = (const float*)d_in[12];
  const float* out_b   = (const float*)d_in[13];
  const float* pos_emb = (const float*)d_in[14];
  const float* pos_w   = (const float*)d_in[15];
  const float* pos_b   = (const float*)d_in[16];
  float* out = (float*)d_out;

  // chunk size: 16384 needs ~231 MB of ws; fall back to 8192 if tight.
  // ws_size is constant per process -> deterministic, graph-capture-safe.
  const int chunkN = (ws_size >= (size_t)240500000) ? 16384 : 8192;
  const int nch    = kTok / chunkN;

  char* p = (char*)d_ws;
  _Float16* w1th = (_Float16*)p; p += (size_t)1024 * 512 * 2;
  _Float16* w1tl = (_Float16*)p; p += (size_t)1024 * 512 * 2;
  _Float16* w2th = (_Float16*)p; p += (size_t)512 * 1024 * 2;
  _Float16* w2tl = (_Float16*)p; p += (size_t)512 * 1024 * 2;
  _Float16* wseh = (_Float16*)p; p += (size_t)512 * 512 * 2;
  _Float16* wsel = (_Float16*)p; p += (size_t)512 * 512 * 2;
  _Float16* t1h  = (_Float16*)p; p += (size_t)chunkN * 1024 * 2;
  _Float16* t1l  = (_Float16*)p; p += (size_t)chunkN * 1024 * 2;
  float*    x    = (float*)p;    p += (size_t)chunkN * kH * 4;
  _Float16* khs  = (_Float16*)p; p += (size_t)kTok * kHalf * 2;   // K hi/lo fp16
  _Float16* kls  = (_Float16*)p; p += (size_t)kTok * kHalf * 2;
  _Float16* khe  = (_Float16*)p; p += (size_t)kTok * kHalf * 2;
  _Float16* kle  = (_Float16*)p; p += (size_t)kTok * kHalf * 2;
  float*    wts  = (float*)p;    p += (size_t)kL * 4;
  float*    cout_= (float*)p;    p += (size_t)kB * 512 * 4;
  float*    ssqp = (float*)p;    p += (size_t)2 * kTok * 4 * 4;   // [mat][tok][4] partials
  _Float16* hh   = t1h;          // alias: t1 dead once x is written
  _Float16* hl   = t1l;

  pos_kernel<<<dim3((kL + 255) / 256), dim3(256), 0, stream>>>(pos_emb, pos_w, pos_b, wts);
  transpose_split<<<dim3(1024 * 512 / 256), dim3(256), 0, stream>>>(w1, w1th, w1tl, 1024, 9);
  transpose_split<<<dim3(512 * 1024 / 256), dim3(256), 0, stream>>>(w2, w2th, w2tl, 512, 10);
  transpose_split<<<dim3(256 * 512 / 256), dim3(256), 0, stream>>>(sem_w, wseh, wsel, 256, 9);
  transpose_split<<<dim3(256 * 512 / 256), dim3(256), 0, stream>>>(
      epi_w, wseh + (size_t)256 * 512, wsel + (size_t)256 * 512, 256, 9);

  for (int c = 0; c < nch; ++c) {
    const int tok0 = c * chunkN;
    hgemm<0><<<dim3(1024 / 128, chunkN / 128), dim3(256), 0, stream>>>(
        seq, embed, nullptr, nullptr, w1th, w1tl, b1, nullptr,
        nullptr, t1h, t1l, nullptr, nullptr, 512, 1024, tok0);
    hgemm<1><<<dim3(512 / 128, chunkN / 128), dim3(256), 0, stream>>>(
        seq, embed, t1h, t1l, w2th, w2tl, b2, nullptr,
        x, nullptr, nullptr, nullptr, nullptr, 1024, 512, tok0);
    ln_split<<<dim3(chunkN / 4), dim3(256), 0, stream>>>(x, ln_g, ln_b, hh, hl);
    hgemm<2><<<dim3(512 / 128, chunkN / 128), dim3(256), 0, stream>>>(
        seq, embed, hh, hl, wseh, wsel, sem_b, epi_b,
        ssqp, kls, kle, (float*)khs, (float*)khe,
        512, 512, tok0);
  }

  scan_chunked<<<dim3(512), dim3(256), 0, stream>>>(khs, kls, khe, kle, ssqp, wts, cout_);
  out_gemm<<<dim3(kV / 128), dim3(256), 0, stream>>>(cout_, out_w, out_b, out);

  (void)in_sizes; (void)n_in; (void)out_size;
}

// Round 3
// 1621.892 us; speedup vs baseline: 1.0976x; 1.0022x over previous
//
#include <hip/hip_runtime.h>
#include <hip/hip_bf16.h>
#include <math.h>

namespace {

constexpr int kH     = 512;
constexpr int kL     = 1024;
constexpr int kB     = 64;
constexpr int kHalf  = 256;
constexpr int kV     = 32000;
constexpr int kTok   = kB * kL;     // 65536

using f32x4 = __attribute__((ext_vector_type(4))) float;
using f16x8 = __attribute__((ext_vector_type(8))) _Float16;

__device__ inline void fsplit(float v, _Float16& h, _Float16& l) {
  h = (_Float16)v;
  l = (_Float16)(v - (float)h);
}

// Gm float [64][64] XOR swizzle (writes 4-way, reads are broadcast)
__device__ inline int gmidx(int r, int c) { return r * 64 + (c ^ ((r & 7) << 2)); }

// ---------------- positional weights
__global__ void pos_kernel(const float* __restrict__ pos_emb,
                           const float* __restrict__ pos_w,
                           const float* __restrict__ pos_b,
                           float* __restrict__ wts)
{
  int t = blockIdx.x * blockDim.x + threadIdx.x;
  if (t >= kL) return;
  float z = pos_b[0];
#pragma unroll
  for (int p = 0; p < 16; ++p) z += pos_emb[t * 16 + p] * pos_w[p];
  wts[t] = 1.f / (1.f + expf(-z));
}

// ---------------- transpose + hi/lo fp16 split: W[K][N] fp32 -> Th/Tl[N][K]
__global__ __launch_bounds__(256) void transpose_split(
    const float* __restrict__ W, _Float16* __restrict__ Th,
    _Float16* __restrict__ Tl, int N, int kshift)
{
  const int idx = blockIdx.x * 256 + threadIdx.x;
  const int K = 1 << kshift;
  const int k = idx & (K - 1);
  const int n = idx >> kshift;
  const float w = W[(size_t)k * N + n];
  const _Float16 h = (_Float16)w;
  Th[idx] = h;
  Tl[idx] = (_Float16)(w - (float)h);
}

// ---------------- split-fp16 MFMA GEMM: C[M,N] = A[M,K] @ (Bh+Bl)[N,K]^T
template <int EPI>
__global__ __launch_bounds__(256) void hgemm(
    const int* __restrict__ seq, const float* __restrict__ embed,
    const _Float16* __restrict__ Ah, const _Float16* __restrict__ Al,
    const _Float16* __restrict__ Bh, const _Float16* __restrict__ Bl,
    const float* __restrict__ bias, const float* __restrict__ bias2,
    float* __restrict__ Xout, _Float16* __restrict__ Oh, _Float16* __restrict__ Ol,
    float* __restrict__ ks, float* __restrict__ ke,
    int K, int N, int tok0c)
{
  __shared__ _Float16 lds[4][128][40];   // Ahi, Alo, Bhi, Blo; +8 pad (80B stride)
  const int tid  = threadIdx.x;
  const int lane = tid & 63;
  const int wv   = tid >> 6;
  const int wm   = (wv >> 1) * 64;
  const int wn   = (wv & 1) * 64;
  const int bm0  = blockIdx.y * 128;
  const int bn0  = blockIdx.x * 128;

  f32x4 acc[4][4];
#pragma unroll
  for (int i = 0; i < 4; ++i)
#pragma unroll
    for (int j = 0; j < 4; ++j) acc[i][j] = {0.f, 0.f, 0.f, 0.f};

  const int sr = tid >> 1;            // staging row 0..127
  const int sc = (tid & 1) << 4;      // 0 or 16 (halves)
  const _Float16* gBh = Bh + (size_t)(bn0 + sr) * K + sc;
  const _Float16* gBl = Bl + (size_t)(bn0 + sr) * K + sc;
  const _Float16* gAh = nullptr;
  const _Float16* gAl = nullptr;
  const float*    gAe = nullptr;
  if constexpr (EPI == 0) {
    const int tokrow = seq[tok0c + bm0 + sr];
    gAe = embed + (size_t)tokrow * kH + sc;
  } else {
    gAh = Ah + (size_t)(bm0 + sr) * K + sc;
    gAl = Al + (size_t)(bm0 + sr) * K + sc;
  }

  const int lrow = lane & 15;
  const int lk   = (lane >> 4) * 8;

  for (int k0 = 0; k0 < K; k0 += 32) {
    const uint4 vC0 = *(const uint4*)(gBh + k0);
    const uint4 vC1 = *(const uint4*)(gBh + k0 + 8);
    const uint4 vD0 = *(const uint4*)(gBl + k0);
    const uint4 vD1 = *(const uint4*)(gBl + k0 + 8);
    if constexpr (EPI == 0) {
      const float4 a0 = *(const float4*)(gAe + k0);
      const float4 a1 = *(const float4*)(gAe + k0 + 4);
      const float4 a2 = *(const float4*)(gAe + k0 + 8);
      const float4 a3 = *(const float4*)(gAe + k0 + 12);
      const float vv[16] = {a0.x,a0.y,a0.z,a0.w, a1.x,a1.y,a1.z,a1.w,
                            a2.x,a2.y,a2.z,a2.w, a3.x,a3.y,a3.z,a3.w};
      union { _Float16 h[16]; uint4 u[2]; } ph, pl;
#pragma unroll
      for (int i = 0; i < 16; ++i) fsplit(vv[i], ph.h[i], pl.h[i]);
      __syncthreads();
      *(uint4*)&lds[0][sr][sc]     = ph.u[0];
      *(uint4*)&lds[0][sr][sc + 8] = ph.u[1];
      *(uint4*)&lds[1][sr][sc]     = pl.u[0];
      *(uint4*)&lds[1][sr][sc + 8] = pl.u[1];
    } else {
      const uint4 vA0 = *(const uint4*)(gAh + k0);
      const uint4 vA1 = *(const uint4*)(gAh + k0 + 8);
      const uint4 vB0 = *(const uint4*)(gAl + k0);
      const uint4 vB1 = *(const uint4*)(gAl + k0 + 8);
      __syncthreads();
      *(uint4*)&lds[0][sr][sc]     = vA0;
      *(uint4*)&lds[0][sr][sc + 8] = vA1;
      *(uint4*)&lds[1][sr][sc]     = vB0;
      *(uint4*)&lds[1][sr][sc + 8] = vB1;
    }
    *(uint4*)&lds[2][sr][sc]     = vC0;
    *(uint4*)&lds[2][sr][sc + 8] = vC1;
    *(uint4*)&lds[3][sr][sc]     = vD0;
    *(uint4*)&lds[3][sr][sc + 8] = vD1;
    __syncthreads();

    f16x8 fBh[4], fBl[4];
#pragma unroll
    for (int ni = 0; ni < 4; ++ni) {
      fBh[ni] = *(const f16x8*)&lds[2][wn + ni * 16 + lrow][lk];
      fBl[ni] = *(const f16x8*)&lds[3][wn + ni * 16 + lrow][lk];
    }
#pragma unroll
    for (int mi = 0; mi < 4; ++mi) {
      const f16x8 ah = *(const f16x8*)&lds[0][wm + mi * 16 + lrow][lk];
      const f16x8 al = *(const f16x8*)&lds[1][wm + mi * 16 + lrow][lk];
#pragma unroll
      for (int ni = 0; ni < 4; ++ni) {
        acc[mi][ni] = __builtin_amdgcn_mfma_f32_16x16x32_f16(ah, fBh[ni], acc[mi][ni], 0, 0, 0);
        acc[mi][ni] = __builtin_amdgcn_mfma_f32_16x16x32_f16(ah, fBl[ni], acc[mi][ni], 0, 0, 0);
        acc[mi][ni] = __builtin_amdgcn_mfma_f32_16x16x32_f16(al, fBh[ni], acc[mi][ni], 0, 0, 0);
      }
    }
  }

  const int erow0 = (lane >> 4) * 4;
  if constexpr (EPI == 0) {
#pragma unroll
    for (int mi = 0; mi < 4; ++mi)
#pragma unroll
      for (int ni = 0; ni < 4; ++ni) {
        const int gn = bn0 + wn + ni * 16 + (lane & 15);
        const float bv = bias[gn];
#pragma unroll
        for (int r = 0; r < 4; ++r) {
          const int gm = bm0 + wm + mi * 16 + erow0 + r;
          float v = fmaxf(acc[mi][ni][r] + bv, 0.f);
          const _Float16 h = (_Float16)v;
          Oh[(size_t)gm * N + gn] = h;
          Ol[(size_t)gm * N + gn] = (_Float16)(v - (float)h);
        }
      }
  } else if constexpr (EPI == 1) {
#pragma unroll
    for (int mi = 0; mi < 4; ++mi)
#pragma unroll
      for (int r = 0; r < 4; ++r) {
        const int gm = bm0 + wm + mi * 16 + erow0 + r;
        const int tok = seq[tok0c + gm];
        const float* er = embed + (size_t)tok * kH;
#pragma unroll
        for (int ni = 0; ni < 4; ++ni) {
          const int gn = bn0 + wn + ni * 16 + (lane & 15);
          Xout[(size_t)gm * N + gn] = acc[mi][ni][r] + bias[gn] + er[gn];
        }
      }
  } else {
    // EPI==2: write K as fp16 hi/lo pairs + per-quarter ssq partials (Xout).
    _Float16* kh_s = (_Float16*)ks;
    _Float16* kh_e = (_Float16*)ke;
    float s2[4][4];
#pragma unroll
    for (int mi = 0; mi < 4; ++mi)
#pragma unroll
      for (int r = 0; r < 4; ++r) s2[mi][r] = 0.f;
#pragma unroll
    for (int mi = 0; mi < 4; ++mi)
#pragma unroll
      for (int ni = 0; ni < 4; ++ni) {
        const int gn = bn0 + wn + ni * 16 + (lane & 15);
        const float bv = (gn < 256) ? bias[gn] : bias2[gn - 256];
        _Float16* Dh = (gn < 256) ? kh_s : kh_e;
        _Float16* Dl = (gn < 256) ? Oh : Ol;
        const int col = gn & 255;
#pragma unroll
        for (int r = 0; r < 4; ++r) {
          const int gm = bm0 + wm + mi * 16 + erow0 + r;
          const float v = acc[mi][ni][r] + bv;
          s2[mi][r] += v * v;
          _Float16 h, l;
          fsplit(v, h, l);
          Dh[(size_t)(tok0c + gm) * 256 + col] = h;
          Dl[(size_t)(tok0c + gm) * 256 + col] = l;
        }
      }
    // deterministic per-quarter partial sums: ssqPart[mat][tok][half*2 + (wv&1)]
    const int matq  = bn0 >> 8;
    const int halfq = (bn0 >> 7) & 1;
#pragma unroll
    for (int mi = 0; mi < 4; ++mi)
#pragma unroll
      for (int r = 0; r < 4; ++r) {
        float s2v = s2[mi][r];
        s2v += __shfl_xor(s2v, 1);
        s2v += __shfl_xor(s2v, 2);
        s2v += __shfl_xor(s2v, 4);
        s2v += __shfl_xor(s2v, 8);
        if ((lane & 15) == 0) {
          const int gm = bm0 + wm + mi * 16 + erow0 + r;
          Xout[((size_t)matq * kTok + (size_t)(tok0c + gm)) * 4 + halfq * 2 + (wv & 1)] = s2v;
        }
      }
  }
}

// ---------------- LayerNorm: x fp32 -> hi/lo fp16
__global__ __launch_bounds__(256) void ln_split(
    const float* __restrict__ x, const float* __restrict__ g,
    const float* __restrict__ bta, _Float16* __restrict__ hh,
    _Float16* __restrict__ hl)
{
  const int wid  = threadIdx.x >> 6;
  const int lane = threadIdx.x & 63;
  const int ltok = blockIdx.x * 4 + wid;
  const float* xp = x + (size_t)ltok * kH;
  const float4 v0 = *(const float4*)(xp + lane * 8);
  const float4 v1 = *(const float4*)(xp + lane * 8 + 4);
  float s  = v0.x + v0.y + v0.z + v0.w + v1.x + v1.y + v1.z + v1.w;
  float ss = v0.x * v0.x + v0.y * v0.y + v0.z * v0.z + v0.w * v0.w +
             v1.x * v1.x + v1.y * v1.y + v1.z * v1.z + v1.w * v1.w;
#pragma unroll
  for (int m = 1; m < 64; m <<= 1) { s += __shfl_xor(s, m); ss += __shfl_xor(ss, m); }
  const float mu  = s * (1.f / kH);
  const float var = ss * (1.f / kH) - mu * mu;
  const float rs  = 1.f / sqrtf(var + 1e-5f);
  const float4 g0 = *(const float4*)(g + lane * 8);
  const float4 g1 = *(const float4*)(g + lane * 8 + 4);
  const float4 b0 = *(const float4*)(bta + lane * 8);
  const float4 b1 = *(const float4*)(bta + lane * 8 + 4);
  const float vv[8] = {v0.x, v0.y, v0.z, v0.w, v1.x, v1.y, v1.z, v1.w};
  const float gg[8] = {g0.x, g0.y, g0.z, g0.w, g1.x, g1.y, g1.z, g1.w};
  const float bb[8] = {b0.x, b0.y, b0.z, b0.w, b1.x, b1.y, b1.z, b1.w};
  union { _Float16 h[8]; uint4 u; } ph, pl;
#pragma unroll
  for (int i = 0; i < 8; ++i) {
    const float o = (vv[i] - mu) * rs * gg[i] + bb[i];
    fsplit(o, ph.h[i], pl.h[i]);
  }
  *(uint4*)(hh + (size_t)ltok * kH + lane * 8) = ph.u;
  *(uint4*)(hl + (size_t)ltok * kH + lane * 8) = pl.u;
}

// ---------------- chunked WY delta-rule scan (v7).
// v7 vs v6: (1) all half-tiles stride 72 (144B) rows, XOR dropped -> every
// MFMA fragment read is 2-way (free); (2) U B-fragments hoisted out of the
// panel loop (were re-read 4x); ring loads deep-issued (4 panels at chunk
// top), kt loads 2 panels ahead in named regs; (3) triangular solve
// cooperative: wave0 = inner + next-8-rows, waves1-3 = deferred rank-8
// far-update via ubS broadcast, per-block barrier. Numerics order preserved.
struct RingT { _Float16 h[2][4608], l[2][4608]; };        // 36864 B
union Reg1 {
  RingT ring;
  struct { float m[64][66]; } r;                          // Rr residual 16896 B
  struct { _Float16 h[4608], l[4608]; } kt[2];            // K^T subtiles 36864 B
};
struct STile { _Float16 h[4608], l[4608]; };              // 18432 B
union Reg2 { STile s; float Gm[64 * 64]; float cred[4][64]; };
union Reg3 { STile s; struct { _Float16 Uh[4608], Ul[4608]; } u; };

__global__ __launch_bounds__(256, 2) void scan_chunked(
    const _Float16* __restrict__ khs, const _Float16* __restrict__ kls,
    const _Float16* __restrict__ khe, const _Float16* __restrict__ kle,
    const float* __restrict__ ssqP, const float* __restrict__ wts,
    float* __restrict__ c_out)
{
  __shared__ Reg1 R1;
  __shared__ Reg2 R2;
  __shared__ Reg3 R3;
  __shared__ float ubS[2][64][12];   // solve ub broadcast, dbuf (6144 B)
  __shared__ float aS[64], wS[64];

  const int tid  = threadIdx.x;
  const int lane = tid & 63;
  const int wv   = tid >> 6;
  const int l15  = lane & 15;
  const int quad = lane >> 4;
  const int wg   = blockIdx.x;
  const int b    = wg >> 3;
  const int mat  = (wg >> 2) & 1;
  const int q    = wg & 3;
  const int j0   = q * 64;
  const _Float16* Kh = (mat ? khe : khs) + (size_t)b * (1024 * 256);
  const _Float16* Kl = (mat ? kle : kls) + (size_t)b * (1024 * 256);

  // S[p*4+nt]: rows p*64 + wv*16 + quad*4 + r ; cols nt*16 + l15 (WG-local j)
  f32x4 S[16];
#pragma unroll
  for (int i = 0; i < 16; ++i) S[i] = {0.f, 0.f, 0.f, 0.f};

  // ring staging mapping: row stk, 16-half col group dg
  const int stk = tid >> 2;          // 0..63
  const int dg  = (tid & 3) << 4;    // 0,16,32,48

  for (int ck = 0; ck < 16; ++ck) {
    const int tok0 = ck * 64;

    __syncthreads();   // B0: prev chunk kt/U/Gm readers done; regions writable

    // aS/wS from precomputed ssq partials (tiny; consumed at solve)
    if (tid < 64) {
      const float4 sq = *(const float4*)(
          ssqP + ((size_t)mat * kTok + (size_t)b * 1024 + tok0 + tid) * 4);
      const float w = mat ? wts[tok0 + tid] : 1.f;
      wS[tid] = w;
      aS[tid] = w / (sq.x + sq.y + sq.z + sq.w + 1e-6f);
    }

    // deep-issue ALL 4 ring K panels into registers (drained panel by panel)
    const _Float16* gh = Kh + (size_t)(tok0 + stk) * 256 + dg;
    const _Float16* gl = Kl + (size_t)(tok0 + stk) * 256 + dg;
    uint4 rh[8], rl[8];
#pragma unroll
    for (int pp = 0; pp < 4; ++pp) {
      rh[2 * pp]     = *(const uint4*)(gh + pp * 64);
      rh[2 * pp + 1] = *(const uint4*)(gh + pp * 64 + 8);
      rl[2 * pp]     = *(const uint4*)(gl + pp * 64);
      rl[2 * pp + 1] = *(const uint4*)(gl + pp * 64 + 8);
    }

    // stage S^T panel 0 into R2 (even buffer)
#pragma unroll
    for (int nt = 0; nt < 4; ++nt) {
      const f32x4 v = S[0 * 4 + nt];
      union { _Float16 h[4]; uint2 u; } qh, ql;
#pragma unroll
      for (int r = 0; r < 4; ++r) fsplit(v[r], qh.h[r], ql.h[r]);
      const int ix = (nt * 16 + l15) * 72 + wv * 16 + quad * 4;
      *(uint2*)&R2.s.h[ix] = qh.u;
      *(uint2*)&R2.s.l[ix] = ql.u;
    }
    // write ring panel 0
    {
      const int wb = stk * 72 + dg;
      *(uint4*)&R1.ring.h[0][wb]     = rh[0];
      *(uint4*)&R1.ring.h[0][wb + 8] = rh[1];
      *(uint4*)&R1.ring.l[0][wb]     = rl[0];
      *(uint4*)&R1.ring.l[0][wb + 8] = rl[1];
    }
    __syncthreads();   // B1

    f32x4 Qa[4], Ga[4];
#pragma unroll
    for (int i = 0; i < 4; ++i) { Qa[i] = {0.f,0.f,0.f,0.f}; Ga[i] = {0.f,0.f,0.f,0.f}; }

#pragma unroll
    for (int p = 0; p < 4; ++p) {
      const int cur = p & 1;
      const _Float16* sh = cur ? R3.s.h : R2.s.h;
      const _Float16* sl = cur ? R3.s.l : R2.s.l;
      _Float16* nh = cur ? R2.s.h : R3.s.h;
      _Float16* nl = cur ? R2.s.l : R3.s.l;

      if (p < 3) {   // stage next S^T panel (buffer's readers done at prev barrier)
#pragma unroll
        for (int nt = 0; nt < 4; ++nt) {
          const f32x4 v = S[(p + 1) * 4 + nt];
          union { _Float16 h[4]; uint2 u; } sqh, sql;
#pragma unroll
          for (int r = 0; r < 4; ++r) fsplit(v[r], sqh.h[r], sql.h[r]);
          const int ix = (nt * 16 + l15) * 72 + wv * 16 + quad * 4;
          *(uint2*)&nh[ix] = sqh.u;
          *(uint2*)&nl[ix] = sql.u;
        }
      }

#pragma unroll
      for (int kit = 0; kit < 2; ++kit) {
        const int dim = kit * 32 + quad * 8;
        const f16x8 ah = *(const f16x8*)&R1.ring.h[cur][(wv * 16 + l15) * 72 + dim];
        const f16x8 al = *(const f16x8*)&R1.ring.l[cur][(wv * 16 + l15) * 72 + dim];
#pragma unroll
        for (int nt = 0; nt < 4; ++nt) {
          const int ix = (nt * 16 + l15) * 72 + dim;
          const f16x8 bh = *(const f16x8*)&sh[ix];
          const f16x8 bl = *(const f16x8*)&sl[ix];
          Qa[nt] = __builtin_amdgcn_mfma_f32_16x16x32_f16(ah, bh, Qa[nt], 0, 0, 0);
          Qa[nt] = __builtin_amdgcn_mfma_f32_16x16x32_f16(ah, bl, Qa[nt], 0, 0, 0);
          Qa[nt] = __builtin_amdgcn_mfma_f32_16x16x32_f16(al, bh, Qa[nt], 0, 0, 0);
        }
#pragma unroll
        for (int nt = 0; nt < 4; ++nt) {
          const int ix = (nt * 16 + l15) * 72 + dim;
          const f16x8 gb  = *(const f16x8*)&R1.ring.h[cur][ix];
          const f16x8 gl2 = *(const f16x8*)&R1.ring.l[cur][ix];
          Ga[nt] = __builtin_amdgcn_mfma_f32_16x16x32_f16(ah, gb, Ga[nt], 0, 0, 0);
          Ga[nt] = __builtin_amdgcn_mfma_f32_16x16x32_f16(ah, gl2, Ga[nt], 0, 0, 0);
          Ga[nt] = __builtin_amdgcn_mfma_f32_16x16x32_f16(al, gb, Ga[nt], 0, 0, 0);
        }
      }
      if (p == 0) {
        const int wb = stk * 72 + dg;
        *(uint4*)&R1.ring.h[1][wb]     = rh[2];
        *(uint4*)&R1.ring.h[1][wb + 8] = rh[3];
        *(uint4*)&R1.ring.l[1][wb]     = rl[2];
        *(uint4*)&R1.ring.l[1][wb + 8] = rl[3];
      } else if (p == 1) {
        const int wb = stk * 72 + dg;
        *(uint4*)&R1.ring.h[0][wb]     = rh[4];
        *(uint4*)&R1.ring.h[0][wb + 8] = rh[5];
        *(uint4*)&R1.ring.l[0][wb]     = rl[4];
        *(uint4*)&R1.ring.l[0][wb + 8] = rl[5];
      } else if (p == 2) {
        const int wb = stk * 72 + dg;
        *(uint4*)&R1.ring.h[1][wb]     = rh[6];
        *(uint4*)&R1.ring.h[1][wb + 8] = rh[7];
        *(uint4*)&R1.ring.l[1][wb]     = rl[6];
        *(uint4*)&R1.ring.l[1][wb + 8] = rl[7];
      }
      __syncthreads();   // end of panel p
    }

    // ---- writeback: Q -> Rr[t][j] (aliases ring), G -> Gm (aliases S^T even)
#pragma unroll
    for (int nt = 0; nt < 4; ++nt) {
#pragma unroll
      for (int r = 0; r < 4; ++r)
        R1.r.m[wv * 16 + quad * 4 + r][nt * 16 + l15] = Qa[nt][r];
      *(float4*)&R2.Gm[gmidx(nt * 16 + l15, wv * 16 + quad * 4)] = *(const float4*)&Ga[nt];
    }

    // issue kt panels 0,1 into named regs (land under the solve)
    const _Float16* ktsrc_h = Kh + (size_t)(tok0 + lane) * 256 + wv * 16;
    const _Float16* ktsrc_l = Kl + (size_t)(tok0 + lane) * 256 + wv * 16;
    f16x8 kh0a = *(const f16x8*)(ktsrc_h);
    f16x8 kh0b = *(const f16x8*)(ktsrc_h + 8);
    f16x8 kl0a = *(const f16x8*)(ktsrc_l);
    f16x8 kl0b = *(const f16x8*)(ktsrc_l + 8);
    f16x8 kh1a = *(const f16x8*)(ktsrc_h + 64);
    f16x8 kh1b = *(const f16x8*)(ktsrc_h + 72);
    f16x8 kl1a = *(const f16x8*)(ktsrc_l + 64);
    f16x8 kl1b = *(const f16x8*)(ktsrc_l + 72);

    // wave0: preload solve kv for block 0
    float kvh[8], kvl[8];
    if (wv == 0) {
#pragma unroll
      for (int i = 0; i < 8; ++i) {
        const size_t go = (size_t)(tok0 + i) * 256 + j0 + lane;
        kvh[i] = (float)Kh[go];
        kvl[i] = (float)Kl[go];
      }
    }
    __syncthreads();   // B4: Rr/Gm/aS/wS visible

    // ---- cooperative blocked triangular solve
    float ubPrev[8];
    for (int blk = 0; blk < 8; ++blk) {
      const int t0 = blk * 8;
      if (wv == 0) {
        __builtin_amdgcn_s_setprio(1);
        float rl_[8], kv[8], ub[8];
#pragma unroll
        for (int i = 0; i < 8; ++i) kv[i] = kvh[i] + kvl[i];
        if (blk < 7) {   // software-pipeline next block's kv loads
#pragma unroll
          for (int i = 0; i < 8; ++i) {
            const size_t go = (size_t)(tok0 + t0 + 8 + i) * 256 + j0 + lane;
            kvh[i] = (float)Kh[go];
            kvl[i] = (float)Kl[go];
          }
        }
#pragma unroll
        for (int i = 0; i < 8; ++i) rl_[i] = R1.r.m[t0 + i][lane];
#pragma unroll
        for (int i = 0; i < 8; ++i) {
          const int t = t0 + i;
          float u = wS[t] * kv[i] - aS[t] * rl_[i];
          if (ck == 15 && t == 63) u = 0.f;   // token L-1 is the query only
          ub[i] = u;
#pragma unroll
          for (int i2 = i + 1; i2 < 8; ++i2)
            rl_[i2] += R2.Gm[gmidx(t0 + i2, t)] * u;
        }
        // publish ub (fp16 hi/lo U, and fp32 broadcast for far waves)
        union { _Float16 h[8]; uint4 u4; } uh, ul;
#pragma unroll
        for (int i = 0; i < 8; ++i) fsplit(ub[i], uh.h[i], ul.h[i]);
        *(uint4*)&R3.u.Uh[lane * 72 + t0] = uh.u4;
        *(uint4*)&R3.u.Ul[lane * 72 + t0] = ul.u4;
        float4 ub0 = {ub[0], ub[1], ub[2], ub[3]};
        float4 ub1 = {ub[4], ub[5], ub[6], ub[7]};
        *(float4*)&ubS[blk & 1][lane][0] = ub0;
        *(float4*)&ubS[blk & 1][lane][4] = ub1;
        // near-update: rows [t0+8, t0+16) get ub[blk-1] then ub[blk]
        if (blk < 7) {
          const int t0p = t0 - 8;
#pragma unroll
          for (int r2 = 0; r2 < 8; ++r2) {
            const int t2 = t0 + 8 + r2;
            float acc = R1.r.m[t2][lane];
            if (blk > 0) {
              const float4 g0 = *(const float4*)&R2.Gm[gmidx(t2, t0p)];
              const float4 g1 = *(const float4*)&R2.Gm[gmidx(t2, t0p + 4)];
              acc += g0.x*ubPrev[0] + g0.y*ubPrev[1] + g0.z*ubPrev[2] + g0.w*ubPrev[3]
                   + g1.x*ubPrev[4] + g1.y*ubPrev[5] + g1.z*ubPrev[6] + g1.w*ubPrev[7];
            }
            const float4 h0 = *(const float4*)&R2.Gm[gmidx(t2, t0)];
            const float4 h1 = *(const float4*)&R2.Gm[gmidx(t2, t0 + 4)];
            acc += h0.x*ub[0] + h0.y*ub[1] + h0.z*ub[2] + h0.w*ub[3]
                 + h1.x*ub[4] + h1.y*ub[5] + h1.z*ub[6] + h1.w*ub[7];
            R1.r.m[t2][lane] = acc;
          }
        }
#pragma unroll
        for (int i = 0; i < 8; ++i) ubPrev[i] = ub[i];
        __builtin_amdgcn_s_setprio(0);
      } else if (blk > 0) {
        // far-update: ub[blk-1] to rows [t0+16, 64), strided across waves 1..3
        const int t0p = t0 - 8;
        const float4 u0 = *(const float4*)&ubS[(blk - 1) & 1][lane][0];
        const float4 u1 = *(const float4*)&ubS[(blk - 1) & 1][lane][4];
        for (int t2 = t0 + 16 + (wv - 1); t2 < 64; t2 += 3) {
          const float4 g0 = *(const float4*)&R2.Gm[gmidx(t2, t0p)];
          const float4 g1 = *(const float4*)&R2.Gm[gmidx(t2, t0p + 4)];
          float acc = R1.r.m[t2][lane];
          acc += g0.x*u0.x + g0.y*u0.y + g0.z*u0.z + g0.w*u0.w
               + g1.x*u1.x + g1.y*u1.y + g1.z*u1.z + g1.w*u1.w;
          R1.r.m[t2][lane] = acc;
        }
      }
      __syncthreads();   // last iteration doubles as B5: Uh/Ul visible, Rr dead
    }

    // write kt panel 0 (ring/Rr region dead)
    const int wix = (wv * 16 + (lane >> 2)) * 72 + (lane & 3) * 16;
    *(f16x8*)&R1.kt[0].h[wix]     = kh0a;
    *(f16x8*)&R1.kt[0].h[wix + 8] = kh0b;
    *(f16x8*)&R1.kt[0].l[wix]     = kl0a;
    *(f16x8*)&R1.kt[0].l[wix + 8] = kl0b;
    __syncthreads();   // Bu0

    // hoist U B-fragments once (p-invariant; was re-read every panel)
    f16x8 uFh[8], uFl[8];
#pragma unroll
    for (int kit = 0; kit < 2; ++kit)
#pragma unroll
      for (int nt = 0; nt < 4; ++nt) {
        const int ix = (nt * 16 + l15) * 72 + kit * 32 + quad * 8;
        uFh[kit * 4 + nt] = *(const f16x8*)&R3.u.Uh[ix];
        uFl[kit * 4 + nt] = *(const f16x8*)&R3.u.Ul[ix];
      }

    // ---- S += K^T U, panel by panel
#pragma unroll
    for (int p = 0; p < 4; ++p) {
      const int cur = p & 1;
      if (p == 0) {          // re-issue kt panel 2 into the p0 regs
        kh0a = *(const f16x8*)(ktsrc_h + 128);
        kh0b = *(const f16x8*)(ktsrc_h + 136);
        kl0a = *(const f16x8*)(ktsrc_l + 128);
        kl0b = *(const f16x8*)(ktsrc_l + 136);
      } else if (p == 1) {   // re-issue kt panel 3 into the p1 regs
        kh1a = *(const f16x8*)(ktsrc_h + 192);
        kh1b = *(const f16x8*)(ktsrc_h + 200);
        kl1a = *(const f16x8*)(ktsrc_l + 192);
        kl1b = *(const f16x8*)(ktsrc_l + 200);
      }
      union { _Float16 e[8]; f16x8 v; } uah[2], ual[2];
#pragma unroll
      for (int kit = 0; kit < 2; ++kit) {
        const int base = (wv * 16 + 8 * kit + 2 * quad) * 72 + l15;
#pragma unroll
        for (int jj = 0; jj < 8; ++jj) {
          const int off = (jj >> 2) * 72 + (jj & 3) * 16;
          uah[kit].e[jj] = R1.kt[cur].h[base + off];
          ual[kit].e[jj] = R1.kt[cur].l[base + off];
        }
      }
#pragma unroll
      for (int kit = 0; kit < 2; ++kit) {
#pragma unroll
        for (int nt = 0; nt < 4; ++nt) {
          const f16x8 bh = uFh[kit * 4 + nt];
          const f16x8 bl = uFl[kit * 4 + nt];
          f32x4 s = S[p * 4 + nt];
          s = __builtin_amdgcn_mfma_f32_16x16x32_f16(uah[kit].v, bh, s, 0, 0, 0);
          s = __builtin_amdgcn_mfma_f32_16x16x32_f16(uah[kit].v, bl, s, 0, 0, 0);
          s = __builtin_amdgcn_mfma_f32_16x16x32_f16(ual[kit].v, bh, s, 0, 0, 0);
          S[p * 4 + nt] = s;
        }
      }
      if (p == 0) {
        *(f16x8*)&R1.kt[1].h[wix]     = kh1a;
        *(f16x8*)&R1.kt[1].h[wix + 8] = kh1b;
        *(f16x8*)&R1.kt[1].l[wix]     = kl1a;
        *(f16x8*)&R1.kt[1].l[wix + 8] = kl1b;
        __syncthreads();
      } else if (p == 1) {
        *(f16x8*)&R1.kt[0].h[wix]     = kh0a;
        *(f16x8*)&R1.kt[0].h[wix + 8] = kh0b;
        *(f16x8*)&R1.kt[0].l[wix]     = kl0a;
        *(f16x8*)&R1.kt[0].l[wix + 8] = kl0b;
        __syncthreads();
      } else if (p == 2) {
        *(f16x8*)&R1.kt[1].h[wix]     = kh1a;
        *(f16x8*)&R1.kt[1].h[wix + 8] = kh1b;
        *(f16x8*)&R1.kt[1].l[wix]     = kl1a;
        *(f16x8*)&R1.kt[1].l[wix + 8] = kl1b;
        __syncthreads();
      }
    }
    // p=3 reads finish before next chunk's B0 rewrites Reg1
  }

  // ---- readout: c[col] = sum_rows S[row][col] * k_last[row]
  float part[4] = {0.f, 0.f, 0.f, 0.f};
  const size_t lastoff = (size_t)(kL - 1) * 256;
#pragma unroll
  for (int p = 0; p < 4; ++p) {
    float klr[4];
#pragma unroll
    for (int r = 0; r < 4; ++r) {
      const int row = p * 64 + wv * 16 + quad * 4 + r;
      klr[r] = (float)Kh[lastoff + row] + (float)Kl[lastoff + row];
    }
#pragma unroll
    for (int nt = 0; nt < 4; ++nt)
#pragma unroll
      for (int r = 0; r < 4; ++r) part[nt] += S[p * 4 + nt][r] * klr[r];
  }
#pragma unroll
  for (int nt = 0; nt < 4; ++nt) {
    part[nt] += __shfl_xor(part[nt], 16);
    part[nt] += __shfl_xor(part[nt], 32);
  }
  __syncthreads();   // all prior LDS reads done before cred aliases Gm
  if (lane < 16) {
#pragma unroll
    for (int nt = 0; nt < 4; ++nt) R2.cred[wv][nt * 16 + l15] = part[nt];
  }
  __syncthreads();
  if (tid < 64) {
    const float c = R2.cred[0][tid] + R2.cred[1][tid] + R2.cred[2][tid] + R2.cred[3][tid];
    c_out[(size_t)b * 512 + mat * 256 + j0 + tid] = c;
  }
}

// ---------------- output GEMM: (64 x 512) @ (512 x 32000) + out_b -> fp32
__global__ __launch_bounds__(256) void out_gemm(
    const float* __restrict__ A, const float* __restrict__ Bm,
    const float* __restrict__ bias, float* __restrict__ C)
{
  __shared__ float As[16][64];
  __shared__ float Bs[16][128];
  const int tid = threadIdx.x;
  const int bn0 = blockIdx.x * 128;
  const int tm = tid >> 4, tn = tid & 15;
  float acc[4][8];
#pragma unroll
  for (int i = 0; i < 4; ++i)
#pragma unroll
    for (int j = 0; j < 8; ++j) acc[i][j] = 0.f;

  const int am  = tid & 63;
  const int ak  = (tid >> 6) * 4;
  const int bkr = tid >> 5;
  const int bcg = (tid & 31) * 4;

  for (int k0 = 0; k0 < kH; k0 += 16) {
    const float4 a0 = *(const float4*)(A + (size_t)am * kH + k0 + ak);
    const float4 b0 = *(const float4*)(Bm + (size_t)(k0 + bkr) * kV + bn0 + bcg);
    const float4 b1 = *(const float4*)(Bm + (size_t)(k0 + bkr + 8) * kV + bn0 + bcg);
    __syncthreads();
    As[ak + 0][am] = a0.x; As[ak + 1][am] = a0.y;
    As[ak + 2][am] = a0.z; As[ak + 3][am] = a0.w;
    *(float4*)&Bs[bkr][bcg]     = b0;
    *(float4*)&Bs[bkr + 8][bcg] = b1;
    __syncthreads();
#pragma unroll
    for (int kk = 0; kk < 16; ++kk) {
      const float4 aA = *(const float4*)&As[kk][tm * 4];
      const float4 bA = *(const float4*)&Bs[kk][tn * 4];
      const float4 bB = *(const float4*)&Bs[kk][64 + tn * 4];
      const float av[4] = {aA.x, aA.y, aA.z, aA.w};
      const float bv[8] = {bA.x, bA.y, bA.z, bA.w, bB.x, bB.y, bB.z, bB.w};
#pragma unroll
      for (int i = 0; i < 4; ++i)
#pragma unroll
        for (int j = 0; j < 8; ++j) acc[i][j] += av[i] * bv[j];
    }
  }

#pragma unroll
  for (int i = 0; i < 4; ++i) {
    const int row = tm * 4 + i;
#pragma unroll
    for (int hh = 0; hh < 2; ++hh) {
      const int n0 = bn0 + tn * 4 + hh * 64;
      const float4 bb = *(const float4*)(bias + n0);
      float4 o;
      o.x = acc[i][hh * 4 + 0] + bb.x;
      o.y = acc[i][hh * 4 + 1] + bb.y;
      o.z = acc[i][hh * 4 + 2] + bb.z;
      o.w = acc[i][hh * 4 + 3] + bb.w;
      *(float4*)(C + (size_t)row * kV + n0) = o;
    }
  }
}

}  // namespace

extern "C" void kernel_launch(void* const* d_in, const int* in_sizes, int n_in,
                              void* d_out, int out_size, void* d_ws, size_t ws_size,
                              hipStream_t stream)
{
  const int*   seq     = (const int*)  d_in[0];
  const float* embed   = (const float*)d_in[1];
  const float* w1      = (const float*)d_in[2];
  const float* b1      = (const float*)d_in[3];
  const float* w2      = (const float*)d_in[4];
  const float* b2      = (const float*)d_in[5];
  const float* ln_g    = (const float*)d_in[6];
  const float* ln_b    = (const float*)d_in[7];
  const float* sem_w   = (const float*)d_in[8];
  const float* sem_b   = (const float*)d_in[9];
  const float* epi_w   = (const float*)d_in[10];
  const float* epi_b   = (const float*)d_in[11];
  const float* out_w   = (const float*)d_in[12];
  const float* out_b   = (const float*)d_in[13];
  const float* pos_emb = (const float*)d_in[14];
  const float* pos_w   = (const float*)d_in[15];
  const float* pos_b   = (const float*)d_in[16];
  float* out = (float*)d_out;

  // chunk size: 16384 needs ~231 MB of ws; fall back to 8192 if tight.
  // ws_size is constant per process -> deterministic, graph-capture-safe.
  const int chunkN = (ws_size >= (size_t)240500000) ? 16384 : 8192;
  const int nch    = kTok / chunkN;

  char* p = (char*)d_ws;
  _Float16* w1th = (_Float16*)p; p += (size_t)1024 * 512 * 2;
  _Float16* w1tl = (_Float16*)p; p += (size_t)1024 * 512 * 2;
  _Float16* w2th = (_Float16*)p; p += (size_t)512 * 1024 * 2;
  _Float16* w2tl = (_Float16*)p; p += (size_t)512 * 1024 * 2;
  _Float16* wseh = (_Float16*)p; p += (size_t)512 * 512 * 2;
  _Float16* wsel = (_Float16*)p; p += (size_t)512 * 512 * 2;
  _Float16* t1h  = (_Float16*)p; p += (size_t)chunkN * 1024 * 2;
  _Float16* t1l  = (_Float16*)p; p += (size_t)chunkN * 1024 * 2;
  float*    x    = (float*)p;    p += (size_t)chunkN * kH * 4;
  _Float16* khs  = (_Float16*)p; p += (size_t)kTok * kHalf * 2;   // K hi/lo fp16
  _Float16* kls  = (_Float16*)p; p += (size_t)kTok * kHalf * 2;
  _Float16* khe  = (_Float16*)p; p += (size_t)kTok * kHalf * 2;
  _Float16* kle  = (_Float16*)p; p += (size_t)kTok * kHalf * 2;
  float*    wts  = (float*)p;    p += (size_t)kL * 4;
  float*    cout_= (float*)p;    p += (size_t)kB * 512 * 4;
  float*    ssqp = (float*)p;    p += (size_t)2 * kTok * 4 * 4;   // [mat][tok][4] partials
  _Float16* hh   = t1h;          // alias: t1 dead once x is written
  _Float16* hl   = t1l;

  pos_kernel<<<dim3((kL + 255) / 256), dim3(256), 0, stream>>>(pos_emb, pos_w, pos_b, wts);
  transpose_split<<<dim3(1024 * 512 / 256), dim3(256), 0, stream>>>(w1, w1th, w1tl, 1024, 9);
  transpose_split<<<dim3(512 * 1024 / 256), dim3(256), 0, stream>>>(w2, w2th, w2tl, 512, 10);
  transpose_split<<<dim3(256 * 512 / 256), dim3(256), 0, stream>>>(sem_w, wseh, wsel, 256, 9);
  transpose_split<<<dim3(256 * 512 / 256), dim3(256), 0, stream>>>(
      epi_w, wseh + (size_t)256 * 512, wsel + (size_t)256 * 512, 256, 9);

  for (int c = 0; c < nch; ++c) {
    const int tok0 = c * chunkN;
    hgemm<0><<<dim3(1024 / 128, chunkN / 128), dim3(256), 0, stream>>>(
        seq, embed, nullptr, nullptr, w1th, w1tl, b1, nullptr,
        nullptr, t1h, t1l, nullptr, nullptr, 512, 1024, tok0);
    hgemm<1><<<dim3(512 / 128, chunkN / 128), dim3(256), 0, stream>>>(
        seq, embed, t1h, t1l, w2th, w2tl, b2, nullptr,
        x, nullptr, nullptr, nullptr, nullptr, 1024, 512, tok0);
    ln_split<<<dim3(chunkN / 4), dim3(256), 0, stream>>>(x, ln_g, ln_b, hh, hl);
    hgemm<2><<<dim3(512 / 128, chunkN / 128), dim3(256), 0, stream>>>(
        seq, embed, hh, hl, wseh, wsel, sem_b, epi_b,
        ssqp, kls, kle, (float*)khs, (float*)khe,
        512, 512, tok0);
  }

  scan_chunked<<<dim3(512), dim3(256), 0, stream>>>(khs, kls, khe, kle, ssqp, wts, cout_);
  out_gemm<<<dim3(kV / 128), dim3(256), 0, stream>>>(cout_, out_w, out_b, out);

  (void)in_sizes; (void)n_in; (void)out_size;
}

// Round 4
// 1559.075 us; speedup vs baseline: 1.1418x; 1.0403x over previous
//
#include <hip/hip_runtime.h>
#include <hip/hip_bf16.h>
#include <math.h>

namespace {

constexpr int kH     = 512;
constexpr int kL     = 1024;
constexpr int kB     = 64;
constexpr int kHalf  = 256;
constexpr int kV     = 32000;
constexpr int kTok   = kB * kL;     // 65536

using f32x4 = __attribute__((ext_vector_type(4))) float;
using f16x8 = __attribute__((ext_vector_type(8))) _Float16;

__device__ inline void fsplit(float v, _Float16& h, _Float16& l) {
  h = (_Float16)v;
  l = (_Float16)(v - (float)h);
}

// Gm float [64][64] XOR swizzle (2-way per 16-lane phase on writes; solve reads broadcast)
__device__ inline int gmidx(int r, int c) { return r * 64 + (c ^ ((r & 7) << 2)); }

// ---------------- positional weights
__global__ void pos_kernel(const float* __restrict__ pos_emb,
                           const float* __restrict__ pos_w,
                           const float* __restrict__ pos_b,
                           float* __restrict__ wts)
{
  int t = blockIdx.x * blockDim.x + threadIdx.x;
  if (t >= kL) return;
  float z = pos_b[0];
#pragma unroll
  for (int p = 0; p < 16; ++p) z += pos_emb[t * 16 + p] * pos_w[p];
  wts[t] = 1.f / (1.f + expf(-z));
}

// ---------------- transpose + hi/lo fp16 split: W[K][N] fp32 -> Th/Tl[N][K]
__global__ __launch_bounds__(256) void transpose_split(
    const float* __restrict__ W, _Float16* __restrict__ Th,
    _Float16* __restrict__ Tl, int N, int kshift)
{
  const int idx = blockIdx.x * 256 + threadIdx.x;
  const int K = 1 << kshift;
  const int k = idx & (K - 1);
  const int n = idx >> kshift;
  const float w = W[(size_t)k * N + n];
  const _Float16 h = (_Float16)w;
  Th[idx] = h;
  Tl[idx] = (_Float16)(w - (float)h);
}

// ---------------- split-fp16 MFMA GEMM: C[M,N] = A[M,K] @ (Bh+Bl)[N,K]^T
template <int EPI>
__global__ __launch_bounds__(256) void hgemm(
    const int* __restrict__ seq, const float* __restrict__ embed,
    const _Float16* __restrict__ Ah, const _Float16* __restrict__ Al,
    const _Float16* __restrict__ Bh, const _Float16* __restrict__ Bl,
    const float* __restrict__ bias, const float* __restrict__ bias2,
    float* __restrict__ Xout, _Float16* __restrict__ Oh, _Float16* __restrict__ Ol,
    float* __restrict__ ks, float* __restrict__ ke,
    int K, int N, int tok0c)
{
  __shared__ _Float16 lds[4][128][40];   // Ahi, Alo, Bhi, Blo; +8 pad (80B stride)
  const int tid  = threadIdx.x;
  const int lane = tid & 63;
  const int wv   = tid >> 6;
  const int wm   = (wv >> 1) * 64;
  const int wn   = (wv & 1) * 64;
  const int bm0  = blockIdx.y * 128;
  const int bn0  = blockIdx.x * 128;

  f32x4 acc[4][4];
#pragma unroll
  for (int i = 0; i < 4; ++i)
#pragma unroll
    for (int j = 0; j < 4; ++j) acc[i][j] = {0.f, 0.f, 0.f, 0.f};

  const int sr = tid >> 1;            // staging row 0..127
  const int sc = (tid & 1) << 4;      // 0 or 16 (halves)
  const _Float16* gBh = Bh + (size_t)(bn0 + sr) * K + sc;
  const _Float16* gBl = Bl + (size_t)(bn0 + sr) * K + sc;
  const _Float16* gAh = nullptr;
  const _Float16* gAl = nullptr;
  const float*    gAe = nullptr;
  if constexpr (EPI == 0) {
    const int tokrow = seq[tok0c + bm0 + sr];
    gAe = embed + (size_t)tokrow * kH + sc;
  } else {
    gAh = Ah + (size_t)(bm0 + sr) * K + sc;
    gAl = Al + (size_t)(bm0 + sr) * K + sc;
  }

  const int lrow = lane & 15;
  const int lk   = (lane >> 4) * 8;

  for (int k0 = 0; k0 < K; k0 += 32) {
    const uint4 vC0 = *(const uint4*)(gBh + k0);
    const uint4 vC1 = *(const uint4*)(gBh + k0 + 8);
    const uint4 vD0 = *(const uint4*)(gBl + k0);
    const uint4 vD1 = *(const uint4*)(gBl + k0 + 8);
    if constexpr (EPI == 0) {
      const float4 a0 = *(const float4*)(gAe + k0);
      const float4 a1 = *(const float4*)(gAe + k0 + 4);
      const float4 a2 = *(const float4*)(gAe + k0 + 8);
      const float4 a3 = *(const float4*)(gAe + k0 + 12);
      const float vv[16] = {a0.x,a0.y,a0.z,a0.w, a1.x,a1.y,a1.z,a1.w,
                            a2.x,a2.y,a2.z,a2.w, a3.x,a3.y,a3.z,a3.w};
      union { _Float16 h[16]; uint4 u[2]; } ph, pl;
#pragma unroll
      for (int i = 0; i < 16; ++i) fsplit(vv[i], ph.h[i], pl.h[i]);
      __syncthreads();
      *(uint4*)&lds[0][sr][sc]     = ph.u[0];
      *(uint4*)&lds[0][sr][sc + 8] = ph.u[1];
      *(uint4*)&lds[1][sr][sc]     = pl.u[0];
      *(uint4*)&lds[1][sr][sc + 8] = pl.u[1];
    } else {
      const uint4 vA0 = *(const uint4*)(gAh + k0);
      const uint4 vA1 = *(const uint4*)(gAh + k0 + 8);
      const uint4 vB0 = *(const uint4*)(gAl + k0);
      const uint4 vB1 = *(const uint4*)(gAl + k0 + 8);
      __syncthreads();
      *(uint4*)&lds[0][sr][sc]     = vA0;
      *(uint4*)&lds[0][sr][sc + 8] = vA1;
      *(uint4*)&lds[1][sr][sc]     = vB0;
      *(uint4*)&lds[1][sr][sc + 8] = vB1;
    }
    *(uint4*)&lds[2][sr][sc]     = vC0;
    *(uint4*)&lds[2][sr][sc + 8] = vC1;
    *(uint4*)&lds[3][sr][sc]     = vD0;
    *(uint4*)&lds[3][sr][sc + 8] = vD1;
    __syncthreads();

    f16x8 fBh[4], fBl[4];
#pragma unroll
    for (int ni = 0; ni < 4; ++ni) {
      fBh[ni] = *(const f16x8*)&lds[2][wn + ni * 16 + lrow][lk];
      fBl[ni] = *(const f16x8*)&lds[3][wn + ni * 16 + lrow][lk];
    }
#pragma unroll
    for (int mi = 0; mi < 4; ++mi) {
      const f16x8 ah = *(const f16x8*)&lds[0][wm + mi * 16 + lrow][lk];
      const f16x8 al = *(const f16x8*)&lds[1][wm + mi * 16 + lrow][lk];
#pragma unroll
      for (int ni = 0; ni < 4; ++ni) {
        acc[mi][ni] = __builtin_amdgcn_mfma_f32_16x16x32_f16(ah, fBh[ni], acc[mi][ni], 0, 0, 0);
        acc[mi][ni] = __builtin_amdgcn_mfma_f32_16x16x32_f16(ah, fBl[ni], acc[mi][ni], 0, 0, 0);
        acc[mi][ni] = __builtin_amdgcn_mfma_f32_16x16x32_f16(al, fBh[ni], acc[mi][ni], 0, 0, 0);
      }
    }
  }

  const int erow0 = (lane >> 4) * 4;
  if constexpr (EPI == 0) {
#pragma unroll
    for (int mi = 0; mi < 4; ++mi)
#pragma unroll
      for (int ni = 0; ni < 4; ++ni) {
        const int gn = bn0 + wn + ni * 16 + (lane & 15);
        const float bv = bias[gn];
#pragma unroll
        for (int r = 0; r < 4; ++r) {
          const int gm = bm0 + wm + mi * 16 + erow0 + r;
          float v = fmaxf(acc[mi][ni][r] + bv, 0.f);
          const _Float16 h = (_Float16)v;
          Oh[(size_t)gm * N + gn] = h;
          Ol[(size_t)gm * N + gn] = (_Float16)(v - (float)h);
        }
      }
  } else if constexpr (EPI == 1) {
#pragma unroll
    for (int mi = 0; mi < 4; ++mi)
#pragma unroll
      for (int r = 0; r < 4; ++r) {
        const int gm = bm0 + wm + mi * 16 + erow0 + r;
        const int tok = seq[tok0c + gm];
        const float* er = embed + (size_t)tok * kH;
#pragma unroll
        for (int ni = 0; ni < 4; ++ni) {
          const int gn = bn0 + wn + ni * 16 + (lane & 15);
          Xout[(size_t)gm * N + gn] = acc[mi][ni][r] + bias[gn] + er[gn];
        }
      }
  } else {
    // EPI==2: write K as fp16 hi/lo pairs + per-quarter ssq partials (Xout).
    _Float16* kh_s = (_Float16*)ks;
    _Float16* kh_e = (_Float16*)ke;
    float s2[4][4];
#pragma unroll
    for (int mi = 0; mi < 4; ++mi)
#pragma unroll
      for (int r = 0; r < 4; ++r) s2[mi][r] = 0.f;
#pragma unroll
    for (int mi = 0; mi < 4; ++mi)
#pragma unroll
      for (int ni = 0; ni < 4; ++ni) {
        const int gn = bn0 + wn + ni * 16 + (lane & 15);
        const float bv = (gn < 256) ? bias[gn] : bias2[gn - 256];
        _Float16* Dh = (gn < 256) ? kh_s : kh_e;
        _Float16* Dl = (gn < 256) ? Oh : Ol;
        const int col = gn & 255;
#pragma unroll
        for (int r = 0; r < 4; ++r) {
          const int gm = bm0 + wm + mi * 16 + erow0 + r;
          const float v = acc[mi][ni][r] + bv;
          s2[mi][r] += v * v;
          _Float16 h, l;
          fsplit(v, h, l);
          Dh[(size_t)(tok0c + gm) * 256 + col] = h;
          Dl[(size_t)(tok0c + gm) * 256 + col] = l;
        }
      }
    // deterministic per-quarter partial sums: ssqPart[mat][tok][half*2 + (wv&1)]
    const int matq  = bn0 >> 8;
    const int halfq = (bn0 >> 7) & 1;
#pragma unroll
    for (int mi = 0; mi < 4; ++mi)
#pragma unroll
      for (int r = 0; r < 4; ++r) {
        float s2v = s2[mi][r];
        s2v += __shfl_xor(s2v, 1);
        s2v += __shfl_xor(s2v, 2);
        s2v += __shfl_xor(s2v, 4);
        s2v += __shfl_xor(s2v, 8);
        if ((lane & 15) == 0) {
          const int gm = bm0 + wm + mi * 16 + erow0 + r;
          Xout[((size_t)matq * kTok + (size_t)(tok0c + gm)) * 4 + halfq * 2 + (wv & 1)] = s2v;
        }
      }
  }
}

// ---------------- LayerNorm: x fp32 -> hi/lo fp16
__global__ __launch_bounds__(256) void ln_split(
    const float* __restrict__ x, const float* __restrict__ g,
    const float* __restrict__ bta, _Float16* __restrict__ hh,
    _Float16* __restrict__ hl)
{
  const int wid  = threadIdx.x >> 6;
  const int lane = threadIdx.x & 63;
  const int ltok = blockIdx.x * 4 + wid;
  const float* xp = x + (size_t)ltok * kH;
  const float4 v0 = *(const float4*)(xp + lane * 8);
  const float4 v1 = *(const float4*)(xp + lane * 8 + 4);
  float s  = v0.x + v0.y + v0.z + v0.w + v1.x + v1.y + v1.z + v1.w;
  float ss = v0.x * v0.x + v0.y * v0.y + v0.z * v0.z + v0.w * v0.w +
             v1.x * v1.x + v1.y * v1.y + v1.z * v1.z + v1.w * v1.w;
#pragma unroll
  for (int m = 1; m < 64; m <<= 1) { s += __shfl_xor(s, m); ss += __shfl_xor(ss, m); }
  const float mu  = s * (1.f / kH);
  const float var = ss * (1.f / kH) - mu * mu;
  const float rs  = 1.f / sqrtf(var + 1e-5f);
  const float4 g0 = *(const float4*)(g + lane * 8);
  const float4 g1 = *(const float4*)(g + lane * 8 + 4);
  const float4 b0 = *(const float4*)(bta + lane * 8);
  const float4 b1 = *(const float4*)(bta + lane * 8 + 4);
  const float vv[8] = {v0.x, v0.y, v0.z, v0.w, v1.x, v1.y, v1.z, v1.w};
  const float gg[8] = {g0.x, g0.y, g0.z, g0.w, g1.x, g1.y, g1.z, g1.w};
  const float bb[8] = {b0.x, b0.y, b0.z, b0.w, b1.x, b1.y, b1.z, b1.w};
  union { _Float16 h[8]; uint4 u; } ph, pl;
#pragma unroll
  for (int i = 0; i < 8; ++i) {
    const float o = (vv[i] - mu) * rs * gg[i] + bb[i];
    fsplit(o, ph.h[i], pl.h[i]);
  }
  *(uint4*)(hh + (size_t)ltok * kH + lane * 8) = ph.u;
  *(uint4*)(hl + (size_t)ltok * kH + lane * 8) = pl.u;
}

// ---------------- chunked WY delta-rule scan (v8).
// v8 vs v7: spill-free register budget (2-deep staging only: one K panel in
// flight for the ring, one kt panel in flight; U B-fragments re-read per
// panel from LDS instead of a 64-reg hoist) + XCD-affinity blockIdx remap
// (the 4 quarter-WGs of one (b,mat) share wg%8 -> same XCD L2, so K is
// HBM-fetched once per (b,mat) pass instead of 4x). Keeps v7's stride-72
// tiles, precomputed ssq, and cooperative solve.
struct RingT { _Float16 h[2][4608], l[2][4608]; };        // 36864 B
union Reg1 {
  RingT ring;
  struct { float m[64][66]; } r;                          // Rr residual 16896 B
  struct { _Float16 h[4608], l[4608]; } kt[2];            // K^T subtiles 36864 B
};
struct STile { _Float16 h[4608], l[4608]; };              // 18432 B
union Reg2 { STile s; float Gm[64 * 64]; float cred[4][64]; };
union Reg3 { STile s; struct { _Float16 Uh[4608], Ul[4608]; } u; };

__global__ __launch_bounds__(256, 2) void scan_chunked(
    const _Float16* __restrict__ khs, const _Float16* __restrict__ kls,
    const _Float16* __restrict__ khe, const _Float16* __restrict__ kle,
    const float* __restrict__ ssqP, const float* __restrict__ wts,
    float* __restrict__ c_out)
{
  __shared__ Reg1 R1;
  __shared__ Reg2 R2;
  __shared__ Reg3 R3;
  __shared__ float ubS[2][64][12];   // solve ub broadcast, dbuf (6144 B)
  __shared__ float aS[64], wS[64];

  const int tid  = threadIdx.x;
  const int lane = tid & 63;
  const int wv   = tid >> 6;
  const int l15  = lane & 15;
  const int quad = lane >> 4;
  // XCD-affinity decode (bijective): quarters q=0..3 of one (b,mat) get
  // wg values differing by 8 -> same wg%8 -> same XCD under round-robin.
  const int wg   = blockIdx.x;
  const int grp  = (wg & 7) + ((wg >> 5) << 3);   // 0..127
  const int q    = (wg >> 3) & 3;
  const int b    = grp >> 1;
  const int mat  = grp & 1;
  const int j0   = q * 64;
  const _Float16* Kh = (mat ? khe : khs) + (size_t)b * (1024 * 256);
  const _Float16* Kl = (mat ? kle : kls) + (size_t)b * (1024 * 256);

  // S[p*4+nt]: rows p*64 + wv*16 + quad*4 + r ; cols nt*16 + l15 (WG-local j)
  f32x4 S[16];
#pragma unroll
  for (int i = 0; i < 16; ++i) S[i] = {0.f, 0.f, 0.f, 0.f};

  // ring staging mapping: row stk, 16-half col group dg
  const int stk = tid >> 2;          // 0..63
  const int dg  = (tid & 3) << 4;    // 0,16,32,48

  for (int ck = 0; ck < 16; ++ck) {
    const int tok0 = ck * 64;

    __syncthreads();   // B0: prev chunk kt/U/Gm readers done; regions writable

    // aS/wS from precomputed ssq partials (tiny; consumed at solve)
    if (tid < 64) {
      const float4 sq = *(const float4*)(
          ssqP + ((size_t)mat * kTok + (size_t)b * 1024 + tok0 + tid) * 4);
      const float w = mat ? wts[tok0 + tid] : 1.f;
      wS[tid] = w;
      aS[tid] = w / (sq.x + sq.y + sq.z + sq.w + 1e-6f);
    }

    // issue K panel-0 staging loads (one panel in flight — spill-safe)
    const _Float16* gh = Kh + (size_t)(tok0 + stk) * 256 + dg;
    const _Float16* gl = Kl + (size_t)(tok0 + stk) * 256 + dg;
    uint4 ph0 = *(const uint4*)(gh);
    uint4 ph1 = *(const uint4*)(gh + 8);
    uint4 pl0 = *(const uint4*)(gl);
    uint4 pl1 = *(const uint4*)(gl + 8);

    // stage S^T panel 0 into R2 (even buffer)
#pragma unroll
    for (int nt = 0; nt < 4; ++nt) {
      const f32x4 v = S[0 * 4 + nt];
      union { _Float16 h[4]; uint2 u; } qh, ql;
#pragma unroll
      for (int r = 0; r < 4; ++r) fsplit(v[r], qh.h[r], ql.h[r]);
      const int ix = (nt * 16 + l15) * 72 + wv * 16 + quad * 4;
      *(uint2*)&R2.s.h[ix] = qh.u;
      *(uint2*)&R2.s.l[ix] = ql.u;
    }
    // write ring panel 0
    const int wb = stk * 72 + dg;
    *(uint4*)&R1.ring.h[0][wb]     = ph0;
    *(uint4*)&R1.ring.h[0][wb + 8] = ph1;
    *(uint4*)&R1.ring.l[0][wb]     = pl0;
    *(uint4*)&R1.ring.l[0][wb + 8] = pl1;
    __syncthreads();   // B1

    f32x4 Qa[4], Ga[4];
#pragma unroll
    for (int i = 0; i < 4; ++i) { Qa[i] = {0.f,0.f,0.f,0.f}; Ga[i] = {0.f,0.f,0.f,0.f}; }

#pragma unroll
    for (int p = 0; p < 4; ++p) {
      const int cur = p & 1;
      const _Float16* sh = cur ? R3.s.h : R2.s.h;
      const _Float16* sl = cur ? R3.s.l : R2.s.l;
      _Float16* nh = cur ? R2.s.h : R3.s.h;
      _Float16* nl = cur ? R2.s.l : R3.s.l;

      uint4 qh0, qh1, ql0, ql1;
      if (p < 3) {
        // issue next K panel loads early (L2-resident via XCD affinity)
        qh0 = *(const uint4*)(gh + (p + 1) * 64);
        qh1 = *(const uint4*)(gh + (p + 1) * 64 + 8);
        ql0 = *(const uint4*)(gl + (p + 1) * 64);
        ql1 = *(const uint4*)(gl + (p + 1) * 64 + 8);
        // stage next S^T panel (buffer's readers done at prev barrier)
#pragma unroll
        for (int nt = 0; nt < 4; ++nt) {
          const f32x4 v = S[(p + 1) * 4 + nt];
          union { _Float16 h[4]; uint2 u; } sqh, sql;
#pragma unroll
          for (int r = 0; r < 4; ++r) fsplit(v[r], sqh.h[r], sql.h[r]);
          const int ix = (nt * 16 + l15) * 72 + wv * 16 + quad * 4;
          *(uint2*)&nh[ix] = sqh.u;
          *(uint2*)&nl[ix] = sql.u;
        }
      }

#pragma unroll
      for (int kit = 0; kit < 2; ++kit) {
        const int dim = kit * 32 + quad * 8;
        const f16x8 ah = *(const f16x8*)&R1.ring.h[cur][(wv * 16 + l15) * 72 + dim];
        const f16x8 al = *(const f16x8*)&R1.ring.l[cur][(wv * 16 + l15) * 72 + dim];
#pragma unroll
        for (int nt = 0; nt < 4; ++nt) {
          const int ix = (nt * 16 + l15) * 72 + dim;
          const f16x8 bh = *(const f16x8*)&sh[ix];
          const f16x8 bl = *(const f16x8*)&sl[ix];
          Qa[nt] = __builtin_amdgcn_mfma_f32_16x16x32_f16(ah, bh, Qa[nt], 0, 0, 0);
          Qa[nt] = __builtin_amdgcn_mfma_f32_16x16x32_f16(ah, bl, Qa[nt], 0, 0, 0);
          Qa[nt] = __builtin_amdgcn_mfma_f32_16x16x32_f16(al, bh, Qa[nt], 0, 0, 0);
        }
#pragma unroll
        for (int nt = 0; nt < 4; ++nt) {
          const int ix = (nt * 16 + l15) * 72 + dim;
          const f16x8 gb  = *(const f16x8*)&R1.ring.h[cur][ix];
          const f16x8 gl2 = *(const f16x8*)&R1.ring.l[cur][ix];
          Ga[nt] = __builtin_amdgcn_mfma_f32_16x16x32_f16(ah, gb, Ga[nt], 0, 0, 0);
          Ga[nt] = __builtin_amdgcn_mfma_f32_16x16x32_f16(ah, gl2, Ga[nt], 0, 0, 0);
          Ga[nt] = __builtin_amdgcn_mfma_f32_16x16x32_f16(al, gb, Ga[nt], 0, 0, 0);
        }
      }
      if (p < 3) {   // write next K panel into other ring buf
        *(uint4*)&R1.ring.h[1 - cur][wb]     = qh0;
        *(uint4*)&R1.ring.h[1 - cur][wb + 8] = qh1;
        *(uint4*)&R1.ring.l[1 - cur][wb]     = ql0;
        *(uint4*)&R1.ring.l[1 - cur][wb + 8] = ql1;
      }
      __syncthreads();   // end of panel p
    }

    // ---- writeback: Q -> Rr[t][j] (aliases ring), G -> Gm (aliases S^T even)
#pragma unroll
    for (int nt = 0; nt < 4; ++nt) {
#pragma unroll
      for (int r = 0; r < 4; ++r)
        R1.r.m[wv * 16 + quad * 4 + r][nt * 16 + l15] = Qa[nt][r];
      *(float4*)&R2.Gm[gmidx(nt * 16 + l15, wv * 16 + quad * 4)] = *(const float4*)&Ga[nt];
    }

    // issue kt panel 0 into named regs (land under the solve)
    const _Float16* ktsrc_h = Kh + (size_t)(tok0 + lane) * 256 + wv * 16;
    const _Float16* ktsrc_l = Kl + (size_t)(tok0 + lane) * 256 + wv * 16;
    f16x8 kh0a = *(const f16x8*)(ktsrc_h);
    f16x8 kh0b = *(const f16x8*)(ktsrc_h + 8);
    f16x8 kl0a = *(const f16x8*)(ktsrc_l);
    f16x8 kl0b = *(const f16x8*)(ktsrc_l + 8);

    // wave0: preload solve kv for block 0
    float kvh[8], kvl[8];
    if (wv == 0) {
#pragma unroll
      for (int i = 0; i < 8; ++i) {
        const size_t go = (size_t)(tok0 + i) * 256 + j0 + lane;
        kvh[i] = (float)Kh[go];
        kvl[i] = (float)Kl[go];
      }
    }
    __syncthreads();   // B4: Rr/Gm/aS/wS visible

    // ---- cooperative blocked triangular solve
    float ubPrev[8];
    for (int blk = 0; blk < 8; ++blk) {
      const int t0 = blk * 8;
      if (wv == 0) {
        __builtin_amdgcn_s_setprio(1);
        float rl_[8], kv[8], ub[8];
#pragma unroll
        for (int i = 0; i < 8; ++i) kv[i] = kvh[i] + kvl[i];
        if (blk < 7) {   // software-pipeline next block's kv loads
#pragma unroll
          for (int i = 0; i < 8; ++i) {
            const size_t go = (size_t)(tok0 + t0 + 8 + i) * 256 + j0 + lane;
            kvh[i] = (float)Kh[go];
            kvl[i] = (float)Kl[go];
          }
        }
#pragma unroll
        for (int i = 0; i < 8; ++i) rl_[i] = R1.r.m[t0 + i][lane];
#pragma unroll
        for (int i = 0; i < 8; ++i) {
          const int t = t0 + i;
          float u = wS[t] * kv[i] - aS[t] * rl_[i];
          if (ck == 15 && t == 63) u = 0.f;   // token L-1 is the query only
          ub[i] = u;
#pragma unroll
          for (int i2 = i + 1; i2 < 8; ++i2)
            rl_[i2] += R2.Gm[gmidx(t0 + i2, t)] * u;
        }
        // publish ub (fp16 hi/lo U, and fp32 broadcast for far waves)
        union { _Float16 h[8]; uint4 u4; } uh, ul;
#pragma unroll
        for (int i = 0; i < 8; ++i) fsplit(ub[i], uh.h[i], ul.h[i]);
        *(uint4*)&R3.u.Uh[lane * 72 + t0] = uh.u4;
        *(uint4*)&R3.u.Ul[lane * 72 + t0] = ul.u4;
        float4 ub0 = {ub[0], ub[1], ub[2], ub[3]};
        float4 ub1 = {ub[4], ub[5], ub[6], ub[7]};
        *(float4*)&ubS[blk & 1][lane][0] = ub0;
        *(float4*)&ubS[blk & 1][lane][4] = ub1;
        // near-update: rows [t0+8, t0+16) get ub[blk-1] then ub[blk]
        if (blk < 7) {
          const int t0p = t0 - 8;
#pragma unroll
          for (int r2 = 0; r2 < 8; ++r2) {
            const int t2 = t0 + 8 + r2;
            float acc = R1.r.m[t2][lane];
            if (blk > 0) {
              const float4 g0 = *(const float4*)&R2.Gm[gmidx(t2, t0p)];
              const float4 g1 = *(const float4*)&R2.Gm[gmidx(t2, t0p + 4)];
              acc += g0.x*ubPrev[0] + g0.y*ubPrev[1] + g0.z*ubPrev[2] + g0.w*ubPrev[3]
                   + g1.x*ubPrev[4] + g1.y*ubPrev[5] + g1.z*ubPrev[6] + g1.w*ubPrev[7];
            }
            const float4 h0 = *(const float4*)&R2.Gm[gmidx(t2, t0)];
            const float4 h1 = *(const float4*)&R2.Gm[gmidx(t2, t0 + 4)];
            acc += h0.x*ub[0] + h0.y*ub[1] + h0.z*ub[2] + h0.w*ub[3]
                 + h1.x*ub[4] + h1.y*ub[5] + h1.z*ub[6] + h1.w*ub[7];
            R1.r.m[t2][lane] = acc;
          }
        }
#pragma unroll
        for (int i = 0; i < 8; ++i) ubPrev[i] = ub[i];
        __builtin_amdgcn_s_setprio(0);
      } else if (blk > 0) {
        // far-update: ub[blk-1] to rows [t0+16, 64), strided across waves 1..3
        const int t0p = t0 - 8;
        const float4 u0 = *(const float4*)&ubS[(blk - 1) & 1][lane][0];
        const float4 u1 = *(const float4*)&ubS[(blk - 1) & 1][lane][4];
        for (int t2 = t0 + 16 + (wv - 1); t2 < 64; t2 += 3) {
          const float4 g0 = *(const float4*)&R2.Gm[gmidx(t2, t0p)];
          const float4 g1 = *(const float4*)&R2.Gm[gmidx(t2, t0p + 4)];
          float acc = R1.r.m[t2][lane];
          acc += g0.x*u0.x + g0.y*u0.y + g0.z*u0.z + g0.w*u0.w
               + g1.x*u1.x + g1.y*u1.y + g1.z*u1.z + g1.w*u1.w;
          R1.r.m[t2][lane] = acc;
        }
      }
      __syncthreads();   // last iteration doubles as B5: Uh/Ul visible, Rr dead
    }

    // write kt panel 0 (ring/Rr region dead)
    const int wix = (wv * 16 + (lane >> 2)) * 72 + (lane & 3) * 16;
    *(f16x8*)&R1.kt[0].h[wix]     = kh0a;
    *(f16x8*)&R1.kt[0].h[wix + 8] = kh0b;
    *(f16x8*)&R1.kt[0].l[wix]     = kl0a;
    *(f16x8*)&R1.kt[0].l[wix + 8] = kl0b;
    __syncthreads();   // Bu0

    // ---- S += K^T U, panel by panel (2-deep staging, U frags from LDS)
#pragma unroll
    for (int p = 0; p < 4; ++p) {
      const int cur = p & 1;
      f16x8 n0h, n1h, n0l, n1l;
      if (p < 3) {   // issue next-panel loads early (T14 split)
        n0h = *(const f16x8*)(ktsrc_h + (p + 1) * 64);
        n1h = *(const f16x8*)(ktsrc_h + (p + 1) * 64 + 8);
        n0l = *(const f16x8*)(ktsrc_l + (p + 1) * 64);
        n1l = *(const f16x8*)(ktsrc_l + (p + 1) * 64 + 8);
      }
      union { _Float16 e[8]; f16x8 v; } uah[2], ual[2];
#pragma unroll
      for (int kit = 0; kit < 2; ++kit) {
        const int base = (wv * 16 + 8 * kit + 2 * quad) * 72 + l15;
#pragma unroll
        for (int jj = 0; jj < 8; ++jj) {
          const int off = (jj >> 2) * 72 + (jj & 3) * 16;
          uah[kit].e[jj] = R1.kt[cur].h[base + off];
          ual[kit].e[jj] = R1.kt[cur].l[base + off];
        }
      }
#pragma unroll
      for (int kit = 0; kit < 2; ++kit) {
        const int ko = kit * 32 + quad * 8;
#pragma unroll
        for (int nt = 0; nt < 4; ++nt) {
          const int ix = (nt * 16 + l15) * 72 + ko;
          const f16x8 bh = *(const f16x8*)&R3.u.Uh[ix];
          const f16x8 bl = *(const f16x8*)&R3.u.Ul[ix];
          f32x4 s = S[p * 4 + nt];
          s = __builtin_amdgcn_mfma_f32_16x16x32_f16(uah[kit].v, bh, s, 0, 0, 0);
          s = __builtin_amdgcn_mfma_f32_16x16x32_f16(uah[kit].v, bl, s, 0, 0, 0);
          s = __builtin_amdgcn_mfma_f32_16x16x32_f16(ual[kit].v, bh, s, 0, 0, 0);
          S[p * 4 + nt] = s;
        }
      }
      if (p < 3) {   // write next panel (buf safe: its readers done at prev barrier)
        *(f16x8*)&R1.kt[1 - cur].h[wix]     = n0h;
        *(f16x8*)&R1.kt[1 - cur].h[wix + 8] = n1h;
        *(f16x8*)&R1.kt[1 - cur].l[wix]     = n0l;
        *(f16x8*)&R1.kt[1 - cur].l[wix + 8] = n1l;
        __syncthreads();   // Bup
      }
    }
    // p=3 reads finish before next chunk's B0 rewrites Reg1
  }

  // ---- readout: c[col] = sum_rows S[row][col] * k_last[row]
  float part[4] = {0.f, 0.f, 0.f, 0.f};
  const size_t lastoff = (size_t)(kL - 1) * 256;
#pragma unroll
  for (int p = 0; p < 4; ++p) {
    float klr[4];
#pragma unroll
    for (int r = 0; r < 4; ++r) {
      const int row = p * 64 + wv * 16 + quad * 4 + r;
      klr[r] = (float)Kh[lastoff + row] + (float)Kl[lastoff + row];
    }
#pragma unroll
    for (int nt = 0; nt < 4; ++nt)
#pragma unroll
      for (int r = 0; r < 4; ++r) part[nt] += S[p * 4 + nt][r] * klr[r];
  }
#pragma unroll
  for (int nt = 0; nt < 4; ++nt) {
    part[nt] += __shfl_xor(part[nt], 16);
    part[nt] += __shfl_xor(part[nt], 32);
  }
  __syncthreads();   // all prior LDS reads done before cred aliases Gm
  if (lane < 16) {
#pragma unroll
    for (int nt = 0; nt < 4; ++nt) R2.cred[wv][nt * 16 + l15] = part[nt];
  }
  __syncthreads();
  if (tid < 64) {
    const float c = R2.cred[0][tid] + R2.cred[1][tid] + R2.cred[2][tid] + R2.cred[3][tid];
    c_out[(size_t)b * 512 + mat * 256 + j0 + tid] = c;
  }
}

// ---------------- output GEMM: (64 x 512) @ (512 x 32000) + out_b -> fp32
__global__ __launch_bounds__(256) void out_gemm(
    const float* __restrict__ A, const float* __restrict__ Bm,
    const float* __restrict__ bias, float* __restrict__ C)
{
  __shared__ float As[16][64];
  __shared__ float Bs[16][128];
  const int tid = threadIdx.x;
  const int bn0 = blockIdx.x * 128;
  const int tm = tid >> 4, tn = tid & 15;
  float acc[4][8];
#pragma unroll
  for (int i = 0; i < 4; ++i)
#pragma unroll
    for (int j = 0; j < 8; ++j) acc[i][j] = 0.f;

  const int am  = tid & 63;
  const int ak  = (tid >> 6) * 4;
  const int bkr = tid >> 5;
  const int bcg = (tid & 31) * 4;

  for (int k0 = 0; k0 < kH; k0 += 16) {
    const float4 a0 = *(const float4*)(A + (size_t)am * kH + k0 + ak);
    const float4 b0 = *(const float4*)(Bm + (size_t)(k0 + bkr) * kV + bn0 + bcg);
    const float4 b1 = *(const float4*)(Bm + (size_t)(k0 + bkr + 8) * kV + bn0 + bcg);
    __syncthreads();
    As[ak + 0][am] = a0.x; As[ak + 1][am] = a0.y;
    As[ak + 2][am] = a0.z; As[ak + 3][am] = a0.w;
    *(float4*)&Bs[bkr][bcg]     = b0;
    *(float4*)&Bs[bkr + 8][bcg] = b1;
    __syncthreads();
#pragma unroll
    for (int kk = 0; kk < 16; ++kk) {
      const float4 aA = *(const float4*)&As[kk][tm * 4];
      const float4 bA = *(const float4*)&Bs[kk][tn * 4];
      const float4 bB = *(const float4*)&Bs[kk][64 + tn * 4];
      const float av[4] = {aA.x, aA.y, aA.z, aA.w};
      const float bv[8] = {bA.x, bA.y, bA.z, bA.w, bB.x, bB.y, bB.z, bB.w};
#pragma unroll
      for (int i = 0; i < 4; ++i)
#pragma unroll
        for (int j = 0; j < 8; ++j) acc[i][j] += av[i] * bv[j];
    }
  }

#pragma unroll
  for (int i = 0; i < 4; ++i) {
    const int row = tm * 4 + i;
#pragma unroll
    for (int hh = 0; hh < 2; ++hh) {
      const int n0 = bn0 + tn * 4 + hh * 64;
      const float4 bb = *(const float4*)(bias + n0);
      float4 o;
      o.x = acc[i][hh * 4 + 0] + bb.x;
      o.y = acc[i][hh * 4 + 1] + bb.y;
      o.z = acc[i][hh * 4 + 2] + bb.z;
      o.w = acc[i][hh * 4 + 3] + bb.w;
      *(float4*)(C + (size_t)row * kV + n0) = o;
    }
  }
}

}  // namespace

extern "C" void kernel_launch(void* const* d_in, const int* in_sizes, int n_in,
                              void* d_out, int out_size, void* d_ws, size_t ws_size,
                              hipStream_t stream)
{
  const int*   seq     = (const int*)  d_in[0];
  const float* embed   = (const float*)d_in[1];
  const float* w1      = (const float*)d_in[2];
  const float* b1      = (const float*)d_in[3];
  const float* w2      = (const float*)d_in[4];
  const float* b2      = (const float*)d_in[5];
  const float* ln_g    = (const float*)d_in[6];
  const float* ln_b    = (const float*)d_in[7];
  const float* sem_w   = (const float*)d_in[8];
  const float* sem_b   = (const float*)d_in[9];
  const float* epi_w   = (const float*)d_in[10];
  const float* epi_b   = (const float*)d_in[11];
  const float* out_w   = (const float*)d_in[12];
  const float* out_b   = (const float*)d_in[13];
  const float* pos_emb = (const float*)d_in[14];
  const float* pos_w   = (const float*)d_in[15];
  const float* pos_b   = (const float*)d_in[16];
  float* out = (float*)d_out;

  // chunk size: 16384 needs ~231 MB of ws; fall back to 8192 if tight.
  // ws_size is constant per process -> deterministic, graph-capture-safe.
  const int chunkN = (ws_size >= (size_t)240500000) ? 16384 : 8192;
  const int nch    = kTok / chunkN;

  char* p = (char*)d_ws;
  _Float16* w1th = (_Float16*)p; p += (size_t)1024 * 512 * 2;
  _Float16* w1tl = (_Float16*)p; p += (size_t)1024 * 512 * 2;
  _Float16* w2th = (_Float16*)p; p += (size_t)512 * 1024 * 2;
  _Float16* w2tl = (_Float16*)p; p += (size_t)512 * 1024 * 2;
  _Float16* wseh = (_Float16*)p; p += (size_t)512 * 512 * 2;
  _Float16* wsel = (_Float16*)p; p += (size_t)512 * 512 * 2;
  _Float16* t1h  = (_Float16*)p; p += (size_t)chunkN * 1024 * 2;
  _Float16* t1l  = (_Float16*)p; p += (size_t)chunkN * 1024 * 2;
  float*    x    = (float*)p;    p += (size_t)chunkN * kH * 4;
  _Float16* khs  = (_Float16*)p; p += (size_t)kTok * kHalf * 2;   // K hi/lo fp16
  _Float16* kls  = (_Float16*)p; p += (size_t)kTok * kHalf * 2;
  _Float16* khe  = (_Float16*)p; p += (size_t)kTok * kHalf * 2;
  _Float16* kle  = (_Float16*)p; p += (size_t)kTok * kHalf * 2;
  float*    wts  = (float*)p;    p += (size_t)kL * 4;
  float*    cout_= (float*)p;    p += (size_t)kB * 512 * 4;
  float*    ssqp = (float*)p;    p += (size_t)2 * kTok * 4 * 4;   // [mat][tok][4] partials
  _Float16* hh   = t1h;          // alias: t1 dead once x is written
  _Float16* hl   = t1l;

  pos_kernel<<<dim3((kL + 255) / 256), dim3(256), 0, stream>>>(pos_emb, pos_w, pos_b, wts);
  transpose_split<<<dim3(1024 * 512 / 256), dim3(256), 0, stream>>>(w1, w1th, w1tl, 1024, 9);
  transpose_split<<<dim3(512 * 1024 / 256), dim3(256), 0, stream>>>(w2, w2th, w2tl, 512, 10);
  transpose_split<<<dim3(256 * 512 / 256), dim3(256), 0, stream>>>(sem_w, wseh, wsel, 256, 9);
  transpose_split<<<dim3(256 * 512 / 256), dim3(256), 0, stream>>>(
      epi_w, wseh + (size_t)256 * 512, wsel + (size_t)256 * 512, 256, 9);

  for (int c = 0; c < nch; ++c) {
    const int tok0 = c * chunkN;
    hgemm<0><<<dim3(1024 / 128, chunkN / 128), dim3(256), 0, stream>>>(
        seq, embed, nullptr, nullptr, w1th, w1tl, b1, nullptr,
        nullptr, t1h, t1l, nullptr, nullptr, 512, 1024, tok0);
    hgemm<1><<<dim3(512 / 128, chunkN / 128), dim3(256), 0, stream>>>(
        seq, embed, t1h, t1l, w2th, w2tl, b2, nullptr,
        x, nullptr, nullptr, nullptr, nullptr, 1024, 512, tok0);
    ln_split<<<dim3(chunkN / 4), dim3(256), 0, stream>>>(x, ln_g, ln_b, hh, hl);
    hgemm<2><<<dim3(512 / 128, chunkN / 128), dim3(256), 0, stream>>>(
        seq, embed, hh, hl, wseh, wsel, sem_b, epi_b,
        ssqp, kls, kle, (float*)khs, (float*)khe,
        512, 512, tok0);
  }

  scan_chunked<<<dim3(512), dim3(256), 0, stream>>>(khs, kls, khe, kle, ssqp, wts, cout_);
  out_gemm<<<dim3(kV / 128), dim3(256), 0, stream>>>(cout_, out_w, out_b, out);

  (void)in_sizes; (void)n_in; (void)out_size;
}

// Round 5
// 1231.284 us; speedup vs baseline: 1.4457x; 1.2662x over previous
//
#include <hip/hip_runtime.h>
#include <hip/hip_bf16.h>
#include <math.h>

namespace {

constexpr int kH     = 512;
constexpr int kL     = 1024;
constexpr int kB     = 64;
constexpr int kHalf  = 256;
constexpr int kV     = 32000;
constexpr int kTok   = kB * kL;     // 65536

using f32x4 = __attribute__((ext_vector_type(4))) float;
using f16x8 = __attribute__((ext_vector_type(8))) _Float16;

__device__ inline void fsplit(float v, _Float16& h, _Float16& l) {
  h = (_Float16)v;
  l = (_Float16)(v - (float)h);
}

// ---------------- positional weights
__global__ void pos_kernel(const float* __restrict__ pos_emb,
                           const float* __restrict__ pos_w,
                           const float* __restrict__ pos_b,
                           float* __restrict__ wts)
{
  int t = blockIdx.x * blockDim.x + threadIdx.x;
  if (t >= kL) return;
  float z = pos_b[0];
#pragma unroll
  for (int p = 0; p < 16; ++p) z += pos_emb[t * 16 + p] * pos_w[p];
  wts[t] = 1.f / (1.f + expf(-z));
}

// ---------------- transpose + hi/lo fp16 split: W[K][N] fp32 -> Th/Tl[N][K]
__global__ __launch_bounds__(256) void transpose_split(
    const float* __restrict__ W, _Float16* __restrict__ Th,
    _Float16* __restrict__ Tl, int N, int kshift)
{
  const int idx = blockIdx.x * 256 + threadIdx.x;
  const int K = 1 << kshift;
  const int k = idx & (K - 1);
  const int n = idx >> kshift;
  const float w = W[(size_t)k * N + n];
  const _Float16 h = (_Float16)w;
  Th[idx] = h;
  Tl[idx] = (_Float16)(w - (float)h);
}

// ---------------- split-fp16 MFMA GEMM: C[M,N] = A[M,K] @ (Bh+Bl)[N,K]^T
template <int EPI>
__global__ __launch_bounds__(256) void hgemm(
    const int* __restrict__ seq, const float* __restrict__ embed,
    const _Float16* __restrict__ Ah, const _Float16* __restrict__ Al,
    const _Float16* __restrict__ Bh, const _Float16* __restrict__ Bl,
    const float* __restrict__ bias, const float* __restrict__ bias2,
    float* __restrict__ Xout, _Float16* __restrict__ Oh, _Float16* __restrict__ Ol,
    float* __restrict__ ks, float* __restrict__ ke,
    int K, int N, int tok0c)
{
  __shared__ _Float16 lds[4][128][40];   // Ahi, Alo, Bhi, Blo; +8 pad (80B stride)
  const int tid  = threadIdx.x;
  const int lane = tid & 63;
  const int wv   = tid >> 6;
  const int wm   = (wv >> 1) * 64;
  const int wn   = (wv & 1) * 64;
  const int bm0  = blockIdx.y * 128;
  const int bn0  = blockIdx.x * 128;

  f32x4 acc[4][4];
#pragma unroll
  for (int i = 0; i < 4; ++i)
#pragma unroll
    for (int j = 0; j < 4; ++j) acc[i][j] = {0.f, 0.f, 0.f, 0.f};

  const int sr = tid >> 1;            // staging row 0..127
  const int sc = (tid & 1) << 4;      // 0 or 16 (halves)
  const _Float16* gBh = Bh + (size_t)(bn0 + sr) * K + sc;
  const _Float16* gBl = Bl + (size_t)(bn0 + sr) * K + sc;
  const _Float16* gAh = nullptr;
  const _Float16* gAl = nullptr;
  const float*    gAe = nullptr;
  if constexpr (EPI == 0) {
    const int tokrow = seq[tok0c + bm0 + sr];
    gAe = embed + (size_t)tokrow * kH + sc;
  } else {
    gAh = Ah + (size_t)(bm0 + sr) * K + sc;
    gAl = Al + (size_t)(bm0 + sr) * K + sc;
  }

  const int lrow = lane & 15;
  const int lk   = (lane >> 4) * 8;

  for (int k0 = 0; k0 < K; k0 += 32) {
    const uint4 vC0 = *(const uint4*)(gBh + k0);
    const uint4 vC1 = *(const uint4*)(gBh + k0 + 8);
    const uint4 vD0 = *(const uint4*)(gBl + k0);
    const uint4 vD1 = *(const uint4*)(gBl + k0 + 8);
    if constexpr (EPI == 0) {
      const float4 a0 = *(const float4*)(gAe + k0);
      const float4 a1 = *(const float4*)(gAe + k0 + 4);
      const float4 a2 = *(const float4*)(gAe + k0 + 8);
      const float4 a3 = *(const float4*)(gAe + k0 + 12);
      const float vv[16] = {a0.x,a0.y,a0.z,a0.w, a1.x,a1.y,a1.z,a1.w,
                            a2.x,a2.y,a2.z,a2.w, a3.x,a3.y,a3.z,a3.w};
      union { _Float16 h[16]; uint4 u[2]; } ph, pl;
#pragma unroll
      for (int i = 0; i < 16; ++i) fsplit(vv[i], ph.h[i], pl.h[i]);
      __syncthreads();
      *(uint4*)&lds[0][sr][sc]     = ph.u[0];
      *(uint4*)&lds[0][sr][sc + 8] = ph.u[1];
      *(uint4*)&lds[1][sr][sc]     = pl.u[0];
      *(uint4*)&lds[1][sr][sc + 8] = pl.u[1];
    } else {
      const uint4 vA0 = *(const uint4*)(gAh + k0);
      const uint4 vA1 = *(const uint4*)(gAh + k0 + 8);
      const uint4 vB0 = *(const uint4*)(gAl + k0);
      const uint4 vB1 = *(const uint4*)(gAl + k0 + 8);
      __syncthreads();
      *(uint4*)&lds[0][sr][sc]     = vA0;
      *(uint4*)&lds[0][sr][sc + 8] = vA1;
      *(uint4*)&lds[1][sr][sc]     = vB0;
      *(uint4*)&lds[1][sr][sc + 8] = vB1;
    }
    *(uint4*)&lds[2][sr][sc]     = vC0;
    *(uint4*)&lds[2][sr][sc + 8] = vC1;
    *(uint4*)&lds[3][sr][sc]     = vD0;
    *(uint4*)&lds[3][sr][sc + 8] = vD1;
    __syncthreads();

    f16x8 fBh[4], fBl[4];
#pragma unroll
    for (int ni = 0; ni < 4; ++ni) {
      fBh[ni] = *(const f16x8*)&lds[2][wn + ni * 16 + lrow][lk];
      fBl[ni] = *(const f16x8*)&lds[3][wn + ni * 16 + lrow][lk];
    }
#pragma unroll
    for (int mi = 0; mi < 4; ++mi) {
      const f16x8 ah = *(const f16x8*)&lds[0][wm + mi * 16 + lrow][lk];
      const f16x8 al = *(const f16x8*)&lds[1][wm + mi * 16 + lrow][lk];
#pragma unroll
      for (int ni = 0; ni < 4; ++ni) {
        acc[mi][ni] = __builtin_amdgcn_mfma_f32_16x16x32_f16(ah, fBh[ni], acc[mi][ni], 0, 0, 0);
        acc[mi][ni] = __builtin_amdgcn_mfma_f32_16x16x32_f16(ah, fBl[ni], acc[mi][ni], 0, 0, 0);
        acc[mi][ni] = __builtin_amdgcn_mfma_f32_16x16x32_f16(al, fBh[ni], acc[mi][ni], 0, 0, 0);
      }
    }
  }

  const int erow0 = (lane >> 4) * 4;
  if constexpr (EPI == 0) {
#pragma unroll
    for (int mi = 0; mi < 4; ++mi)
#pragma unroll
      for (int ni = 0; ni < 4; ++ni) {
        const int gn = bn0 + wn + ni * 16 + (lane & 15);
        const float bv = bias[gn];
#pragma unroll
        for (int r = 0; r < 4; ++r) {
          const int gm = bm0 + wm + mi * 16 + erow0 + r;
          float v = fmaxf(acc[mi][ni][r] + bv, 0.f);
          const _Float16 h = (_Float16)v;
          Oh[(size_t)gm * N + gn] = h;
          Ol[(size_t)gm * N + gn] = (_Float16)(v - (float)h);
        }
      }
  } else if constexpr (EPI == 1) {
#pragma unroll
    for (int mi = 0; mi < 4; ++mi)
#pragma unroll
      for (int r = 0; r < 4; ++r) {
        const int gm = bm0 + wm + mi * 16 + erow0 + r;
        const int tok = seq[tok0c + gm];
        const float* er = embed + (size_t)tok * kH;
#pragma unroll
        for (int ni = 0; ni < 4; ++ni) {
          const int gn = bn0 + wn + ni * 16 + (lane & 15);
          Xout[(size_t)gm * N + gn] = acc[mi][ni][r] + bias[gn] + er[gn];
        }
      }
  } else {
    // EPI==2: write K as fp16 hi/lo pairs + per-quarter ssq partials (Xout).
    _Float16* kh_s = (_Float16*)ks;
    _Float16* kh_e = (_Float16*)ke;
    float s2[4][4];
#pragma unroll
    for (int mi = 0; mi < 4; ++mi)
#pragma unroll
      for (int r = 0; r < 4; ++r) s2[mi][r] = 0.f;
#pragma unroll
    for (int mi = 0; mi < 4; ++mi)
#pragma unroll
      for (int ni = 0; ni < 4; ++ni) {
        const int gn = bn0 + wn + ni * 16 + (lane & 15);
        const float bv = (gn < 256) ? bias[gn] : bias2[gn - 256];
        _Float16* Dh = (gn < 256) ? kh_s : kh_e;
        _Float16* Dl = (gn < 256) ? Oh : Ol;
        const int col = gn & 255;
#pragma unroll
        for (int r = 0; r < 4; ++r) {
          const int gm = bm0 + wm + mi * 16 + erow0 + r;
          const float v = acc[mi][ni][r] + bv;
          s2[mi][r] += v * v;
          _Float16 h, l;
          fsplit(v, h, l);
          Dh[(size_t)(tok0c + gm) * 256 + col] = h;
          Dl[(size_t)(tok0c + gm) * 256 + col] = l;
        }
      }
    // deterministic per-quarter partial sums: ssqPart[mat][tok][half*2 + (wv&1)]
    const int matq  = bn0 >> 8;
    const int halfq = (bn0 >> 7) & 1;
#pragma unroll
    for (int mi = 0; mi < 4; ++mi)
#pragma unroll
      for (int r = 0; r < 4; ++r) {
        float s2v = s2[mi][r];
        s2v += __shfl_xor(s2v, 1);
        s2v += __shfl_xor(s2v, 2);
        s2v += __shfl_xor(s2v, 4);
        s2v += __shfl_xor(s2v, 8);
        if ((lane & 15) == 0) {
          const int gm = bm0 + wm + mi * 16 + erow0 + r;
          Xout[((size_t)matq * kTok + (size_t)(tok0c + gm)) * 4 + halfq * 2 + (wv & 1)] = s2v;
        }
      }
  }
}

// ---------------- LayerNorm: x fp32 -> hi/lo fp16
__global__ __launch_bounds__(256) void ln_split(
    const float* __restrict__ x, const float* __restrict__ g,
    const float* __restrict__ bta, _Float16* __restrict__ hh,
    _Float16* __restrict__ hl)
{
  const int wid  = threadIdx.x >> 6;
  const int lane = threadIdx.x & 63;
  const int ltok = blockIdx.x * 4 + wid;
  const float* xp = x + (size_t)ltok * kH;
  const float4 v0 = *(const float4*)(xp + lane * 8);
  const float4 v1 = *(const float4*)(xp + lane * 8 + 4);
  float s  = v0.x + v0.y + v0.z + v0.w + v1.x + v1.y + v1.z + v1.w;
  float ss = v0.x * v0.x + v0.y * v0.y + v0.z * v0.z + v0.w * v0.w +
             v1.x * v1.x + v1.y * v1.y + v1.z * v1.z + v1.w * v1.w;
#pragma unroll
  for (int m = 1; m < 64; m <<= 1) { s += __shfl_xor(s, m); ss += __shfl_xor(ss, m); }
  const float mu  = s * (1.f / kH);
  const float var = ss * (1.f / kH) - mu * mu;
  const float rs  = 1.f / sqrtf(var + 1e-5f);
  const float4 g0 = *(const float4*)(g + lane * 8);
  const float4 g1 = *(const float4*)(g + lane * 8 + 4);
  const float4 b0 = *(const float4*)(bta + lane * 8);
  const float4 b1 = *(const float4*)(bta + lane * 8 + 4);
  const float vv[8] = {v0.x, v0.y, v0.z, v0.w, v1.x, v1.y, v1.z, v1.w};
  const float gg[8] = {g0.x, g0.y, g0.z, g0.w, g1.x, g1.y, g1.z, g1.w};
  const float bb[8] = {b0.x, b0.y, b0.z, b0.w, b1.x, b1.y, b1.z, b1.w};
  union { _Float16 h[8]; uint4 u; } ph, pl;
#pragma unroll
  for (int i = 0; i < 8; ++i) {
    const float o = (vv[i] - mu) * rs * gg[i] + bb[i];
    fsplit(o, ph.h[i], pl.h[i]);
  }
  *(uint4*)(hh + (size_t)ltok * kH + lane * 8) = ph.u;
  *(uint4*)(hl + (size_t)ltok * kH + lane * 8) = pl.u;
}

// ---------------- T precompute: T = (I + diag(aS)*tril_strict(K K^T))^{-1}
// One WG (1 wave) per (b, mat, ck): 2048 independent problems.
// wg = (b*2+mat)*16 + ck. Output Th/Tl[wg][t][t'] fp16 hi/lo, row-major.
__global__ __launch_bounds__(64) void tinv_kernel(
    const _Float16* __restrict__ khs, const _Float16* __restrict__ kls,
    const _Float16* __restrict__ khe, const _Float16* __restrict__ kle,
    const float* __restrict__ ssqP, const float* __restrict__ wts,
    _Float16* __restrict__ Tgh, _Float16* __restrict__ Tgl)
{
  __shared__ float Gs[64][68];   // aS-scaled G (row-scaled); stride 68 (16B-aligned rows)
  const int lane = threadIdx.x;
  const int l15  = lane & 15;
  const int quad = lane >> 4;
  const int wg   = blockIdx.x;
  const int ck   = wg & 15;
  const int mat  = (wg >> 4) & 1;
  const int b    = wg >> 5;
  const _Float16* Kh = (mat ? khe : khs) + (size_t)b * (1024 * 256) + (size_t)ck * 64 * 256;
  const _Float16* Kl = (mat ? kle : kls) + (size_t)b * (1024 * 256) + (size_t)ck * 64 * 256;

  // aS for token t = lane
  const float4 sq = *(const float4*)(ssqP + ((size_t)mat * kTok + (size_t)b * 1024 + ck * 64 + lane) * 4);
  const float w  = mat ? wts[ck * 64 + lane] : 1.f;
  const float aS = w / (sq.x + sq.y + sq.z + sq.w + 1e-6f);

  // G = K K^T via split-fp16 MFMA
  f32x4 D[16];
#pragma unroll
  for (int i = 0; i < 16; ++i) D[i] = {0.f, 0.f, 0.f, 0.f};
#pragma unroll
  for (int kit = 0; kit < 8; ++kit) {
    f16x8 fh[4], fl[4];
#pragma unroll
    for (int mi = 0; mi < 4; ++mi) {
      fh[mi] = *(const f16x8*)(Kh + (size_t)(mi * 16 + l15) * 256 + kit * 32 + quad * 8);
      fl[mi] = *(const f16x8*)(Kl + (size_t)(mi * 16 + l15) * 256 + kit * 32 + quad * 8);
    }
#pragma unroll
    for (int mi = 0; mi < 4; ++mi)
#pragma unroll
      for (int ni = 0; ni < 4; ++ni) {
        f32x4 d = D[mi * 4 + ni];
        d = __builtin_amdgcn_mfma_f32_16x16x32_f16(fh[mi], fh[ni], d, 0, 0, 0);
        d = __builtin_amdgcn_mfma_f32_16x16x32_f16(fh[mi], fl[ni], d, 0, 0, 0);
        d = __builtin_amdgcn_mfma_f32_16x16x32_f16(fl[mi], fh[ni], d, 0, 0, 0);
        D[mi * 4 + ni] = d;
      }
  }
  // scatter with per-row aS scale: L[t][t'] = aS[t] * G[t][t']
#pragma unroll
  for (int mi = 0; mi < 4; ++mi)
#pragma unroll
    for (int ni = 0; ni < 4; ++ni)
#pragma unroll
      for (int r = 0; r < 4; ++r) {
        const int row = mi * 16 + quad * 4 + r;
        const float as_r = __shfl(aS, row);
        Gs[row][ni * 16 + l15] = as_r * D[mi * 4 + ni][r];
      }
  __syncthreads();

  // unit-lower-triangular inverse, column j = lane; x kept in registers
  float x[64];
#pragma unroll
  for (int t = 0; t < 64; ++t) x[t] = (t == lane) ? 1.f : 0.f;
#pragma unroll
  for (int t = 1; t < 64; ++t) {
    float acc = 0.f;
    const int n4 = t >> 2;
#pragma unroll
    for (int q4 = 0; q4 < 16; ++q4) {
      if (q4 >= n4) break;
      const float4 g = *(const float4*)&Gs[t][q4 * 4];
      acc += g.x * x[q4 * 4] + g.y * x[q4 * 4 + 1] + g.z * x[q4 * 4 + 2] + g.w * x[q4 * 4 + 3];
    }
#pragma unroll
    for (int tp = 0; tp < 4; ++tp) {
      const int ti = n4 * 4 + tp;
      if (ti >= t) break;
      acc += Gs[t][ti] * x[ti];
    }
    x[t] -= acc;
  }
  if (ck == 15) x[63] = 0.f;   // token L-1 is the query only: U row 63 = 0

  // store transposed (x = column lane of T): Tg[t][t'=lane]
  const size_t base = (size_t)wg * 4096;
#pragma unroll
  for (int t = 0; t < 64; ++t) {
    _Float16 h, l;
    fsplit(x[t], h, l);
    Tgh[base + t * 64 + lane] = h;
    Tgl[base + t * 64 + lane] = l;
  }
}

// ---------------- chunked WY delta-rule scan (v9).
// v9: the serial triangular solve is GONE — T = (I+A*G_strict)^{-1} is
// precomputed per chunk by tinv_kernel (depends only on K, not S). Chunk =
// {Q = K S^T (MFMA, S^T LDS dbuf); Y = W*Kv - A*Q (regs); U = T*Y (MFMA,
// T rows streamed from global); S += K^T U (MFMA, K^T frags as L2-hot
// scalar global loads — XCD affinity makes them hits)}. 7 barriers/chunk
// (was 18), no K ring, no Gm/Rr/ubS LDS, no G recompute (was 4x redundant).
struct HTile { _Float16 h[4608], l[4608]; };   // [64][72] halves hi/lo, 18432 B

__global__ __launch_bounds__(256) void scan_chunked(
    const _Float16* __restrict__ khs, const _Float16* __restrict__ kls,
    const _Float16* __restrict__ khe, const _Float16* __restrict__ kle,
    const float* __restrict__ ssqP, const float* __restrict__ wts,
    const _Float16* __restrict__ Tgh, const _Float16* __restrict__ Tgl,
    float* __restrict__ c_out)
{
  __shared__ HTile Sb[2];                                   // S^T dbuf 36864 B
  __shared__ union { HTile t; float cred[4][64]; } Yb;      // Y^T      18432 B
  __shared__ HTile Ub;                                      // U^T      18432 B

  const int tid  = threadIdx.x;
  const int lane = tid & 63;
  const int wv   = tid >> 6;
  const int l15  = lane & 15;
  const int quad = lane >> 4;
  // XCD-affinity decode (bijective): quarters q=0..3 of one (b,mat) share wg%8
  const int wg   = blockIdx.x;
  const int grp  = (wg & 7) + ((wg >> 5) << 3);   // 0..127
  const int q    = (wg >> 3) & 3;
  const int b    = grp >> 1;
  const int mat  = grp & 1;
  const int j0   = q * 64;
  const _Float16* Kh = (mat ? khe : khs) + (size_t)b * (1024 * 256);
  const _Float16* Kl = (mat ? kle : kls) + (size_t)b * (1024 * 256);
  const _Float16* Tbh = Tgh + (size_t)((b * 2 + mat) * 16) * 4096;
  const _Float16* Tbl = Tgl + (size_t)((b * 2 + mat) * 16) * 4096;

  // S[p*4+nt]: rows p*64 + wv*16 + quad*4 + r ; cols nt*16 + l15 (WG-local j)
  f32x4 S[16];
#pragma unroll
  for (int i = 0; i < 16; ++i) S[i] = {0.f, 0.f, 0.f, 0.f};

  for (int ck = 0; ck < 16; ++ck) {
    const int tok0 = ck * 64;

    // ---- per-own-row scalars (global, tiny, latency hidden under staging)
    float myw[4], mya[4], kvv[4][4];
#pragma unroll
    for (int r = 0; r < 4; ++r) {
      const int t = tok0 + wv * 16 + quad * 4 + r;
      const float4 sq = *(const float4*)(ssqP + ((size_t)mat * kTok + (size_t)b * 1024 + t) * 4);
      const float w = mat ? wts[t] : 1.f;
      myw[r] = w;
      mya[r] = w / (sq.x + sq.y + sq.z + sq.w + 1e-6f);
#pragma unroll
      for (int nt = 0; nt < 4; ++nt) {
        const size_t go = (size_t)t * 256 + j0 + nt * 16 + l15;
        kvv[r][nt] = (float)Kh[go] + (float)Kl[go];
      }
    }
    // ---- T A-fragments for this chunk (global, row-major contiguous)
    f16x8 tah[2], tal[2];
#pragma unroll
    for (int kit = 0; kit < 2; ++kit) {
      const size_t to = (size_t)ck * 4096 + (size_t)(wv * 16 + l15) * 64 + kit * 32 + quad * 8;
      tah[kit] = *(const f16x8*)(Tbh + to);
      tal[kit] = *(const f16x8*)(Tbl + to);
    }
    // ---- Q A-frag panel-0 prefetch (K rows, contiguous in d)
    const _Float16* arow_h = Kh + (size_t)(tok0 + wv * 16 + l15) * 256 + quad * 8;
    const _Float16* arow_l = Kl + (size_t)(tok0 + wv * 16 + l15) * 256 + quad * 8;
    f16x8 a0h = *(const f16x8*)(arow_h);
    f16x8 a1h = *(const f16x8*)(arow_h + 32);
    f16x8 a0l = *(const f16x8*)(arow_l);
    f16x8 a1l = *(const f16x8*)(arow_l + 32);

    // ---- stage S^T panel 0 into Sb[0]
#pragma unroll
    for (int nt = 0; nt < 4; ++nt) {
      const f32x4 v = S[0 * 4 + nt];
      union { _Float16 h[4]; uint2 u; } qh, ql;
#pragma unroll
      for (int r = 0; r < 4; ++r) fsplit(v[r], qh.h[r], ql.h[r]);
      const int ix = (nt * 16 + l15) * 72 + wv * 16 + quad * 4;
      *(uint2*)&Sb[0].h[ix] = qh.u;
      *(uint2*)&Sb[0].l[ix] = ql.u;
    }
    __syncthreads();   // BP0

    // ---- Q = K S^T over 4 d-panels
    f32x4 Qa[4];
#pragma unroll
    for (int i = 0; i < 4; ++i) Qa[i] = {0.f, 0.f, 0.f, 0.f};
#pragma unroll
    for (int p = 0; p < 4; ++p) {
      const int cur = p & 1;
      f16x8 n0h, n1h, n0l, n1l;
      if (p < 3) {
        n0h = *(const f16x8*)(arow_h + (p + 1) * 64);
        n1h = *(const f16x8*)(arow_h + (p + 1) * 64 + 32);
        n0l = *(const f16x8*)(arow_l + (p + 1) * 64);
        n1l = *(const f16x8*)(arow_l + (p + 1) * 64 + 32);
        // stage next S^T panel (its readers finished at the p-1 barrier)
#pragma unroll
        for (int nt = 0; nt < 4; ++nt) {
          const f32x4 v = S[(p + 1) * 4 + nt];
          union { _Float16 h[4]; uint2 u; } sh2, sl2;
#pragma unroll
          for (int r = 0; r < 4; ++r) fsplit(v[r], sh2.h[r], sl2.h[r]);
          const int ix = (nt * 16 + l15) * 72 + wv * 16 + quad * 4;
          *(uint2*)&Sb[1 - cur].h[ix] = sh2.u;
          *(uint2*)&Sb[1 - cur].l[ix] = sl2.u;
        }
      }
#pragma unroll
      for (int kit = 0; kit < 2; ++kit) {
        const f16x8 ah = kit ? a1h : a0h;
        const f16x8 al = kit ? a1l : a0l;
#pragma unroll
        for (int nt = 0; nt < 4; ++nt) {
          const int ix = (nt * 16 + l15) * 72 + kit * 32 + quad * 8;
          const f16x8 bh = *(const f16x8*)&Sb[cur].h[ix];
          const f16x8 bl = *(const f16x8*)&Sb[cur].l[ix];
          Qa[nt] = __builtin_amdgcn_mfma_f32_16x16x32_f16(ah, bh, Qa[nt], 0, 0, 0);
          Qa[nt] = __builtin_amdgcn_mfma_f32_16x16x32_f16(ah, bl, Qa[nt], 0, 0, 0);
          Qa[nt] = __builtin_amdgcn_mfma_f32_16x16x32_f16(al, bh, Qa[nt], 0, 0, 0);
        }
      }
      if (p < 3) { a0h = n0h; a1h = n1h; a0l = n0l; a1l = n1l; }
      __syncthreads();   // end of panel p
    }

    // ---- Y = W*Kv - A*Q, stage Y^T[j][t]
#pragma unroll
    for (int nt = 0; nt < 4; ++nt) {
      union { _Float16 h[4]; uint2 u; } yh, yl;
#pragma unroll
      for (int r = 0; r < 4; ++r) {
        const float y = myw[r] * kvv[r][nt] - mya[r] * Qa[nt][r];
        fsplit(y, yh.h[r], yl.h[r]);
      }
      const int ix = (nt * 16 + l15) * 72 + wv * 16 + quad * 4;
      *(uint2*)&Yb.t.h[ix] = yh.u;
      *(uint2*)&Yb.t.l[ix] = yl.u;
    }
    __syncthreads();   // BY

    // ---- U = T*Y
    f32x4 Ua[4];
#pragma unroll
    for (int i = 0; i < 4; ++i) Ua[i] = {0.f, 0.f, 0.f, 0.f};
#pragma unroll
    for (int kit = 0; kit < 2; ++kit)
#pragma unroll
      for (int nt = 0; nt < 4; ++nt) {
        const int ix = (nt * 16 + l15) * 72 + kit * 32 + quad * 8;
        const f16x8 yh = *(const f16x8*)&Yb.t.h[ix];
        const f16x8 yl = *(const f16x8*)&Yb.t.l[ix];
        Ua[nt] = __builtin_amdgcn_mfma_f32_16x16x32_f16(tah[kit], yh, Ua[nt], 0, 0, 0);
        Ua[nt] = __builtin_amdgcn_mfma_f32_16x16x32_f16(tah[kit], yl, Ua[nt], 0, 0, 0);
        Ua[nt] = __builtin_amdgcn_mfma_f32_16x16x32_f16(tal[kit], yh, Ua[nt], 0, 0, 0);
      }
    // stage U^T[j][t]
#pragma unroll
    for (int nt = 0; nt < 4; ++nt) {
      union { _Float16 h[4]; uint2 u; } uh, ul;
#pragma unroll
      for (int r = 0; r < 4; ++r) fsplit(Ua[nt][r], uh.h[r], ul.h[r]);
      const int ix = (nt * 16 + l15) * 72 + wv * 16 + quad * 4;
      *(uint2*)&Ub.h[ix] = uh.u;
      *(uint2*)&Ub.l[ix] = ul.u;
    }
    __syncthreads();   // BU

    // ---- S += K^T U, barrier-free (A-frags = L2-hot scalar global loads)
#pragma unroll
    for (int p = 0; p < 4; ++p) {
      union { _Float16 e[8]; f16x8 v; } kah[2], kal[2];
#pragma unroll
      for (int kit = 0; kit < 2; ++kit)
#pragma unroll
        for (int jj = 0; jj < 8; ++jj) {
          const size_t gko = (size_t)(tok0 + kit * 32 + quad * 8 + jj) * 256
                           + p * 64 + wv * 16 + l15;
          kah[kit].e[jj] = Kh[gko];
          kal[kit].e[jj] = Kl[gko];
        }
#pragma unroll
      for (int kit = 0; kit < 2; ++kit)
#pragma unroll
        for (int nt = 0; nt < 4; ++nt) {
          const int ix = (nt * 16 + l15) * 72 + kit * 32 + quad * 8;
          const f16x8 ubh = *(const f16x8*)&Ub.h[ix];
          const f16x8 ubl = *(const f16x8*)&Ub.l[ix];
          f32x4 s = S[p * 4 + nt];
          s = __builtin_amdgcn_mfma_f32_16x16x32_f16(kah[kit].v, ubh, s, 0, 0, 0);
          s = __builtin_amdgcn_mfma_f32_16x16x32_f16(kah[kit].v, ubl, s, 0, 0, 0);
          s = __builtin_amdgcn_mfma_f32_16x16x32_f16(kal[kit].v, ubh, s, 0, 0, 0);
          S[p * 4 + nt] = s;
        }
    }
    // next chunk's BP0 orders Ub WAR and Sb reuse
  }

  // ---- readout: c[col] = sum_rows S[row][col] * k_last[row]
  float part[4] = {0.f, 0.f, 0.f, 0.f};
  const size_t lastoff = (size_t)(kL - 1) * 256;
#pragma unroll
  for (int p = 0; p < 4; ++p) {
    float klr[4];
#pragma unroll
    for (int r = 0; r < 4; ++r) {
      const int row = p * 64 + wv * 16 + quad * 4 + r;
      klr[r] = (float)Kh[lastoff + row] + (float)Kl[lastoff + row];
    }
#pragma unroll
    for (int nt = 0; nt < 4; ++nt)
#pragma unroll
      for (int r = 0; r < 4; ++r) part[nt] += S[p * 4 + nt][r] * klr[r];
  }
#pragma unroll
  for (int nt = 0; nt < 4; ++nt) {
    part[nt] += __shfl_xor(part[nt], 16);
    part[nt] += __shfl_xor(part[nt], 32);
  }
  __syncthreads();   // all prior LDS reads done before cred aliases Yb
  if (lane < 16) {
#pragma unroll
    for (int nt = 0; nt < 4; ++nt) Yb.cred[wv][nt * 16 + l15] = part[nt];
  }
  __syncthreads();
  if (tid < 64) {
    const float c = Yb.cred[0][tid] + Yb.cred[1][tid] + Yb.cred[2][tid] + Yb.cred[3][tid];
    c_out[(size_t)b * 512 + mat * 256 + j0 + tid] = c;
  }
}

// ---------------- output GEMM: (64 x 512) @ (512 x 32000) + out_b -> fp32
__global__ __launch_bounds__(256) void out_gemm(
    const float* __restrict__ A, const float* __restrict__ Bm,
    const float* __restrict__ bias, float* __restrict__ C)
{
  __shared__ float As[16][64];
  __shared__ float Bs[16][128];
  const int tid = threadIdx.x;
  const int bn0 = blockIdx.x * 128;
  const int tm = tid >> 4, tn = tid & 15;
  float acc[4][8];
#pragma unroll
  for (int i = 0; i < 4; ++i)
#pragma unroll
    for (int j = 0; j < 8; ++j) acc[i][j] = 0.f;

  const int am  = tid & 63;
  const int ak  = (tid >> 6) * 4;
  const int bkr = tid >> 5;
  const int bcg = (tid & 31) * 4;

  for (int k0 = 0; k0 < kH; k0 += 16) {
    const float4 a0 = *(const float4*)(A + (size_t)am * kH + k0 + ak);
    const float4 b0 = *(const float4*)(Bm + (size_t)(k0 + bkr) * kV + bn0 + bcg);
    const float4 b1 = *(const float4*)(Bm + (size_t)(k0 + bkr + 8) * kV + bn0 + bcg);
    __syncthreads();
    As[ak + 0][am] = a0.x; As[ak + 1][am] = a0.y;
    As[ak + 2][am] = a0.z; As[ak + 3][am] = a0.w;
    *(float4*)&Bs[bkr][bcg]     = b0;
    *(float4*)&Bs[bkr + 8][bcg] = b1;
    __syncthreads();
#pragma unroll
    for (int kk = 0; kk < 16; ++kk) {
      const float4 aA = *(const float4*)&As[kk][tm * 4];
      const float4 bA = *(const float4*)&Bs[kk][tn * 4];
      const float4 bB = *(const float4*)&Bs[kk][64 + tn * 4];
      const float av[4] = {aA.x, aA.y, aA.z, aA.w};
      const float bv[8] = {bA.x, bA.y, bA.z, bA.w, bB.x, bB.y, bB.z, bB.w};
#pragma unroll
      for (int i = 0; i < 4; ++i)
#pragma unroll
        for (int j = 0; j < 8; ++j) acc[i][j] += av[i] * bv[j];
    }
  }

#pragma unroll
  for (int i = 0; i < 4; ++i) {
    const int row = tm * 4 + i;
#pragma unroll
    for (int hh = 0; hh < 2; ++hh) {
      const int n0 = bn0 + tn * 4 + hh * 64;
      const float4 bb = *(const float4*)(bias + n0);
      float4 o;
      o.x = acc[i][hh * 4 + 0] + bb.x;
      o.y = acc[i][hh * 4 + 1] + bb.y;
      o.z = acc[i][hh * 4 + 2] + bb.z;
      o.w = acc[i][hh * 4 + 3] + bb.w;
      *(float4*)(C + (size_t)row * kV + n0) = o;
    }
  }
}

}  // namespace

extern "C" void kernel_launch(void* const* d_in, const int* in_sizes, int n_in,
                              void* d_out, int out_size, void* d_ws, size_t ws_size,
                              hipStream_t stream)
{
  const int*   seq     = (const int*)  d_in[0];
  const float* embed   = (const float*)d_in[1];
  const float* w1      = (const float*)d_in[2];
  const float* b1      = (const float*)d_in[3];
  const float* w2      = (const float*)d_in[4];
  const float* b2      = (const float*)d_in[5];
  const float* ln_g    = (const float*)d_in[6];
  const float* ln_b    = (const float*)d_in[7];
  const float* sem_w   = (const float*)d_in[8];
  const float* sem_b   = (const float*)d_in[9];
  const float* epi_w   = (const float*)d_in[10];
  const float* epi_b   = (const float*)d_in[11];
  const float* out_w   = (const float*)d_in[12];
  const float* out_b   = (const float*)d_in[13];
  const float* pos_emb = (const float*)d_in[14];
  const float* pos_w   = (const float*)d_in[15];
  const float* pos_b   = (const float*)d_in[16];
  float* out = (float*)d_out;

  // chunk size: 16384 needs ~231 MB of ws; fall back to 8192 if tight.
  // ws_size is constant per process -> deterministic, graph-capture-safe.
  const int chunkN = (ws_size >= (size_t)240500000) ? 16384 : 8192;
  const int nch    = kTok / chunkN;

  char* p = (char*)d_ws;
  _Float16* w1th = (_Float16*)p; p += (size_t)1024 * 512 * 2;
  _Float16* w1tl = (_Float16*)p; p += (size_t)1024 * 512 * 2;
  _Float16* w2th = (_Float16*)p; p += (size_t)512 * 1024 * 2;
  _Float16* w2tl = (_Float16*)p; p += (size_t)512 * 1024 * 2;
  _Float16* wseh = (_Float16*)p; p += (size_t)512 * 512 * 2;
  _Float16* wsel = (_Float16*)p; p += (size_t)512 * 512 * 2;
  _Float16* t1h  = (_Float16*)p; p += (size_t)chunkN * 1024 * 2;
  _Float16* t1l  = (_Float16*)p; p += (size_t)chunkN * 1024 * 2;
  float*    x    = (float*)p;    p += (size_t)chunkN * kH * 4;
  _Float16* khs  = (_Float16*)p; p += (size_t)kTok * kHalf * 2;   // K hi/lo fp16
  _Float16* kls  = (_Float16*)p; p += (size_t)kTok * kHalf * 2;
  _Float16* khe  = (_Float16*)p; p += (size_t)kTok * kHalf * 2;
  _Float16* kle  = (_Float16*)p; p += (size_t)kTok * kHalf * 2;
  float*    wts  = (float*)p;    p += (size_t)kL * 4;
  float*    cout_= (float*)p;    p += (size_t)kB * 512 * 4;
  float*    ssqp = (float*)p;    p += (size_t)2 * kTok * 4 * 4;   // [mat][tok][4] partials
  _Float16* hh   = t1h;          // alias: t1 dead once x is written
  _Float16* hl   = t1l;
  // T buffers alias t1h/t1l (dead after the chunk loop): 2048 chunks x 64x64
  // fp16 hi/lo = 2 x 16.78 MB; t1h+t1l region is >= 33.55 MB in both paths.
  _Float16* Tgh = t1h;
  _Float16* Tgl = t1h + (size_t)2048 * 4096;

  pos_kernel<<<dim3((kL + 255) / 256), dim3(256), 0, stream>>>(pos_emb, pos_w, pos_b, wts);
  transpose_split<<<dim3(1024 * 512 / 256), dim3(256), 0, stream>>>(w1, w1th, w1tl, 1024, 9);
  transpose_split<<<dim3(512 * 1024 / 256), dim3(256), 0, stream>>>(w2, w2th, w2tl, 512, 10);
  transpose_split<<<dim3(256 * 512 / 256), dim3(256), 0, stream>>>(sem_w, wseh, wsel, 256, 9);
  transpose_split<<<dim3(256 * 512 / 256), dim3(256), 0, stream>>>(
      epi_w, wseh + (size_t)256 * 512, wsel + (size_t)256 * 512, 256, 9);

  for (int c = 0; c < nch; ++c) {
    const int tok0 = c * chunkN;
    hgemm<0><<<dim3(1024 / 128, chunkN / 128), dim3(256), 0, stream>>>(
        seq, embed, nullptr, nullptr, w1th, w1tl, b1, nullptr,
        nullptr, t1h, t1l, nullptr, nullptr, 512, 1024, tok0);
    hgemm<1><<<dim3(512 / 128, chunkN / 128), dim3(256), 0, stream>>>(
        seq, embed, t1h, t1l, w2th, w2tl, b2, nullptr,
        x, nullptr, nullptr, nullptr, nullptr, 1024, 512, tok0);
    ln_split<<<dim3(chunkN / 4), dim3(256), 0, stream>>>(x, ln_g, ln_b, hh, hl);
    hgemm<2><<<dim3(512 / 128, chunkN / 128), dim3(256), 0, stream>>>(
        seq, embed, hh, hl, wseh, wsel, sem_b, epi_b,
        ssqp, kls, kle, (float*)khs, (float*)khe,
        512, 512, tok0);
  }

  tinv_kernel<<<dim3(2048), dim3(64), 0, stream>>>(
      khs, kls, khe, kle, ssqp, wts, Tgh, Tgl);
  scan_chunked<<<dim3(512), dim3(256), 0, stream>>>(
      khs, kls, khe, kle, ssqp, wts, Tgh, Tgl, cout_);
  out_gemm<<<dim3(kV / 128), dim3(256), 0, stream>>>(cout_, out_w, out_b, out);

  (void)in_sizes; (void)n_in; (void)out_size;
}

// Round 7
// 1176.861 us; speedup vs baseline: 1.5126x; 1.0462x over previous
//
#include <hip/hip_runtime.h>
#include <hip/hip_bf16.h>
#include <math.h>

namespace {

constexpr int kH     = 512;
constexpr int kL     = 1024;
constexpr int kB     = 64;
constexpr int kHalf  = 256;
constexpr int kV     = 32000;
constexpr int kTok   = kB * kL;     // 65536

using f32x4 = __attribute__((ext_vector_type(4))) float;
using f16x8 = __attribute__((ext_vector_type(8))) _Float16;

__device__ inline void fsplit(float v, _Float16& h, _Float16& l) {
  h = (_Float16)v;
  l = (_Float16)(v - (float)h);
}

// async 16B global->LDS (gfx950). dst must be wave-uniform base; lane l
// receives bytes [l*16, l*16+16).
typedef __attribute__((address_space(3))) void lds_vp;
typedef const __attribute__((address_space(1))) void glb_vp;
__device__ inline void gload16(const void* g, void* l) {
  __builtin_amdgcn_global_load_lds((glb_vp*)g, (lds_vp*)l, 16, 0, 0);
}

// Row-PAIR swizzled half-tile index for [128][32]-half tiles stored flat.
// 64B rows only have 4 granules, so the 8-slot XOR runs across row pairs:
// super-row sr=row>>1 (128B), granule g=(row&1)*4+col/8, g'=g^(sr&7).
// Per-16-lane b128 fragment read: each g' hit exactly twice -> 2-way (free).
__device__ inline int hswz(int row, int col) {
  const int sr = row >> 1;
  const int g  = ((row & 1) << 2) | (col >> 3);
  return sr * 64 + (((g ^ (sr & 7)) << 3) | (col & 7));
}

// ---------------- positional weights
__global__ void pos_kernel(const float* __restrict__ pos_emb,
                           const float* __restrict__ pos_w,
                           const float* __restrict__ pos_b,
                           float* __restrict__ wts)
{
  int t = blockIdx.x * blockDim.x + threadIdx.x;
  if (t >= kL) return;
  float z = pos_b[0];
#pragma unroll
  for (int p = 0; p < 16; ++p) z += pos_emb[t * 16 + p] * pos_w[p];
  wts[t] = 1.f / (1.f + expf(-z));
}

// ---------------- transpose + hi/lo fp16 split: W[K][N] fp32 -> Th/Tl[N][K]
__global__ __launch_bounds__(256) void transpose_split(
    const float* __restrict__ W, _Float16* __restrict__ Th,
    _Float16* __restrict__ Tl, int N, int kshift)
{
  const int idx = blockIdx.x * 256 + threadIdx.x;
  const int K = 1 << kshift;
  const int k = idx & (K - 1);
  const int n = idx >> kshift;
  const float w = W[(size_t)k * N + n];
  const _Float16 h = (_Float16)w;
  Th[idx] = h;
  Tl[idx] = (_Float16)(w - (float)h);
}

// ---------------- split-fp16 MFMA GEMM: C[M,N] = A[M,K] @ (Bh+Bl)[N,K]^T
// v11: v10's async global_load_lds(16B) staging with the CORRECTED row-pair
// swizzle (v10's mask overflowed the 64B row -> NaN). Staging source address
// carries the inverse permutation (both-sides rule): lane l -> super-row
// l>>3, granule l&7; logical granule g=(l&7)^(l>>3).
template <int EPI>
__global__ __launch_bounds__(256) void hgemm(
    const int* __restrict__ seq, const float* __restrict__ embed,
    const _Float16* __restrict__ Ah, const _Float16* __restrict__ Al,
    const _Float16* __restrict__ Bh, const _Float16* __restrict__ Bl,
    const float* __restrict__ bias, const float* __restrict__ bias2,
    float* __restrict__ Xout, _Float16* __restrict__ Oh, _Float16* __restrict__ Ol,
    float* __restrict__ ks, float* __restrict__ ke,
    int K, int N, int tok0c)
{
  __shared__ __align__(16) _Float16 lds[4][128 * 32];   // Ahi, Alo, Bhi, Blo
  const int tid  = threadIdx.x;
  const int lane = tid & 63;
  const int wv   = tid >> 6;
  const int wm   = (wv >> 1) * 64;
  const int wn   = (wv & 1) * 64;
  const int bm0  = blockIdx.y * 128;
  const int bn0  = blockIdx.x * 128;

  f32x4 acc[4][4];
#pragma unroll
  for (int i = 0; i < 4; ++i)
#pragma unroll
    for (int j = 0; j < 4; ++j) acc[i][j] = {0.f, 0.f, 0.f, 0.f};

  // async staging geometry (it=0 rows wv*16.., it=1 +64): lane l writes phys
  // 16B granule (super-row l>>3, slot l&7); inverse-swizzled global source:
  const int sl   = lane >> 3;                 // local super-row 0..7
  const int gg   = (lane & 7) ^ sl;           // logical granule
  const int trow = wv * 16 + sl * 2 + (gg >> 2);
  const int tcol = (gg & 3) * 8;              // halves within the 32-half k-step
  const size_t brow0 = (size_t)(bn0 + trow) * K + tcol;
  const size_t brow1 = (size_t)(bn0 + trow + 64) * K + tcol;
  size_t arow0 = 0, arow1 = 0;
  const float* gAe = nullptr;
  if constexpr (EPI == 0) {
    const int sr = tid >> 1;
    const int tokrow = seq[tok0c + bm0 + sr];
    gAe = embed + (size_t)tokrow * kH + ((tid & 1) << 4);
  } else {
    arow0 = (size_t)(bm0 + trow) * K + tcol;
    arow1 = (size_t)(bm0 + trow + 64) * K + tcol;
  }
  // wave-uniform LDS bases (halves)
  const int lb0 = wv * 512;
  const int lb1 = 2048 + wv * 512;

  const int lrow = lane & 15;
  const int lk   = (lane >> 4) * 8;

  for (int k0 = 0; k0 < K; k0 += 32) {
    float4 a0, a1, a2, a3;
    if constexpr (EPI == 0) {
      a0 = *(const float4*)(gAe + k0);
      a1 = *(const float4*)(gAe + k0 + 4);
      a2 = *(const float4*)(gAe + k0 + 8);
      a3 = *(const float4*)(gAe + k0 + 12);
    }
    __syncthreads();   // previous iteration's fragment reads done
    if constexpr (EPI != 0) {
      gload16(Ah + arow0 + k0, &lds[0][lb0]);
      gload16(Ah + arow1 + k0, &lds[0][lb1]);
      gload16(Al + arow0 + k0, &lds[1][lb0]);
      gload16(Al + arow1 + k0, &lds[1][lb1]);
    }
    gload16(Bh + brow0 + k0, &lds[2][lb0]);
    gload16(Bh + brow1 + k0, &lds[2][lb1]);
    gload16(Bl + brow0 + k0, &lds[3][lb0]);
    gload16(Bl + brow1 + k0, &lds[3][lb1]);
    if constexpr (EPI == 0) {
      const float vv[16] = {a0.x,a0.y,a0.z,a0.w, a1.x,a1.y,a1.z,a1.w,
                            a2.x,a2.y,a2.z,a2.w, a3.x,a3.y,a3.z,a3.w};
      union { _Float16 h[16]; uint4 u[2]; } ph, pl;
#pragma unroll
      for (int i = 0; i < 16; ++i) fsplit(vv[i], ph.h[i], pl.h[i]);
      const int sr = tid >> 1;
      const int sc = (tid & 1) << 4;
      *(uint4*)&lds[0][hswz(sr, sc)]     = ph.u[0];
      *(uint4*)&lds[0][hswz(sr, sc + 8)] = ph.u[1];
      *(uint4*)&lds[1][hswz(sr, sc)]     = pl.u[0];
      *(uint4*)&lds[1][hswz(sr, sc + 8)] = pl.u[1];
    }
    __syncthreads();   // drains vmcnt (async staging) + lgkm (ds writes)

    f16x8 fBh[4], fBl[4];
#pragma unroll
    for (int ni = 0; ni < 4; ++ni) {
      fBh[ni] = *(const f16x8*)&lds[2][hswz(wn + ni * 16 + lrow, lk)];
      fBl[ni] = *(const f16x8*)&lds[3][hswz(wn + ni * 16 + lrow, lk)];
    }
#pragma unroll
    for (int mi = 0; mi < 4; ++mi) {
      const f16x8 ah = *(const f16x8*)&lds[0][hswz(wm + mi * 16 + lrow, lk)];
      const f16x8 al = *(const f16x8*)&lds[1][hswz(wm + mi * 16 + lrow, lk)];
#pragma unroll
      for (int ni = 0; ni < 4; ++ni) {
        acc[mi][ni] = __builtin_amdgcn_mfma_f32_16x16x32_f16(ah, fBh[ni], acc[mi][ni], 0, 0, 0);
        acc[mi][ni] = __builtin_amdgcn_mfma_f32_16x16x32_f16(ah, fBl[ni], acc[mi][ni], 0, 0, 0);
        acc[mi][ni] = __builtin_amdgcn_mfma_f32_16x16x32_f16(al, fBh[ni], acc[mi][ni], 0, 0, 0);
      }
    }
  }

  const int erow0 = (lane >> 4) * 4;
  if constexpr (EPI == 0) {
#pragma unroll
    for (int mi = 0; mi < 4; ++mi)
#pragma unroll
      for (int ni = 0; ni < 4; ++ni) {
        const int gn = bn0 + wn + ni * 16 + (lane & 15);
        const float bv = bias[gn];
#pragma unroll
        for (int r = 0; r < 4; ++r) {
          const int gm = bm0 + wm + mi * 16 + erow0 + r;
          float v = fmaxf(acc[mi][ni][r] + bv, 0.f);
          const _Float16 h = (_Float16)v;
          Oh[(size_t)gm * N + gn] = h;
          Ol[(size_t)gm * N + gn] = (_Float16)(v - (float)h);
        }
      }
  } else if constexpr (EPI == 1) {
#pragma unroll
    for (int mi = 0; mi < 4; ++mi)
#pragma unroll
      for (int r = 0; r < 4; ++r) {
        const int gm = bm0 + wm + mi * 16 + erow0 + r;
        const int tok = seq[tok0c + gm];
        const float* er = embed + (size_t)tok * kH;
#pragma unroll
        for (int ni = 0; ni < 4; ++ni) {
          const int gn = bn0 + wn + ni * 16 + (lane & 15);
          Xout[(size_t)gm * N + gn] = acc[mi][ni][r] + bias[gn] + er[gn];
        }
      }
  } else {
    // EPI==2: write K as fp16 hi/lo pairs + per-quarter ssq partials (Xout).
    _Float16* kh_s = (_Float16*)ks;
    _Float16* kh_e = (_Float16*)ke;
    float s2[4][4];
#pragma unroll
    for (int mi = 0; mi < 4; ++mi)
#pragma unroll
      for (int r = 0; r < 4; ++r) s2[mi][r] = 0.f;
#pragma unroll
    for (int mi = 0; mi < 4; ++mi)
#pragma unroll
      for (int ni = 0; ni < 4; ++ni) {
        const int gn = bn0 + wn + ni * 16 + (lane & 15);
        const float bv = (gn < 256) ? bias[gn] : bias2[gn - 256];
        _Float16* Dh = (gn < 256) ? kh_s : kh_e;
        _Float16* Dl = (gn < 256) ? Oh : Ol;
        const int col = gn & 255;
#pragma unroll
        for (int r = 0; r < 4; ++r) {
          const int gm = bm0 + wm + mi * 16 + erow0 + r;
          const float v = acc[mi][ni][r] + bv;
          s2[mi][r] += v * v;
          _Float16 h, l;
          fsplit(v, h, l);
          Dh[(size_t)(tok0c + gm) * 256 + col] = h;
          Dl[(size_t)(tok0c + gm) * 256 + col] = l;
        }
      }
    // deterministic per-quarter partial sums: ssqPart[mat][tok][half*2 + (wv&1)]
    const int matq  = bn0 >> 8;
    const int halfq = (bn0 >> 7) & 1;
#pragma unroll
    for (int mi = 0; mi < 4; ++mi)
#pragma unroll
      for (int r = 0; r < 4; ++r) {
        float s2v = s2[mi][r];
        s2v += __shfl_xor(s2v, 1);
        s2v += __shfl_xor(s2v, 2);
        s2v += __shfl_xor(s2v, 4);
        s2v += __shfl_xor(s2v, 8);
        if ((lane & 15) == 0) {
          const int gm = bm0 + wm + mi * 16 + erow0 + r;
          Xout[((size_t)matq * kTok + (size_t)(tok0c + gm)) * 4 + halfq * 2 + (wv & 1)] = s2v;
        }
      }
  }
}

// ---------------- LayerNorm: x fp32 -> hi/lo fp16
__global__ __launch_bounds__(256) void ln_split(
    const float* __restrict__ x, const float* __restrict__ g,
    const float* __restrict__ bta, _Float16* __restrict__ hh,
    _Float16* __restrict__ hl)
{
  const int wid  = threadIdx.x >> 6;
  const int lane = threadIdx.x & 63;
  const int ltok = blockIdx.x * 4 + wid;
  const float* xp = x + (size_t)ltok * kH;
  const float4 v0 = *(const float4*)(xp + lane * 8);
  const float4 v1 = *(const float4*)(xp + lane * 8 + 4);
  float s  = v0.x + v0.y + v0.z + v0.w + v1.x + v1.y + v1.z + v1.w;
  float ss = v0.x * v0.x + v0.y * v0.y + v0.z * v0.z + v0.w * v0.w +
             v1.x * v1.x + v1.y * v1.y + v1.z * v1.z + v1.w * v1.w;
#pragma unroll
  for (int m = 1; m < 64; m <<= 1) { s += __shfl_xor(s, m); ss += __shfl_xor(ss, m); }
  const float mu  = s * (1.f / kH);
  const float var = ss * (1.f / kH) - mu * mu;
  const float rs  = 1.f / sqrtf(var + 1e-5f);
  const float4 g0 = *(const float4*)(g + lane * 8);
  const float4 g1 = *(const float4*)(g + lane * 8 + 4);
  const float4 b0 = *(const float4*)(bta + lane * 8);
  const float4 b1 = *(const float4*)(bta + lane * 8 + 4);
  const float vv[8] = {v0.x, v0.y, v0.z, v0.w, v1.x, v1.y, v1.z, v1.w};
  const float gg[8] = {g0.x, g0.y, g0.z, g0.w, g1.x, g1.y, g1.z, g1.w};
  const float bb[8] = {b0.x, b0.y, b0.z, b0.w, b1.x, b1.y, b1.z, b1.w};
  union { _Float16 h[8]; uint4 u; } ph, pl;
#pragma unroll
  for (int i = 0; i < 8; ++i) {
    const float o = (vv[i] - mu) * rs * gg[i] + bb[i];
    fsplit(o, ph.h[i], pl.h[i]);
  }
  *(uint4*)(hh + (size_t)ltok * kH + lane * 8) = ph.u;
  *(uint4*)(hl + (size_t)ltok * kH + lane * 8) = pl.u;
}

// ---------------- T precompute: T = (I + diag(aS)*tril_strict(K K^T))^{-1}
// One WG (1 wave) per (b, mat, ck): 2048 independent problems.
// wg = (b*2+mat)*16 + ck. Output Th/Tl[wg][t][t'] fp16 hi/lo, row-major.
__global__ __launch_bounds__(64) void tinv_kernel(
    const _Float16* __restrict__ khs, const _Float16* __restrict__ kls,
    const _Float16* __restrict__ khe, const _Float16* __restrict__ kle,
    const float* __restrict__ ssqP, const float* __restrict__ wts,
    _Float16* __restrict__ Tgh, _Float16* __restrict__ Tgl)
{
  __shared__ float Gs[64][68];   // aS-scaled G (row-scaled); stride 68 (16B-aligned rows)
  const int lane = threadIdx.x;
  const int l15  = lane & 15;
  const int quad = lane >> 4;
  const int wg   = blockIdx.x;
  const int ck   = wg & 15;
  const int mat  = (wg >> 4) & 1;
  const int b    = wg >> 5;
  const _Float16* Kh = (mat ? khe : khs) + (size_t)b * (1024 * 256) + (size_t)ck * 64 * 256;
  const _Float16* Kl = (mat ? kle : kls) + (size_t)b * (1024 * 256) + (size_t)ck * 64 * 256;

  // aS for token t = lane
  const float4 sq = *(const float4*)(ssqP + ((size_t)mat * kTok + (size_t)b * 1024 + ck * 64 + lane) * 4);
  const float w  = mat ? wts[ck * 64 + lane] : 1.f;
  const float aS = w / (sq.x + sq.y + sq.z + sq.w + 1e-6f);

  // G = K K^T via split-fp16 MFMA
  f32x4 D[16];
#pragma unroll
  for (int i = 0; i < 16; ++i) D[i] = {0.f, 0.f, 0.f, 0.f};
#pragma unroll
  for (int kit = 0; kit < 8; ++kit) {
    f16x8 fh[4], fl[4];
#pragma unroll
    for (int mi = 0; mi < 4; ++mi) {
      fh[mi] = *(const f16x8*)(Kh + (size_t)(mi * 16 + l15) * 256 + kit * 32 + quad * 8);
      fl[mi] = *(const f16x8*)(Kl + (size_t)(mi * 16 + l15) * 256 + kit * 32 + quad * 8);
    }
#pragma unroll
    for (int mi = 0; mi < 4; ++mi)
#pragma unroll
      for (int ni = 0; ni < 4; ++ni) {
        f32x4 d = D[mi * 4 + ni];
        d = __builtin_amdgcn_mfma_f32_16x16x32_f16(fh[mi], fh[ni], d, 0, 0, 0);
        d = __builtin_amdgcn_mfma_f32_16x16x32_f16(fh[mi], fl[ni], d, 0, 0, 0);
        d = __builtin_amdgcn_mfma_f32_16x16x32_f16(fl[mi], fh[ni], d, 0, 0, 0);
        D[mi * 4 + ni] = d;
      }
  }
  // scatter with per-row aS scale: L[t][t'] = aS[t] * G[t][t']
#pragma unroll
  for (int mi = 0; mi < 4; ++mi)
#pragma unroll
    for (int ni = 0; ni < 4; ++ni)
#pragma unroll
      for (int r = 0; r < 4; ++r) {
        const int row = mi * 16 + quad * 4 + r;
        const float as_r = __shfl(aS, row);
        Gs[row][ni * 16 + l15] = as_r * D[mi * 4 + ni][r];
      }
  __syncthreads();

  // unit-lower-triangular inverse, column j = lane; x kept in registers
  float x[64];
#pragma unroll
  for (int t = 0; t < 64; ++t) x[t] = (t == lane) ? 1.f : 0.f;
#pragma unroll
  for (int t = 1; t < 64; ++t) {
    float acc = 0.f;
    const int n4 = t >> 2;
#pragma unroll
    for (int q4 = 0; q4 < 16; ++q4) {
      if (q4 >= n4) break;
      const float4 g = *(const float4*)&Gs[t][q4 * 4];
      acc += g.x * x[q4 * 4] + g.y * x[q4 * 4 + 1] + g.z * x[q4 * 4 + 2] + g.w * x[q4 * 4 + 3];
    }
#pragma unroll
    for (int tp = 0; tp < 4; ++tp) {
      const int ti = n4 * 4 + tp;
      if (ti >= t) break;
      acc += Gs[t][ti] * x[ti];
    }
    x[t] -= acc;
  }
  if (ck == 15) x[63] = 0.f;   // token L-1 is the query only: U row 63 = 0

  // store transposed (x = column lane of T): Tg[t][t'=lane]
  const size_t base = (size_t)wg * 4096;
#pragma unroll
  for (int t = 0; t < 64; ++t) {
    _Float16 h, l;
    fsplit(x[t], h, l);
    Tgh[base + t * 64 + lane] = h;
    Tgl[base + t * 64 + lane] = l;
  }
}

// ---------------- chunked WY delta-rule scan (v9 structure, unchanged).
struct HTile { _Float16 h[4608], l[4608]; };   // [64][72] halves hi/lo, 18432 B

__global__ __launch_bounds__(256) void scan_chunked(
    const _Float16* __restrict__ khs, const _Float16* __restrict__ kls,
    const _Float16* __restrict__ khe, const _Float16* __restrict__ kle,
    const float* __restrict__ ssqP, const float* __restrict__ wts,
    const _Float16* __restrict__ Tgh, const _Float16* __restrict__ Tgl,
    float* __restrict__ c_out)
{
  __shared__ HTile Sb[2];                                   // S^T dbuf 36864 B
  __shared__ union { HTile t; float cred[4][64]; } Yb;      // Y^T      18432 B
  __shared__ HTile Ub;                                      // U^T      18432 B

  const int tid  = threadIdx.x;
  const int lane = tid & 63;
  const int wv   = tid >> 6;
  const int l15  = lane & 15;
  const int quad = lane >> 4;
  // XCD-affinity decode (bijective): quarters q=0..3 of one (b,mat) share wg%8
  const int wg   = blockIdx.x;
  const int grp  = (wg & 7) + ((wg >> 5) << 3);   // 0..127
  const int q    = (wg >> 3) & 3;
  const int b    = grp >> 1;
  const int mat  = grp & 1;
  const int j0   = q * 64;
  const _Float16* Kh = (mat ? khe : khs) + (size_t)b * (1024 * 256);
  const _Float16* Kl = (mat ? kle : kls) + (size_t)b * (1024 * 256);
  const _Float16* Tbh = Tgh + (size_t)((b * 2 + mat) * 16) * 4096;
  const _Float16* Tbl = Tgl + (size_t)((b * 2 + mat) * 16) * 4096;

  // S[p*4+nt]: rows p*64 + wv*16 + quad*4 + r ; cols nt*16 + l15 (WG-local j)
  f32x4 S[16];
#pragma unroll
  for (int i = 0; i < 16; ++i) S[i] = {0.f, 0.f, 0.f, 0.f};

  for (int ck = 0; ck < 16; ++ck) {
    const int tok0 = ck * 64;

    // ---- per-own-row scalars (global, tiny, latency hidden under staging)
    float myw[4], mya[4], kvv[4][4];
#pragma unroll
    for (int r = 0; r < 4; ++r) {
      const int t = tok0 + wv * 16 + quad * 4 + r;
      const float4 sq = *(const float4*)(ssqP + ((size_t)mat * kTok + (size_t)b * 1024 + t) * 4);
      const float w = mat ? wts[t] : 1.f;
      myw[r] = w;
      mya[r] = w / (sq.x + sq.y + sq.z + sq.w + 1e-6f);
#pragma unroll
      for (int nt = 0; nt < 4; ++nt) {
        const size_t go = (size_t)t * 256 + j0 + nt * 16 + l15;
        kvv[r][nt] = (float)Kh[go] + (float)Kl[go];
      }
    }
    // ---- T A-fragments for this chunk (global, row-major contiguous)
    f16x8 tah[2], tal[2];
#pragma unroll
    for (int kit = 0; kit < 2; ++kit) {
      const size_t to = (size_t)ck * 4096 + (size_t)(wv * 16 + l15) * 64 + kit * 32 + quad * 8;
      tah[kit] = *(const f16x8*)(Tbh + to);
      tal[kit] = *(const f16x8*)(Tbl + to);
    }
    // ---- Q A-frag panel-0 prefetch (K rows, contiguous in d)
    const _Float16* arow_h = Kh + (size_t)(tok0 + wv * 16 + l15) * 256 + quad * 8;
    const _Float16* arow_l = Kl + (size_t)(tok0 + wv * 16 + l15) * 256 + quad * 8;
    f16x8 a0h = *(const f16x8*)(arow_h);
    f16x8 a1h = *(const f16x8*)(arow_h + 32);
    f16x8 a0l = *(const f16x8*)(arow_l);
    f16x8 a1l = *(const f16x8*)(arow_l + 32);

    // ---- stage S^T panel 0 into Sb[0]
#pragma unroll
    for (int nt = 0; nt < 4; ++nt) {
      const f32x4 v = S[0 * 4 + nt];
      union { _Float16 h[4]; uint2 u; } qh, ql;
#pragma unroll
      for (int r = 0; r < 4; ++r) fsplit(v[r], qh.h[r], ql.h[r]);
      const int ix = (nt * 16 + l15) * 72 + wv * 16 + quad * 4;
      *(uint2*)&Sb[0].h[ix] = qh.u;
      *(uint2*)&Sb[0].l[ix] = ql.u;
    }
    __syncthreads();   // BP0

    // ---- Q = K S^T over 4 d-panels
    f32x4 Qa[4];
#pragma unroll
    for (int i = 0; i < 4; ++i) Qa[i] = {0.f, 0.f, 0.f, 0.f};
#pragma unroll
    for (int p = 0; p < 4; ++p) {
      const int cur = p & 1;
      f16x8 n0h, n1h, n0l, n1l;
      if (p < 3) {
        n0h = *(const f16x8*)(arow_h + (p + 1) * 64);
        n1h = *(const f16x8*)(arow_h + (p + 1) * 64 + 32);
        n0l = *(const f16x8*)(arow_l + (p + 1) * 64);
        n1l = *(const f16x8*)(arow_l + (p + 1) * 64 + 32);
        // stage next S^T panel (its readers finished at the p-1 barrier)
#pragma unroll
        for (int nt = 0; nt < 4; ++nt) {
          const f32x4 v = S[(p + 1) * 4 + nt];
          union { _Float16 h[4]; uint2 u; } sh2, sl2;
#pragma unroll
          for (int r = 0; r < 4; ++r) fsplit(v[r], sh2.h[r], sl2.h[r]);
          const int ix = (nt * 16 + l15) * 72 + wv * 16 + quad * 4;
          *(uint2*)&Sb[1 - cur].h[ix] = sh2.u;
          *(uint2*)&Sb[1 - cur].l[ix] = sl2.u;
        }
      }
#pragma unroll
      for (int kit = 0; kit < 2; ++kit) {
        const f16x8 ah = kit ? a1h : a0h;
        const f16x8 al = kit ? a1l : a0l;
#pragma unroll
        for (int nt = 0; nt < 4; ++nt) {
          const int ix = (nt * 16 + l15) * 72 + kit * 32 + quad * 8;
          const f16x8 bh = *(const f16x8*)&Sb[cur].h[ix];
          const f16x8 bl = *(const f16x8*)&Sb[cur].l[ix];
          Qa[nt] = __builtin_amdgcn_mfma_f32_16x16x32_f16(ah, bh, Qa[nt], 0, 0, 0);
          Qa[nt] = __builtin_amdgcn_mfma_f32_16x16x32_f16(ah, bl, Qa[nt], 0, 0, 0);
          Qa[nt] = __builtin_amdgcn_mfma_f32_16x16x32_f16(al, bh, Qa[nt], 0, 0, 0);
        }
      }
      if (p < 3) { a0h = n0h; a1h = n1h; a0l = n0l; a1l = n1l; }
      __syncthreads();   // end of panel p
    }

    // ---- Y = W*Kv - A*Q, stage Y^T[j][t]
#pragma unroll
    for (int nt = 0; nt < 4; ++nt) {
      union { _Float16 h[4]; uint2 u; } yh, yl;
#pragma unroll
      for (int r = 0; r < 4; ++r) {
        const float y = myw[r] * kvv[r][nt] - mya[r] * Qa[nt][r];
        fsplit(y, yh.h[r], yl.h[r]);
      }
      const int ix = (nt * 16 + l15) * 72 + wv * 16 + quad * 4;
      *(uint2*)&Yb.t.h[ix] = yh.u;
      *(uint2*)&Yb.t.l[ix] = yl.u;
    }
    __syncthreads();   // BY

    // ---- U = T*Y
    f32x4 Ua[4];
#pragma unroll
    for (int i = 0; i < 4; ++i) Ua[i] = {0.f, 0.f, 0.f, 0.f};
#pragma unroll
    for (int kit = 0; kit < 2; ++kit)
#pragma unroll
      for (int nt = 0; nt < 4; ++nt) {
        const int ix = (nt * 16 + l15) * 72 + kit * 32 + quad * 8;
        const f16x8 yh = *(const f16x8*)&Yb.t.h[ix];
        const f16x8 yl = *(const f16x8*)&Yb.t.l[ix];
        Ua[nt] = __builtin_amdgcn_mfma_f32_16x16x32_f16(tah[kit], yh, Ua[nt], 0, 0, 0);
        Ua[nt] = __builtin_amdgcn_mfma_f32_16x16x32_f16(tah[kit], yl, Ua[nt], 0, 0, 0);
        Ua[nt] = __builtin_amdgcn_mfma_f32_16x16x32_f16(tal[kit], yh, Ua[nt], 0, 0, 0);
      }
    // stage U^T[j][t]
#pragma unroll
    for (int nt = 0; nt < 4; ++nt) {
      union { _Float16 h[4]; uint2 u; } uh, ul;
#pragma unroll
      for (int r = 0; r < 4; ++r) fsplit(Ua[nt][r], uh.h[r], ul.h[r]);
      const int ix = (nt * 16 + l15) * 72 + wv * 16 + quad * 4;
      *(uint2*)&Ub.h[ix] = uh.u;
      *(uint2*)&Ub.l[ix] = ul.u;
    }
    __syncthreads();   // BU

    // ---- S += K^T U, barrier-free (A-frags = L2-hot scalar global loads)
#pragma unroll
    for (int p = 0; p < 4; ++p) {
      union { _Float16 e[8]; f16x8 v; } kah[2], kal[2];
#pragma unroll
      for (int kit = 0; kit < 2; ++kit)
#pragma unroll
        for (int jj = 0; jj < 8; ++jj) {
          const size_t gko = (size_t)(tok0 + kit * 32 + quad * 8 + jj) * 256
                           + p * 64 + wv * 16 + l15;
          kah[kit].e[jj] = Kh[gko];
          kal[kit].e[jj] = Kl[gko];
        }
#pragma unroll
      for (int kit = 0; kit < 2; ++kit)
#pragma unroll
        for (int nt = 0; nt < 4; ++nt) {
          const int ix = (nt * 16 + l15) * 72 + kit * 32 + quad * 8;
          const f16x8 ubh = *(const f16x8*)&Ub.h[ix];
          const f16x8 ubl = *(const f16x8*)&Ub.l[ix];
          f32x4 s = S[p * 4 + nt];
          s = __builtin_amdgcn_mfma_f32_16x16x32_f16(kah[kit].v, ubh, s, 0, 0, 0);
          s = __builtin_amdgcn_mfma_f32_16x16x32_f16(kah[kit].v, ubl, s, 0, 0, 0);
          s = __builtin_amdgcn_mfma_f32_16x16x32_f16(kal[kit].v, ubh, s, 0, 0, 0);
          S[p * 4 + nt] = s;
        }
    }
    // next chunk's BP0 orders Ub WAR and Sb reuse
  }

  // ---- readout: c[col] = sum_rows S[row][col] * k_last[row]
  float part[4] = {0.f, 0.f, 0.f, 0.f};
  const size_t lastoff = (size_t)(kL - 1) * 256;
#pragma unroll
  for (int p = 0; p < 4; ++p) {
    float klr[4];
#pragma unroll
    for (int r = 0; r < 4; ++r) {
      const int row = p * 64 + wv * 16 + quad * 4 + r;
      klr[r] = (float)Kh[lastoff + row] + (float)Kl[lastoff + row];
    }
#pragma unroll
    for (int nt = 0; nt < 4; ++nt)
#pragma unroll
      for (int r = 0; r < 4; ++r) part[nt] += S[p * 4 + nt][r] * klr[r];
  }
#pragma unroll
  for (int nt = 0; nt < 4; ++nt) {
    part[nt] += __shfl_xor(part[nt], 16);
    part[nt] += __shfl_xor(part[nt], 32);
  }
  __syncthreads();   // all prior LDS reads done before cred aliases Yb
  if (lane < 16) {
#pragma unroll
    for (int nt = 0; nt < 4; ++nt) Yb.cred[wv][nt * 16 + l15] = part[nt];
  }
  __syncthreads();
  if (tid < 64) {
    const float c = Yb.cred[0][tid] + Yb.cred[1][tid] + Yb.cred[2][tid] + Yb.cred[3][tid];
    c_out[(size_t)b * 512 + mat * 256 + j0 + tid] = c;
  }
}

// ---------------- output GEMM: (64 x 512) @ (512 x 32000) + out_b -> fp32
__global__ __launch_bounds__(256) void out_gemm(
    const float* __restrict__ A, const float* __restrict__ Bm,
    const float* __restrict__ bias, float* __restrict__ C)
{
  __shared__ float As[16][64];
  __shared__ float Bs[16][128];
  const int tid = threadIdx.x;
  const int bn0 = blockIdx.x * 128;
  const int tm = tid >> 4, tn = tid & 15;
  float acc[4][8];
#pragma unroll
  for (int i = 0; i < 4; ++i)
#pragma unroll
    for (int j = 0; j < 8; ++j) acc[i][j] = 0.f;

  const int am  = tid & 63;
  const int ak  = (tid >> 6) * 4;
  const int bkr = tid >> 5;
  const int bcg = (tid & 31) * 4;

  for (int k0 = 0; k0 < kH; k0 += 16) {
    const float4 a0 = *(const float4*)(A + (size_t)am * kH + k0 + ak);
    const float4 b0 = *(const float4*)(Bm + (size_t)(k0 + bkr) * kV + bn0 + bcg);
    const float4 b1 = *(const float4*)(Bm + (size_t)(k0 + bkr + 8) * kV + bn0 + bcg);
    __syncthreads();
    As[ak + 0][am] = a0.x; As[ak + 1][am] = a0.y;
    As[ak + 2][am] = a0.z; As[ak + 3][am] = a0.w;
    *(float4*)&Bs[bkr][bcg]     = b0;
    *(float4*)&Bs[bkr + 8][bcg] = b1;
    __syncthreads();
#pragma unroll
    for (int kk = 0; kk < 16; ++kk) {
      const float4 aA = *(const float4*)&As[kk][tm * 4];
      const float4 bA = *(const float4*)&Bs[kk][tn * 4];
      const float4 bB = *(const float4*)&Bs[kk][64 + tn * 4];
      const float av[4] = {aA.x, aA.y, aA.z, aA.w};
      const float bv[8] = {bA.x, bA.y, bA.z, bA.w, bB.x, bB.y, bB.z, bB.w};
#pragma unroll
      for (int i = 0; i < 4; ++i)
#pragma unroll
        for (int j = 0; j < 8; ++j) acc[i][j] += av[i] * bv[j];
    }
  }

#pragma unroll
  for (int i = 0; i < 4; ++i) {
    const int row = tm * 4 + i;
#pragma unroll
    for (int hh = 0; hh < 2; ++hh) {
      const int n0 = bn0 + tn * 4 + hh * 64;
      const float4 bb = *(const float4*)(bias + n0);
      float4 o;
      o.x = acc[i][hh * 4 + 0] + bb.x;
      o.y = acc[i][hh * 4 + 1] + bb.y;
      o.z = acc[i][hh * 4 + 2] + bb.z;
      o.w = acc[i][hh * 4 + 3] + bb.w;
      *(float4*)(C + (size_t)row * kV + n0) = o;
    }
  }
}

}  // namespace

extern "C" void kernel_launch(void* const* d_in, const int* in_sizes, int n_in,
                              void* d_out, int out_size, void* d_ws, size_t ws_size,
                              hipStream_t stream)
{
  const int*   seq     = (const int*)  d_in[0];
  const float* embed   = (const float*)d_in[1];
  const float* w1      = (const float*)d_in[2];
  const float* b1      = (const float*)d_in[3];
  const float* w2      = (const float*)d_in[4];
  const float* b2      = (const float*)d_in[5];
  const float* ln_g    = (const float*)d_in[6];
  const float* ln_b    = (const float*)d_in[7];
  const float* sem_w   = (const float*)d_in[8];
  const float* sem_b   = (const float*)d_in[9];
  const float* epi_w   = (const float*)d_in[10];
  const float* epi_b   = (const float*)d_in[11];
  const float* out_w   = (const float*)d_in[12];
  const float* out_b   = (const float*)d_in[13];
  const float* pos_emb = (const float*)d_in[14];
  const float* pos_w   = (const float*)d_in[15];
  const float* pos_b   = (const float*)d_in[16];
  float* out = (float*)d_out;

  // chunk size: 16384 needs ~231 MB of ws; fall back to 8192 if tight.
  // ws_size is constant per process -> deterministic, graph-capture-safe.
  const int chunkN = (ws_size >= (size_t)240500000) ? 16384 : 8192;
  const int nch    = kTok / chunkN;

  char* p = (char*)d_ws;
  _Float16* w1th = (_Float16*)p; p += (size_t)1024 * 512 * 2;
  _Float16* w1tl = (_Float16*)p; p += (size_t)1024 * 512 * 2;
  _Float16* w2th = (_Float16*)p; p += (size_t)512 * 1024 * 2;
  _Float16* w2tl = (_Float16*)p; p += (size_t)512 * 1024 * 2;
  _Float16* wseh = (_Float16*)p; p += (size_t)512 * 512 * 2;
  _Float16* wsel = (_Float16*)p; p += (size_t)512 * 512 * 2;
  _Float16* t1h  = (_Float16*)p; p += (size_t)chunkN * 1024 * 2;
  _Float16* t1l  = (_Float16*)p; p += (size_t)chunkN * 1024 * 2;
  float*    x    = (float*)p;    p += (size_t)chunkN * kH * 4;
  _Float16* khs  = (_Float16*)p; p += (size_t)kTok * kHalf * 2;   // K hi/lo fp16
  _Float16* kls  = (_Float16*)p; p += (size_t)kTok * kHalf * 2;
  _Float16* khe  = (_Float16*)p; p += (size_t)kTok * kHalf * 2;
  _Float16* kle  = (_Float16*)p; p += (size_t)kTok * kHalf * 2;
  float*    wts  = (float*)p;    p += (size_t)kL * 4;
  float*    cout_= (float*)p;    p += (size_t)kB * 512 * 4;
  float*    ssqp = (float*)p;    p += (size_t)2 * kTok * 4 * 4;   // [mat][tok][4] partials
  _Float16* hh   = t1h;          // alias: t1 dead once x is written
  _Float16* hl   = t1l;
  // T buffers alias t1h/t1l (dead after the chunk loop): 2048 chunks x 64x64
  // fp16 hi/lo = 2 x 16.78 MB; t1h+t1l region is >= 33.55 MB in both paths.
  _Float16* Tgh = t1h;
  _Float16* Tgl = t1h + (size_t)2048 * 4096;

  pos_kernel<<<dim3((kL + 255) / 256), dim3(256), 0, stream>>>(pos_emb, pos_w, pos_b, wts);
  transpose_split<<<dim3(1024 * 512 / 256), dim3(256), 0, stream>>>(w1, w1th, w1tl, 1024, 9);
  transpose_split<<<dim3(512 * 1024 / 256), dim3(256), 0, stream>>>(w2, w2th, w2tl, 512, 10);
  transpose_split<<<dim3(256 * 512 / 256), dim3(256), 0, stream>>>(sem_w, wseh, wsel, 256, 9);
  transpose_split<<<dim3(256 * 512 / 256), dim3(256), 0, stream>>>(
      epi_w, wseh + (size_t)256 * 512, wsel + (size_t)256 * 512, 256, 9);

  for (int c = 0; c < nch; ++c) {
    const int tok0 = c * chunkN;
    hgemm<0><<<dim3(1024 / 128, chunkN / 128), dim3(256), 0, stream>>>(
        seq, embed, nullptr, nullptr, w1th, w1tl, b1, nullptr,
        nullptr, t1h, t1l, nullptr, nullptr, 512, 1024, tok0);
    hgemm<1><<<dim3(512 / 128, chunkN / 128), dim3(256), 0, stream>>>(
        seq, embed, t1h, t1l, w2th, w2tl, b2, nullptr,
        x, nullptr, nullptr, nullptr, nullptr, 1024, 512, tok0);
    ln_split<<<dim3(chunkN / 4), dim3(256), 0, stream>>>(x, ln_g, ln_b, hh, hl);
    hgemm<2><<<dim3(512 / 128, chunkN / 128), dim3(256), 0, stream>>>(
        seq, embed, hh, hl, wseh, wsel, sem_b, epi_b,
        ssqp, kls, kle, (float*)khs, (float*)khe,
        512, 512, tok0);
  }

  tinv_kernel<<<dim3(2048), dim3(64), 0, stream>>>(
      khs, kls, khe, kle, ssqp, wts, Tgh, Tgl);
  scan_chunked<<<dim3(512), dim3(256), 0, stream>>>(
      khs, kls, khe, kle, ssqp, wts, Tgh, Tgl, cout_);
  out_gemm<<<dim3(kV / 128), dim3(256), 0, stream>>>(cout_, out_w, out_b, out);

  (void)in_sizes; (void)n_in; (void)out_size;
}

// Round 8
// 1089.671 us; speedup vs baseline: 1.6336x; 1.0800x over previous
//
#include <hip/hip_runtime.h>
#include <hip/hip_bf16.h>
#include <math.h>

namespace {

constexpr int kH     = 512;
constexpr int kL     = 1024;
constexpr int kB     = 64;
constexpr int kHalf  = 256;
constexpr int kV     = 32000;
constexpr int kTok   = kB * kL;     // 65536

using f32x4 = __attribute__((ext_vector_type(4))) float;
using f16x8 = __attribute__((ext_vector_type(8))) _Float16;

__device__ inline void fsplit(float v, _Float16& h, _Float16& l) {
  h = (_Float16)v;
  l = (_Float16)(v - (float)h);
}

// async 16B global->LDS (gfx950). dst must be wave-uniform base; lane l
// receives bytes [l*16, l*16+16).
typedef __attribute__((address_space(3))) void lds_vp;
typedef const __attribute__((address_space(1))) void glb_vp;
__device__ inline void gload16(const void* g, void* l) {
  __builtin_amdgcn_global_load_lds((glb_vp*)g, (lds_vp*)l, 16, 0, 0);
}

// Row-PAIR swizzled half-tile index for [128][32]-half tiles stored flat.
// 64B rows only have 4 granules, so the 8-slot XOR runs across row pairs:
// super-row sr=row>>1 (128B), granule g=(row&1)*4+col/8, g'=g^(sr&7).
// Per-16-lane b128 fragment read: each g' hit exactly twice -> 2-way (free).
__device__ inline int hswz(int row, int col) {
  const int sr = row >> 1;
  const int g  = ((row & 1) << 2) | (col >> 3);
  return sr * 64 + (((g ^ (sr & 7)) << 3) | (col & 7));
}

// ---------------- positional weights
__global__ void pos_kernel(const float* __restrict__ pos_emb,
                           const float* __restrict__ pos_w,
                           const float* __restrict__ pos_b,
                           float* __restrict__ wts)
{
  int t = blockIdx.x * blockDim.x + threadIdx.x;
  if (t >= kL) return;
  float z = pos_b[0];
#pragma unroll
  for (int p = 0; p < 16; ++p) z += pos_emb[t * 16 + p] * pos_w[p];
  wts[t] = 1.f / (1.f + expf(-z));
}

// ---------------- transpose + hi/lo fp16 split: W[K][N] fp32 -> Th/Tl[N][K]
__global__ __launch_bounds__(256) void transpose_split(
    const float* __restrict__ W, _Float16* __restrict__ Th,
    _Float16* __restrict__ Tl, int N, int kshift)
{
  const int idx = blockIdx.x * 256 + threadIdx.x;
  const int K = 1 << kshift;
  const int k = idx & (K - 1);
  const int n = idx >> kshift;
  const float w = W[(size_t)k * N + n];
  const _Float16 h = (_Float16)w;
  Th[idx] = h;
  Tl[idx] = (_Float16)(w - (float)h);
}

// ---------------- mixed-precision MFMA GEMM: C = A(fp16) @ (Bh+Bl)[N,K]^T
// v12: A is plain fp16 (activations, random error ~2^-11 << bf16 output
// floor 2^-8); B (weights) stays split hi/lo. 2 MFMAs per product (was 3),
// 3 staged tiles (was 4), 12 LDS reads/wave/K-step (was 16). K outputs for
// the scan remain hi/lo (scan 3-product numerics untouched).
template <int EPI>
__global__ __launch_bounds__(256) void hgemm(
    const int* __restrict__ seq, const float* __restrict__ embed,
    const _Float16* __restrict__ Ah,
    const _Float16* __restrict__ Bh, const _Float16* __restrict__ Bl,
    const float* __restrict__ bias, const float* __restrict__ bias2,
    float* __restrict__ Xout, _Float16* __restrict__ Oh, _Float16* __restrict__ Ol,
    float* __restrict__ ks, float* __restrict__ ke,
    int K, int N, int tok0c)
{
  __shared__ __align__(16) _Float16 lds[3][128 * 32];   // A, Bhi, Blo
  const int tid  = threadIdx.x;
  const int lane = tid & 63;
  const int wv   = tid >> 6;
  const int wm   = (wv >> 1) * 64;
  const int wn   = (wv & 1) * 64;
  const int bm0  = blockIdx.y * 128;
  const int bn0  = blockIdx.x * 128;

  f32x4 acc[4][4];
#pragma unroll
  for (int i = 0; i < 4; ++i)
#pragma unroll
    for (int j = 0; j < 4; ++j) acc[i][j] = {0.f, 0.f, 0.f, 0.f};

  // async staging geometry (it=0 rows wv*16.., it=1 +64): lane l writes phys
  // 16B granule (super-row l>>3, slot l&7); inverse-swizzled global source:
  const int sl   = lane >> 3;                 // local super-row 0..7
  const int gg   = (lane & 7) ^ sl;           // logical granule
  const int trow = wv * 16 + sl * 2 + (gg >> 2);
  const int tcol = (gg & 3) * 8;              // halves within the 32-half k-step
  const size_t brow0 = (size_t)(bn0 + trow) * K + tcol;
  const size_t brow1 = (size_t)(bn0 + trow + 64) * K + tcol;
  size_t arow0 = 0, arow1 = 0;
  const float* gAe = nullptr;
  if constexpr (EPI == 0) {
    const int sr = tid >> 1;
    const int tokrow = seq[tok0c + bm0 + sr];
    gAe = embed + (size_t)tokrow * kH + ((tid & 1) << 4);
  } else {
    arow0 = (size_t)(bm0 + trow) * K + tcol;
    arow1 = (size_t)(bm0 + trow + 64) * K + tcol;
  }
  // wave-uniform LDS bases (halves)
  const int lb0 = wv * 512;
  const int lb1 = 2048 + wv * 512;

  const int lrow = lane & 15;
  const int lk   = (lane >> 4) * 8;

  for (int k0 = 0; k0 < K; k0 += 32) {
    float4 a0, a1, a2, a3;
    if constexpr (EPI == 0) {
      a0 = *(const float4*)(gAe + k0);
      a1 = *(const float4*)(gAe + k0 + 4);
      a2 = *(const float4*)(gAe + k0 + 8);
      a3 = *(const float4*)(gAe + k0 + 12);
    }
    __syncthreads();   // previous iteration's fragment reads done
    if constexpr (EPI != 0) {
      gload16(Ah + arow0 + k0, &lds[0][lb0]);
      gload16(Ah + arow1 + k0, &lds[0][lb1]);
    }
    gload16(Bh + brow0 + k0, &lds[1][lb0]);
    gload16(Bh + brow1 + k0, &lds[1][lb1]);
    gload16(Bl + brow0 + k0, &lds[2][lb0]);
    gload16(Bl + brow1 + k0, &lds[2][lb1]);
    if constexpr (EPI == 0) {
      const float vv[16] = {a0.x,a0.y,a0.z,a0.w, a1.x,a1.y,a1.z,a1.w,
                            a2.x,a2.y,a2.z,a2.w, a3.x,a3.y,a3.z,a3.w};
      union { _Float16 h[16]; uint4 u[2]; } ph;
#pragma unroll
      for (int i = 0; i < 16; ++i) ph.h[i] = (_Float16)vv[i];
      const int sr = tid >> 1;
      const int sc = (tid & 1) << 4;
      *(uint4*)&lds[0][hswz(sr, sc)]     = ph.u[0];
      *(uint4*)&lds[0][hswz(sr, sc + 8)] = ph.u[1];
    }
    __syncthreads();   // drains vmcnt (async staging) + lgkm (ds writes)

    f16x8 fBh[4], fBl[4];
#pragma unroll
    for (int ni = 0; ni < 4; ++ni) {
      fBh[ni] = *(const f16x8*)&lds[1][hswz(wn + ni * 16 + lrow, lk)];
      fBl[ni] = *(const f16x8*)&lds[2][hswz(wn + ni * 16 + lrow, lk)];
    }
#pragma unroll
    for (int mi = 0; mi < 4; ++mi) {
      const f16x8 ah = *(const f16x8*)&lds[0][hswz(wm + mi * 16 + lrow, lk)];
#pragma unroll
      for (int ni = 0; ni < 4; ++ni) {
        acc[mi][ni] = __builtin_amdgcn_mfma_f32_16x16x32_f16(ah, fBh[ni], acc[mi][ni], 0, 0, 0);
        acc[mi][ni] = __builtin_amdgcn_mfma_f32_16x16x32_f16(ah, fBl[ni], acc[mi][ni], 0, 0, 0);
      }
    }
  }

  const int erow0 = (lane >> 4) * 4;
  if constexpr (EPI == 0) {
#pragma unroll
    for (int mi = 0; mi < 4; ++mi)
#pragma unroll
      for (int ni = 0; ni < 4; ++ni) {
        const int gn = bn0 + wn + ni * 16 + (lane & 15);
        const float bv = bias[gn];
#pragma unroll
        for (int r = 0; r < 4; ++r) {
          const int gm = bm0 + wm + mi * 16 + erow0 + r;
          float v = fmaxf(acc[mi][ni][r] + bv, 0.f);
          Oh[(size_t)gm * N + gn] = (_Float16)v;
        }
      }
  } else if constexpr (EPI == 1) {
#pragma unroll
    for (int mi = 0; mi < 4; ++mi)
#pragma unroll
      for (int r = 0; r < 4; ++r) {
        const int gm = bm0 + wm + mi * 16 + erow0 + r;
        const int tok = seq[tok0c + gm];
        const float* er = embed + (size_t)tok * kH;
#pragma unroll
        for (int ni = 0; ni < 4; ++ni) {
          const int gn = bn0 + wn + ni * 16 + (lane & 15);
          Xout[(size_t)gm * N + gn] = acc[mi][ni][r] + bias[gn] + er[gn];
        }
      }
  } else {
    // EPI==2: write K as fp16 hi/lo pairs + per-quarter ssq partials (Xout).
    _Float16* kh_s = (_Float16*)ks;
    _Float16* kh_e = (_Float16*)ke;
    float s2[4][4];
#pragma unroll
    for (int mi = 0; mi < 4; ++mi)
#pragma unroll
      for (int r = 0; r < 4; ++r) s2[mi][r] = 0.f;
#pragma unroll
    for (int mi = 0; mi < 4; ++mi)
#pragma unroll
      for (int ni = 0; ni < 4; ++ni) {
        const int gn = bn0 + wn + ni * 16 + (lane & 15);
        const float bv = (gn < 256) ? bias[gn] : bias2[gn - 256];
        _Float16* Dh = (gn < 256) ? kh_s : kh_e;
        _Float16* Dl = (gn < 256) ? Oh : Ol;
        const int col = gn & 255;
#pragma unroll
        for (int r = 0; r < 4; ++r) {
          const int gm = bm0 + wm + mi * 16 + erow0 + r;
          const float v = acc[mi][ni][r] + bv;
          s2[mi][r] += v * v;
          _Float16 h, l;
          fsplit(v, h, l);
          Dh[(size_t)(tok0c + gm) * 256 + col] = h;
          Dl[(size_t)(tok0c + gm) * 256 + col] = l;
        }
      }
    // deterministic per-quarter partial sums: ssqPart[mat][tok][half*2 + (wv&1)]
    const int matq  = bn0 >> 8;
    const int halfq = (bn0 >> 7) & 1;
#pragma unroll
    for (int mi = 0; mi < 4; ++mi)
#pragma unroll
      for (int r = 0; r < 4; ++r) {
        float s2v = s2[mi][r];
        s2v += __shfl_xor(s2v, 1);
        s2v += __shfl_xor(s2v, 2);
        s2v += __shfl_xor(s2v, 4);
        s2v += __shfl_xor(s2v, 8);
        if ((lane & 15) == 0) {
          const int gm = bm0 + wm + mi * 16 + erow0 + r;
          Xout[((size_t)matq * kTok + (size_t)(tok0c + gm)) * 4 + halfq * 2 + (wv & 1)] = s2v;
        }
      }
  }
}

// ---------------- LayerNorm: x fp32 -> fp16 (hi only — v12 A-fp16 scheme)
__global__ __launch_bounds__(256) void ln_split(
    const float* __restrict__ x, const float* __restrict__ g,
    const float* __restrict__ bta, _Float16* __restrict__ hh)
{
  const int wid  = threadIdx.x >> 6;
  const int lane = threadIdx.x & 63;
  const int ltok = blockIdx.x * 4 + wid;
  const float* xp = x + (size_t)ltok * kH;
  const float4 v0 = *(const float4*)(xp + lane * 8);
  const float4 v1 = *(const float4*)(xp + lane * 8 + 4);
  float s  = v0.x + v0.y + v0.z + v0.w + v1.x + v1.y + v1.z + v1.w;
  float ss = v0.x * v0.x + v0.y * v0.y + v0.z * v0.z + v0.w * v0.w +
             v1.x * v1.x + v1.y * v1.y + v1.z * v1.z + v1.w * v1.w;
#pragma unroll
  for (int m = 1; m < 64; m <<= 1) { s += __shfl_xor(s, m); ss += __shfl_xor(ss, m); }
  const float mu  = s * (1.f / kH);
  const float var = ss * (1.f / kH) - mu * mu;
  const float rs  = 1.f / sqrtf(var + 1e-5f);
  const float4 g0 = *(const float4*)(g + lane * 8);
  const float4 g1 = *(const float4*)(g + lane * 8 + 4);
  const float4 b0 = *(const float4*)(bta + lane * 8);
  const float4 b1 = *(const float4*)(bta + lane * 8 + 4);
  const float vv[8] = {v0.x, v0.y, v0.z, v0.w, v1.x, v1.y, v1.z, v1.w};
  const float gg[8] = {g0.x, g0.y, g0.z, g0.w, g1.x, g1.y, g1.z, g1.w};
  const float bb[8] = {b0.x, b0.y, b0.z, b0.w, b1.x, b1.y, b1.z, b1.w};
  union { _Float16 h[8]; uint4 u; } ph;
#pragma unroll
  for (int i = 0; i < 8; ++i) {
    const float o = (vv[i] - mu) * rs * gg[i] + bb[i];
    ph.h[i] = (_Float16)o;
  }
  *(uint4*)(hh + (size_t)ltok * kH + lane * 8) = ph.u;
}

// ---------------- T precompute: T = (I + diag(aS)*tril_strict(K K^T))^{-1}
// One WG (1 wave) per (b, mat, ck): 2048 independent problems.
// wg = (b*2+mat)*16 + ck. Output Th/Tl[wg][t][t'] fp16 hi/lo, row-major.
__global__ __launch_bounds__(64) void tinv_kernel(
    const _Float16* __restrict__ khs, const _Float16* __restrict__ kls,
    const _Float16* __restrict__ khe, const _Float16* __restrict__ kle,
    const float* __restrict__ ssqP, const float* __restrict__ wts,
    _Float16* __restrict__ Tgh, _Float16* __restrict__ Tgl)
{
  __shared__ float Gs[64][68];   // aS-scaled G (row-scaled); stride 68 (16B-aligned rows)
  const int lane = threadIdx.x;
  const int l15  = lane & 15;
  const int quad = lane >> 4;
  const int wg   = blockIdx.x;
  const int ck   = wg & 15;
  const int mat  = (wg >> 4) & 1;
  const int b    = wg >> 5;
  const _Float16* Kh = (mat ? khe : khs) + (size_t)b * (1024 * 256) + (size_t)ck * 64 * 256;
  const _Float16* Kl = (mat ? kle : kls) + (size_t)b * (1024 * 256) + (size_t)ck * 64 * 256;

  // aS for token t = lane
  const float4 sq = *(const float4*)(ssqP + ((size_t)mat * kTok + (size_t)b * 1024 + ck * 64 + lane) * 4);
  const float w  = mat ? wts[ck * 64 + lane] : 1.f;
  const float aS = w / (sq.x + sq.y + sq.z + sq.w + 1e-6f);

  // G = K K^T via split-fp16 MFMA
  f32x4 D[16];
#pragma unroll
  for (int i = 0; i < 16; ++i) D[i] = {0.f, 0.f, 0.f, 0.f};
#pragma unroll
  for (int kit = 0; kit < 8; ++kit) {
    f16x8 fh[4], fl[4];
#pragma unroll
    for (int mi = 0; mi < 4; ++mi) {
      fh[mi] = *(const f16x8*)(Kh + (size_t)(mi * 16 + l15) * 256 + kit * 32 + quad * 8);
      fl[mi] = *(const f16x8*)(Kl + (size_t)(mi * 16 + l15) * 256 + kit * 32 + quad * 8);
    }
#pragma unroll
    for (int mi = 0; mi < 4; ++mi)
#pragma unroll
      for (int ni = 0; ni < 4; ++ni) {
        f32x4 d = D[mi * 4 + ni];
        d = __builtin_amdgcn_mfma_f32_16x16x32_f16(fh[mi], fh[ni], d, 0, 0, 0);
        d = __builtin_amdgcn_mfma_f32_16x16x32_f16(fh[mi], fl[ni], d, 0, 0, 0);
        d = __builtin_amdgcn_mfma_f32_16x16x32_f16(fl[mi], fh[ni], d, 0, 0, 0);
        D[mi * 4 + ni] = d;
      }
  }
  // scatter with per-row aS scale: L[t][t'] = aS[t] * G[t][t']
#pragma unroll
  for (int mi = 0; mi < 4; ++mi)
#pragma unroll
    for (int ni = 0; ni < 4; ++ni)
#pragma unroll
      for (int r = 0; r < 4; ++r) {
        const int row = mi * 16 + quad * 4 + r;
        const float as_r = __shfl(aS, row);
        Gs[row][ni * 16 + l15] = as_r * D[mi * 4 + ni][r];
      }
  __syncthreads();

  // unit-lower-triangular inverse, column j = lane; x kept in registers
  float x[64];
#pragma unroll
  for (int t = 0; t < 64; ++t) x[t] = (t == lane) ? 1.f : 0.f;
#pragma unroll
  for (int t = 1; t < 64; ++t) {
    float acc = 0.f;
    const int n4 = t >> 2;
#pragma unroll
    for (int q4 = 0; q4 < 16; ++q4) {
      if (q4 >= n4) break;
      const float4 g = *(const float4*)&Gs[t][q4 * 4];
      acc += g.x * x[q4 * 4] + g.y * x[q4 * 4 + 1] + g.z * x[q4 * 4 + 2] + g.w * x[q4 * 4 + 3];
    }
#pragma unroll
    for (int tp = 0; tp < 4; ++tp) {
      const int ti = n4 * 4 + tp;
      if (ti >= t) break;
      acc += Gs[t][ti] * x[ti];
    }
    x[t] -= acc;
  }
  if (ck == 15) x[63] = 0.f;   // token L-1 is the query only: U row 63 = 0

  // store transposed (x = column lane of T): Tg[t][t'=lane]
  const size_t base = (size_t)wg * 4096;
#pragma unroll
  for (int t = 0; t < 64; ++t) {
    _Float16 h, l;
    fsplit(x[t], h, l);
    Tgh[base + t * 64 + lane] = h;
    Tgl[base + t * 64 + lane] = l;
  }
}

// ---------------- chunked WY delta-rule scan (v9 structure, unchanged).
struct HTile { _Float16 h[4608], l[4608]; };   // [64][72] halves hi/lo, 18432 B

__global__ __launch_bounds__(256) void scan_chunked(
    const _Float16* __restrict__ khs, const _Float16* __restrict__ kls,
    const _Float16* __restrict__ khe, const _Float16* __restrict__ kle,
    const float* __restrict__ ssqP, const float* __restrict__ wts,
    const _Float16* __restrict__ Tgh, const _Float16* __restrict__ Tgl,
    float* __restrict__ c_out)
{
  __shared__ HTile Sb[2];                                   // S^T dbuf 36864 B
  __shared__ union { HTile t; float cred[4][64]; } Yb;      // Y^T      18432 B
  __shared__ HTile Ub;                                      // U^T      18432 B

  const int tid  = threadIdx.x;
  const int lane = tid & 63;
  const int wv   = tid >> 6;
  const int l15  = lane & 15;
  const int quad = lane >> 4;
  // XCD-affinity decode (bijective): quarters q=0..3 of one (b,mat) share wg%8
  const int wg   = blockIdx.x;
  const int grp  = (wg & 7) + ((wg >> 5) << 3);   // 0..127
  const int q    = (wg >> 3) & 3;
  const int b    = grp >> 1;
  const int mat  = grp & 1;
  const int j0   = q * 64;
  const _Float16* Kh = (mat ? khe : khs) + (size_t)b * (1024 * 256);
  const _Float16* Kl = (mat ? kle : kls) + (size_t)b * (1024 * 256);
  const _Float16* Tbh = Tgh + (size_t)((b * 2 + mat) * 16) * 4096;
  const _Float16* Tbl = Tgl + (size_t)((b * 2 + mat) * 16) * 4096;

  // S[p*4+nt]: rows p*64 + wv*16 + quad*4 + r ; cols nt*16 + l15 (WG-local j)
  f32x4 S[16];
#pragma unroll
  for (int i = 0; i < 16; ++i) S[i] = {0.f, 0.f, 0.f, 0.f};

  for (int ck = 0; ck < 16; ++ck) {
    const int tok0 = ck * 64;

    // ---- per-own-row scalars (global, tiny, latency hidden under staging)
    float myw[4], mya[4], kvv[4][4];
#pragma unroll
    for (int r = 0; r < 4; ++r) {
      const int t = tok0 + wv * 16 + quad * 4 + r;
      const float4 sq = *(const float4*)(ssqP + ((size_t)mat * kTok + (size_t)b * 1024 + t) * 4);
      const float w = mat ? wts[t] : 1.f;
      myw[r] = w;
      mya[r] = w / (sq.x + sq.y + sq.z + sq.w + 1e-6f);
#pragma unroll
      for (int nt = 0; nt < 4; ++nt) {
        const size_t go = (size_t)t * 256 + j0 + nt * 16 + l15;
        kvv[r][nt] = (float)Kh[go] + (float)Kl[go];
      }
    }
    // ---- T A-fragments for this chunk (global, row-major contiguous)
    f16x8 tah[2], tal[2];
#pragma unroll
    for (int kit = 0; kit < 2; ++kit) {
      const size_t to = (size_t)ck * 4096 + (size_t)(wv * 16 + l15) * 64 + kit * 32 + quad * 8;
      tah[kit] = *(const f16x8*)(Tbh + to);
      tal[kit] = *(const f16x8*)(Tbl + to);
    }
    // ---- Q A-frag panel-0 prefetch (K rows, contiguous in d)
    const _Float16* arow_h = Kh + (size_t)(tok0 + wv * 16 + l15) * 256 + quad * 8;
    const _Float16* arow_l = Kl + (size_t)(tok0 + wv * 16 + l15) * 256 + quad * 8;
    f16x8 a0h = *(const f16x8*)(arow_h);
    f16x8 a1h = *(const f16x8*)(arow_h + 32);
    f16x8 a0l = *(const f16x8*)(arow_l);
    f16x8 a1l = *(const f16x8*)(arow_l + 32);

    // ---- stage S^T panel 0 into Sb[0]
#pragma unroll
    for (int nt = 0; nt < 4; ++nt) {
      const f32x4 v = S[0 * 4 + nt];
      union { _Float16 h[4]; uint2 u; } qh, ql;
#pragma unroll
      for (int r = 0; r < 4; ++r) fsplit(v[r], qh.h[r], ql.h[r]);
      const int ix = (nt * 16 + l15) * 72 + wv * 16 + quad * 4;
      *(uint2*)&Sb[0].h[ix] = qh.u;
      *(uint2*)&Sb[0].l[ix] = ql.u;
    }
    __syncthreads();   // BP0

    // ---- Q = K S^T over 4 d-panels
    f32x4 Qa[4];
#pragma unroll
    for (int i = 0; i < 4; ++i) Qa[i] = {0.f, 0.f, 0.f, 0.f};
#pragma unroll
    for (int p = 0; p < 4; ++p) {
      const int cur = p & 1;
      f16x8 n0h, n1h, n0l, n1l;
      if (p < 3) {
        n0h = *(const f16x8*)(arow_h + (p + 1) * 64);
        n1h = *(const f16x8*)(arow_h + (p + 1) * 64 + 32);
        n0l = *(const f16x8*)(arow_l + (p + 1) * 64);
        n1l = *(const f16x8*)(arow_l + (p + 1) * 64 + 32);
        // stage next S^T panel (its readers finished at the p-1 barrier)
#pragma unroll
        for (int nt = 0; nt < 4; ++nt) {
          const f32x4 v = S[(p + 1) * 4 + nt];
          union { _Float16 h[4]; uint2 u; } sh2, sl2;
#pragma unroll
          for (int r = 0; r < 4; ++r) fsplit(v[r], sh2.h[r], sl2.h[r]);
          const int ix = (nt * 16 + l15) * 72 + wv * 16 + quad * 4;
          *(uint2*)&Sb[1 - cur].h[ix] = sh2.u;
          *(uint2*)&Sb[1 - cur].l[ix] = sl2.u;
        }
      }
#pragma unroll
      for (int kit = 0; kit < 2; ++kit) {
        const f16x8 ah = kit ? a1h : a0h;
        const f16x8 al = kit ? a1l : a0l;
#pragma unroll
        for (int nt = 0; nt < 4; ++nt) {
          const int ix = (nt * 16 + l15) * 72 + kit * 32 + quad * 8;
          const f16x8 bh = *(const f16x8*)&Sb[cur].h[ix];
          const f16x8 bl = *(const f16x8*)&Sb[cur].l[ix];
          Qa[nt] = __builtin_amdgcn_mfma_f32_16x16x32_f16(ah, bh, Qa[nt], 0, 0, 0);
          Qa[nt] = __builtin_amdgcn_mfma_f32_16x16x32_f16(ah, bl, Qa[nt], 0, 0, 0);
          Qa[nt] = __builtin_amdgcn_mfma_f32_16x16x32_f16(al, bh, Qa[nt], 0, 0, 0);
        }
      }
      if (p < 3) { a0h = n0h; a1h = n1h; a0l = n0l; a1l = n1l; }
      __syncthreads();   // end of panel p
    }

    // ---- Y = W*Kv - A*Q, stage Y^T[j][t]
#pragma unroll
    for (int nt = 0; nt < 4; ++nt) {
      union { _Float16 h[4]; uint2 u; } yh, yl;
#pragma unroll
      for (int r = 0; r < 4; ++r) {
        const float y = myw[r] * kvv[r][nt] - mya[r] * Qa[nt][r];
        fsplit(y, yh.h[r], yl.h[r]);
      }
      const int ix = (nt * 16 + l15) * 72 + wv * 16 + quad * 4;
      *(uint2*)&Yb.t.h[ix] = yh.u;
      *(uint2*)&Yb.t.l[ix] = yl.u;
    }
    __syncthreads();   // BY

    // ---- U = T*Y
    f32x4 Ua[4];
#pragma unroll
    for (int i = 0; i < 4; ++i) Ua[i] = {0.f, 0.f, 0.f, 0.f};
#pragma unroll
    for (int kit = 0; kit < 2; ++kit)
#pragma unroll
      for (int nt = 0; nt < 4; ++nt) {
        const int ix = (nt * 16 + l15) * 72 + kit * 32 + quad * 8;
        const f16x8 yh = *(const f16x8*)&Yb.t.h[ix];
        const f16x8 yl = *(const f16x8*)&Yb.t.l[ix];
        Ua[nt] = __builtin_amdgcn_mfma_f32_16x16x32_f16(tah[kit], yh, Ua[nt], 0, 0, 0);
        Ua[nt] = __builtin_amdgcn_mfma_f32_16x16x32_f16(tah[kit], yl, Ua[nt], 0, 0, 0);
        Ua[nt] = __builtin_amdgcn_mfma_f32_16x16x32_f16(tal[kit], yh, Ua[nt], 0, 0, 0);
      }
    // stage U^T[j][t]
#pragma unroll
    for (int nt = 0; nt < 4; ++nt) {
      union { _Float16 h[4]; uint2 u; } uh, ul;
#pragma unroll
      for (int r = 0; r < 4; ++r) fsplit(Ua[nt][r], uh.h[r], ul.h[r]);
      const int ix = (nt * 16 + l15) * 72 + wv * 16 + quad * 4;
      *(uint2*)&Ub.h[ix] = uh.u;
      *(uint2*)&Ub.l[ix] = ul.u;
    }
    __syncthreads();   // BU

    // ---- S += K^T U, barrier-free (A-frags = L2-hot scalar global loads)
#pragma unroll
    for (int p = 0; p < 4; ++p) {
      union { _Float16 e[8]; f16x8 v; } kah[2], kal[2];
#pragma unroll
      for (int kit = 0; kit < 2; ++kit)
#pragma unroll
        for (int jj = 0; jj < 8; ++jj) {
          const size_t gko = (size_t)(tok0 + kit * 32 + quad * 8 + jj) * 256
                           + p * 64 + wv * 16 + l15;
          kah[kit].e[jj] = Kh[gko];
          kal[kit].e[jj] = Kl[gko];
        }
#pragma unroll
      for (int kit = 0; kit < 2; ++kit)
#pragma unroll
        for (int nt = 0; nt < 4; ++nt) {
          const int ix = (nt * 16 + l15) * 72 + kit * 32 + quad * 8;
          const f16x8 ubh = *(const f16x8*)&Ub.h[ix];
          const f16x8 ubl = *(const f16x8*)&Ub.l[ix];
          f32x4 s = S[p * 4 + nt];
          s = __builtin_amdgcn_mfma_f32_16x16x32_f16(kah[kit].v, ubh, s, 0, 0, 0);
          s = __builtin_amdgcn_mfma_f32_16x16x32_f16(kah[kit].v, ubl, s, 0, 0, 0);
          s = __builtin_amdgcn_mfma_f32_16x16x32_f16(kal[kit].v, ubh, s, 0, 0, 0);
          S[p * 4 + nt] = s;
        }
    }
    // next chunk's BP0 orders Ub WAR and Sb reuse
  }

  // ---- readout: c[col] = sum_rows S[row][col] * k_last[row]
  float part[4] = {0.f, 0.f, 0.f, 0.f};
  const size_t lastoff = (size_t)(kL - 1) * 256;
#pragma unroll
  for (int p = 0; p < 4; ++p) {
    float klr[4];
#pragma unroll
    for (int r = 0; r < 4; ++r) {
      const int row = p * 64 + wv * 16 + quad * 4 + r;
      klr[r] = (float)Kh[lastoff + row] + (float)Kl[lastoff + row];
    }
#pragma unroll
    for (int nt = 0; nt < 4; ++nt)
#pragma unroll
      for (int r = 0; r < 4; ++r) part[nt] += S[p * 4 + nt][r] * klr[r];
  }
#pragma unroll
  for (int nt = 0; nt < 4; ++nt) {
    part[nt] += __shfl_xor(part[nt], 16);
    part[nt] += __shfl_xor(part[nt], 32);
  }
  __syncthreads();   // all prior LDS reads done before cred aliases Yb
  if (lane < 16) {
#pragma unroll
    for (int nt = 0; nt < 4; ++nt) Yb.cred[wv][nt * 16 + l15] = part[nt];
  }
  __syncthreads();
  if (tid < 64) {
    const float c = Yb.cred[0][tid] + Yb.cred[1][tid] + Yb.cred[2][tid] + Yb.cred[3][tid];
    c_out[(size_t)b * 512 + mat * 256 + j0 + tid] = c;
  }
}

// ---------------- output GEMM: (64 x 512) @ (512 x 32000) + out_b -> fp32
__global__ __launch_bounds__(256) void out_gemm(
    const float* __restrict__ A, const float* __restrict__ Bm,
    const float* __restrict__ bias, float* __restrict__ C)
{
  __shared__ float As[16][64];
  __shared__ float Bs[16][128];
  const int tid = threadIdx.x;
  const int bn0 = blockIdx.x * 128;
  const int tm = tid >> 4, tn = tid & 15;
  float acc[4][8];
#pragma unroll
  for (int i = 0; i < 4; ++i)
#pragma unroll
    for (int j = 0; j < 8; ++j) acc[i][j] = 0.f;

  const int am  = tid & 63;
  const int ak  = (tid >> 6) * 4;
  const int bkr = tid >> 5;
  const int bcg = (tid & 31) * 4;

  for (int k0 = 0; k0 < kH; k0 += 16) {
    const float4 a0 = *(const float4*)(A + (size_t)am * kH + k0 + ak);
    const float4 b0 = *(const float4*)(Bm + (size_t)(k0 + bkr) * kV + bn0 + bcg);
    const float4 b1 = *(const float4*)(Bm + (size_t)(k0 + bkr + 8) * kV + bn0 + bcg);
    __syncthreads();
    As[ak + 0][am] = a0.x; As[ak + 1][am] = a0.y;
    As[ak + 2][am] = a0.z; As[ak + 3][am] = a0.w;
    *(float4*)&Bs[bkr][bcg]     = b0;
    *(float4*)&Bs[bkr + 8][bcg] = b1;
    __syncthreads();
#pragma unroll
    for (int kk = 0; kk < 16; ++kk) {
      const float4 aA = *(const float4*)&As[kk][tm * 4];
      const float4 bA = *(const float4*)&Bs[kk][tn * 4];
      const float4 bB = *(const float4*)&Bs[kk][64 + tn * 4];
      const float av[4] = {aA.x, aA.y, aA.z, aA.w};
      const float bv[8] = {bA.x, bA.y, bA.z, bA.w, bB.x, bB.y, bB.z, bB.w};
#pragma unroll
      for (int i = 0; i < 4; ++i)
#pragma unroll
        for (int j = 0; j < 8; ++j) acc[i][j] += av[i] * bv[j];
    }
  }

#pragma unroll
  for (int i = 0; i < 4; ++i) {
    const int row = tm * 4 + i;
#pragma unroll
    for (int hh = 0; hh < 2; ++hh) {
      const int n0 = bn0 + tn * 4 + hh * 64;
      const float4 bb = *(const float4*)(bias + n0);
      float4 o;
      o.x = acc[i][hh * 4 + 0] + bb.x;
      o.y = acc[i][hh * 4 + 1] + bb.y;
      o.z = acc[i][hh * 4 + 2] + bb.z;
      o.w = acc[i][hh * 4 + 3] + bb.w;
      *(float4*)(C + (size_t)row * kV + n0) = o;
    }
  }
}

}  // namespace

extern "C" void kernel_launch(void* const* d_in, const int* in_sizes, int n_in,
                              void* d_out, int out_size, void* d_ws, size_t ws_size,
                              hipStream_t stream)
{
  const int*   seq     = (const int*)  d_in[0];
  const float* embed   = (const float*)d_in[1];
  const float* w1      = (const float*)d_in[2];
  const float* b1      = (const float*)d_in[3];
  const float* w2      = (const float*)d_in[4];
  const float* b2      = (const float*)d_in[5];
  const float* ln_g    = (const float*)d_in[6];
  const float* ln_b    = (const float*)d_in[7];
  const float* sem_w   = (const float*)d_in[8];
  const float* sem_b   = (const float*)d_in[9];
  const float* epi_w   = (const float*)d_in[10];
  const float* epi_b   = (const float*)d_in[11];
  const float* out_w   = (const float*)d_in[12];
  const float* out_b   = (const float*)d_in[13];
  const float* pos_emb = (const float*)d_in[14];
  const float* pos_w   = (const float*)d_in[15];
  const float* pos_b   = (const float*)d_in[16];
  float* out = (float*)d_out;

  // chunk size: 16384 needs ~231 MB of ws; fall back to 8192 if tight.
  // ws_size is constant per process -> deterministic, graph-capture-safe.
  const int chunkN = (ws_size >= (size_t)240500000) ? 16384 : 8192;
  const int nch    = kTok / chunkN;

  char* p = (char*)d_ws;
  _Float16* w1th = (_Float16*)p; p += (size_t)1024 * 512 * 2;
  _Float16* w1tl = (_Float16*)p; p += (size_t)1024 * 512 * 2;
  _Float16* w2th = (_Float16*)p; p += (size_t)512 * 1024 * 2;
  _Float16* w2tl = (_Float16*)p; p += (size_t)512 * 1024 * 2;
  _Float16* wseh = (_Float16*)p; p += (size_t)512 * 512 * 2;
  _Float16* wsel = (_Float16*)p; p += (size_t)512 * 512 * 2;
  _Float16* t1h  = (_Float16*)p; p += (size_t)chunkN * 1024 * 2;
  _Float16* t1l  = (_Float16*)p; p += (size_t)chunkN * 1024 * 2;   // (spare; T-lo alias)
  float*    x    = (float*)p;    p += (size_t)chunkN * kH * 4;
  _Float16* khs  = (_Float16*)p; p += (size_t)kTok * kHalf * 2;   // K hi/lo fp16
  _Float16* kls  = (_Float16*)p; p += (size_t)kTok * kHalf * 2;
  _Float16* khe  = (_Float16*)p; p += (size_t)kTok * kHalf * 2;
  _Float16* kle  = (_Float16*)p; p += (size_t)kTok * kHalf * 2;
  float*    wts  = (float*)p;    p += (size_t)kL * 4;
  float*    cout_= (float*)p;    p += (size_t)kB * 512 * 4;
  float*    ssqp = (float*)p;    p += (size_t)2 * kTok * 4 * 4;   // [mat][tok][4] partials
  _Float16* hh   = t1h;          // alias: t1 dead once x is written
  // T buffers alias t1h/t1l (dead after the chunk loop): 2048 chunks x 64x64
  // fp16 hi/lo = 2 x 16.78 MB.
  _Float16* Tgh = t1h;
  _Float16* Tgl = t1l;

  pos_kernel<<<dim3((kL + 255) / 256), dim3(256), 0, stream>>>(pos_emb, pos_w, pos_b, wts);
  transpose_split<<<dim3(1024 * 512 / 256), dim3(256), 0, stream>>>(w1, w1th, w1tl, 1024, 9);
  transpose_split<<<dim3(512 * 1024 / 256), dim3(256), 0, stream>>>(w2, w2th, w2tl, 512, 10);
  transpose_split<<<dim3(256 * 512 / 256), dim3(256), 0, stream>>>(sem_w, wseh, wsel, 256, 9);
  transpose_split<<<dim3(256 * 512 / 256), dim3(256), 0, stream>>>(
      epi_w, wseh + (size_t)256 * 512, wsel + (size_t)256 * 512, 256, 9);

  for (int c = 0; c < nch; ++c) {
    const int tok0 = c * chunkN;
    hgemm<0><<<dim3(1024 / 128, chunkN / 128), dim3(256), 0, stream>>>(
        seq, embed, nullptr, w1th, w1tl, b1, nullptr,
        nullptr, t1h, nullptr, nullptr, nullptr, 512, 1024, tok0);
    hgemm<1><<<dim3(512 / 128, chunkN / 128), dim3(256), 0, stream>>>(
        seq, embed, t1h, w2th, w2tl, b2, nullptr,
        x, nullptr, nullptr, nullptr, nullptr, 1024, 512, tok0);
    ln_split<<<dim3(chunkN / 4), dim3(256), 0, stream>>>(x, ln_g, ln_b, hh);
    hgemm<2><<<dim3(512 / 128, chunkN / 128), dim3(256), 0, stream>>>(
        seq, embed, hh, wseh, wsel, sem_b, epi_b,
        ssqp, kls, kle, (float*)khs, (float*)khe,
        512, 512, tok0);
  }

  tinv_kernel<<<dim3(2048), dim3(64), 0, stream>>>(
      khs, kls, khe, kle, ssqp, wts, Tgh, Tgl);
  scan_chunked<<<dim3(512), dim3(256), 0, stream>>>(
      khs, kls, khe, kle, ssqp, wts, Tgh, Tgl, cout_);
  out_gemm<<<dim3(kV / 128), dim3(256), 0, stream>>>(cout_, out_w, out_b, out);

  (void)in_sizes; (void)n_in; (void)out_size;
}

// Round 9
// 972.004 us; speedup vs baseline: 1.8314x; 1.1211x over previous
//
#include <hip/hip_runtime.h>
#include <hip/hip_bf16.h>
#include <math.h>

namespace {

constexpr int kH     = 512;
constexpr int kL     = 1024;
constexpr int kB     = 64;
constexpr int kHalf  = 256;
constexpr int kV     = 32000;
constexpr int kTok   = kB * kL;     // 65536

using f32x4 = __attribute__((ext_vector_type(4))) float;
using f16x8 = __attribute__((ext_vector_type(8))) _Float16;

__device__ inline void fsplit(float v, _Float16& h, _Float16& l) {
  h = (_Float16)v;
  l = (_Float16)(v - (float)h);
}

// async 16B global->LDS (gfx950). dst must be wave-uniform base; lane l
// receives bytes [l*16, l*16+16).
typedef __attribute__((address_space(3))) void lds_vp;
typedef const __attribute__((address_space(1))) void glb_vp;
__device__ inline void gload16(const void* g, void* l) {
  __builtin_amdgcn_global_load_lds((glb_vp*)g, (lds_vp*)l, 16, 0, 0);
}

// Row-PAIR swizzled half-tile index for [128][32]-half tiles stored flat.
// 64B rows only have 4 granules, so the 8-slot XOR runs across row pairs:
// super-row sr=row>>1 (128B), granule g=(row&1)*4+col/8, g'=g^(sr&7).
// Per-16-lane b128 fragment read: each g' hit exactly twice -> 2-way (free).
__device__ inline int hswz(int row, int col) {
  const int sr = row >> 1;
  const int g  = ((row & 1) << 2) | (col >> 3);
  return sr * 64 + (((g ^ (sr & 7)) << 3) | (col & 7));
}

// ---------------- positional weights
__global__ void pos_kernel(const float* __restrict__ pos_emb,
                           const float* __restrict__ pos_w,
                           const float* __restrict__ pos_b,
                           float* __restrict__ wts)
{
  int t = blockIdx.x * blockDim.x + threadIdx.x;
  if (t >= kL) return;
  float z = pos_b[0];
#pragma unroll
  for (int p = 0; p < 16; ++p) z += pos_emb[t * 16 + p] * pos_w[p];
  wts[t] = 1.f / (1.f + expf(-z));
}

// ---------------- transpose + hi/lo fp16 split: W[K][N] fp32 -> Th/Tl[N][K]
__global__ __launch_bounds__(256) void transpose_split(
    const float* __restrict__ W, _Float16* __restrict__ Th,
    _Float16* __restrict__ Tl, int N, int kshift)
{
  const int idx = blockIdx.x * 256 + threadIdx.x;
  const int K = 1 << kshift;
  const int k = idx & (K - 1);
  const int n = idx >> kshift;
  const float w = W[(size_t)k * N + n];
  const _Float16 h = (_Float16)w;
  Th[idx] = h;
  Tl[idx] = (_Float16)(w - (float)h);
}

// ---------------- mixed-precision MFMA GEMM: C = A(fp16) @ B[N,K]^T
// v13: 2-phase double-buffered pipeline — at iter t, issue tile-t async
// loads BEFORE computing tile t-1; ONE barrier per K-step drains the
// next-tile vmcnt under the just-finished MFMA phase (was: issue+drain
// back-to-back, ~250cy exposed every step). PROD=1: B plain fp16 (FF
// weights; rounding ~1e-4 relative, << bf16 output floor). PROD=2: B
// split hi/lo (sem/epi weights -> scan K, precision-critical).
template <int EPI, int PROD>
__global__ __launch_bounds__(256) void hgemm(
    const int* __restrict__ seq, const float* __restrict__ embed,
    const _Float16* __restrict__ Ah,
    const _Float16* __restrict__ Bh, const _Float16* __restrict__ Bl,
    const float* __restrict__ bias, const float* __restrict__ bias2,
    float* __restrict__ Xout, _Float16* __restrict__ Oh, _Float16* __restrict__ Ol,
    float* __restrict__ ks, float* __restrict__ ke,
    int K, int N, int tok0c)
{
  constexpr int TILES = 1 + PROD;              // A, Bh (, Bl)
  __shared__ __align__(16) _Float16 lds[2 * TILES * 4096];  // dbuf
  const int tid  = threadIdx.x;
  const int lane = tid & 63;
  const int wv   = tid >> 6;
  const int wm   = (wv >> 1) * 64;
  const int wn   = (wv & 1) * 64;
  const int bm0  = blockIdx.y * 128;
  const int bn0  = blockIdx.x * 128;

  f32x4 acc[4][4];
#pragma unroll
  for (int i = 0; i < 4; ++i)
#pragma unroll
    for (int j = 0; j < 4; ++j) acc[i][j] = {0.f, 0.f, 0.f, 0.f};

  // async staging geometry (it=0 rows wv*16.., it=1 +64): lane l writes phys
  // 16B granule (super-row l>>3, slot l&7); inverse-swizzled global source:
  const int sl   = lane >> 3;                 // local super-row 0..7
  const int gg   = (lane & 7) ^ sl;           // logical granule
  const int trow = wv * 16 + sl * 2 + (gg >> 2);
  const int tcol = (gg & 3) * 8;              // halves within the 32-half k-step
  const size_t brow0 = (size_t)(bn0 + trow) * K + tcol;
  const size_t brow1 = (size_t)(bn0 + trow + 64) * K + tcol;
  size_t arow0 = 0, arow1 = 0;
  const float* gAe = nullptr;
  if constexpr (EPI == 0) {
    const int sr = tid >> 1;
    const int tokrow = seq[tok0c + bm0 + sr];
    gAe = embed + (size_t)tokrow * kH + ((tid & 1) << 4);
  } else {
    arow0 = (size_t)(bm0 + trow) * K + tcol;
    arow1 = (size_t)(bm0 + trow + 64) * K + tcol;
  }
  // wave-uniform LDS bases (halves)
  const int lb0 = wv * 512;
  const int lb1 = 2048 + wv * 512;

  const int lrow = lane & 15;
  const int lk   = (lane >> 4) * 8;
  const int NT   = K >> 5;

  for (int t = 0; t <= NT; ++t) {
    const int kc = t << 5;
    float4 a0, a1, a2, a3;
    if (t < NT) {                       // issue tile-t loads (latency hides
      if constexpr (EPI == 0) {         //  under tile t-1's compute below)
        a0 = *(const float4*)(gAe + kc);
        a1 = *(const float4*)(gAe + kc + 4);
        a2 = *(const float4*)(gAe + kc + 8);
        a3 = *(const float4*)(gAe + kc + 12);
      }
      const int bo = (t & 1) * TILES * 4096;
      if constexpr (EPI != 0) {
        gload16(Ah + arow0 + kc, &lds[bo + lb0]);
        gload16(Ah + arow1 + kc, &lds[bo + lb1]);
      }
      gload16(Bh + brow0 + kc, &lds[bo + 4096 + lb0]);
      gload16(Bh + brow1 + kc, &lds[bo + 4096 + lb1]);
      if constexpr (PROD == 2) {
        gload16(Bl + brow0 + kc, &lds[bo + 8192 + lb0]);
        gload16(Bl + brow1 + kc, &lds[bo + 8192 + lb1]);
      }
    }
    if (t > 0) {                        // compute tile t-1
      const int po = ((t - 1) & 1) * TILES * 4096;
      f16x8 fBh[4], fBl[4];
#pragma unroll
      for (int ni = 0; ni < 4; ++ni) {
        fBh[ni] = *(const f16x8*)&lds[po + 4096 + hswz(wn + ni * 16 + lrow, lk)];
        if constexpr (PROD == 2)
          fBl[ni] = *(const f16x8*)&lds[po + 8192 + hswz(wn + ni * 16 + lrow, lk)];
      }
#pragma unroll
      for (int mi = 0; mi < 4; ++mi) {
        const f16x8 ah = *(const f16x8*)&lds[po + hswz(wm + mi * 16 + lrow, lk)];
#pragma unroll
        for (int ni = 0; ni < 4; ++ni) {
          acc[mi][ni] = __builtin_amdgcn_mfma_f32_16x16x32_f16(ah, fBh[ni], acc[mi][ni], 0, 0, 0);
          if constexpr (PROD == 2)
            acc[mi][ni] = __builtin_amdgcn_mfma_f32_16x16x32_f16(ah, fBl[ni], acc[mi][ni], 0, 0, 0);
        }
      }
    }
    if (t < NT) {
      if constexpr (EPI == 0) {         // manual A stage (embed gather)
        const float vv[16] = {a0.x,a0.y,a0.z,a0.w, a1.x,a1.y,a1.z,a1.w,
                              a2.x,a2.y,a2.z,a2.w, a3.x,a3.y,a3.z,a3.w};
        union { _Float16 h[16]; uint4 u[2]; } ph;
#pragma unroll
        for (int i = 0; i < 16; ++i) ph.h[i] = (_Float16)vv[i];
        const int sr = tid >> 1;
        const int sc = (tid & 1) << 4;
        const int bo = (t & 1) * TILES * 4096;
        *(uint4*)&lds[bo + hswz(sr, sc)]     = ph.u[0];
        *(uint4*)&lds[bo + hswz(sr, sc + 8)] = ph.u[1];
      }
    }
    __syncthreads();   // drains tile-t vmcnt (hidden under tile t-1 MFMA) + lgkm
  }

  const int erow0 = (lane >> 4) * 4;
  if constexpr (EPI == 0) {
#pragma unroll
    for (int mi = 0; mi < 4; ++mi)
#pragma unroll
      for (int ni = 0; ni < 4; ++ni) {
        const int gn = bn0 + wn + ni * 16 + (lane & 15);
        const float bv = bias[gn];
#pragma unroll
        for (int r = 0; r < 4; ++r) {
          const int gm = bm0 + wm + mi * 16 + erow0 + r;
          float v = fmaxf(acc[mi][ni][r] + bv, 0.f);
          Oh[(size_t)gm * N + gn] = (_Float16)v;
        }
      }
  } else if constexpr (EPI == 1) {
#pragma unroll
    for (int mi = 0; mi < 4; ++mi)
#pragma unroll
      for (int r = 0; r < 4; ++r) {
        const int gm = bm0 + wm + mi * 16 + erow0 + r;
        const int tok = seq[tok0c + gm];
        const float* er = embed + (size_t)tok * kH;
#pragma unroll
        for (int ni = 0; ni < 4; ++ni) {
          const int gn = bn0 + wn + ni * 16 + (lane & 15);
          Xout[(size_t)gm * N + gn] = acc[mi][ni][r] + bias[gn] + er[gn];
        }
      }
  } else {
    // EPI==2: write K as fp16 hi/lo pairs + per-quarter ssq partials (Xout).
    _Float16* kh_s = (_Float16*)ks;
    _Float16* kh_e = (_Float16*)ke;
    float s2[4][4];
#pragma unroll
    for (int mi = 0; mi < 4; ++mi)
#pragma unroll
      for (int r = 0; r < 4; ++r) s2[mi][r] = 0.f;
#pragma unroll
    for (int mi = 0; mi < 4; ++mi)
#pragma unroll
      for (int ni = 0; ni < 4; ++ni) {
        const int gn = bn0 + wn + ni * 16 + (lane & 15);
        const float bv = (gn < 256) ? bias[gn] : bias2[gn - 256];
        _Float16* Dh = (gn < 256) ? kh_s : kh_e;
        _Float16* Dl = (gn < 256) ? Oh : Ol;
        const int col = gn & 255;
#pragma unroll
        for (int r = 0; r < 4; ++r) {
          const int gm = bm0 + wm + mi * 16 + erow0 + r;
          const float v = acc[mi][ni][r] + bv;
          s2[mi][r] += v * v;
          _Float16 h, l;
          fsplit(v, h, l);
          Dh[(size_t)(tok0c + gm) * 256 + col] = h;
          Dl[(size_t)(tok0c + gm) * 256 + col] = l;
        }
      }
    // deterministic per-quarter partial sums: ssqPart[mat][tok][half*2 + (wv&1)]
    const int matq  = bn0 >> 8;
    const int halfq = (bn0 >> 7) & 1;
#pragma unroll
    for (int mi = 0; mi < 4; ++mi)
#pragma unroll
      for (int r = 0; r < 4; ++r) {
        float s2v = s2[mi][r];
        s2v += __shfl_xor(s2v, 1);
        s2v += __shfl_xor(s2v, 2);
        s2v += __shfl_xor(s2v, 4);
        s2v += __shfl_xor(s2v, 8);
        if ((lane & 15) == 0) {
          const int gm = bm0 + wm + mi * 16 + erow0 + r;
          Xout[((size_t)matq * kTok + (size_t)(tok0c + gm)) * 4 + halfq * 2 + (wv & 1)] = s2v;
        }
      }
  }
}

// ---------------- LayerNorm: x fp32 -> fp16 (hi only)
__global__ __launch_bounds__(256) void ln_split(
    const float* __restrict__ x, const float* __restrict__ g,
    const float* __restrict__ bta, _Float16* __restrict__ hh)
{
  const int wid  = threadIdx.x >> 6;
  const int lane = threadIdx.x & 63;
  const int ltok = blockIdx.x * 4 + wid;
  const float* xp = x + (size_t)ltok * kH;
  const float4 v0 = *(const float4*)(xp + lane * 8);
  const float4 v1 = *(const float4*)(xp + lane * 8 + 4);
  float s  = v0.x + v0.y + v0.z + v0.w + v1.x + v1.y + v1.z + v1.w;
  float ss = v0.x * v0.x + v0.y * v0.y + v0.z * v0.z + v0.w * v0.w +
             v1.x * v1.x + v1.y * v1.y + v1.z * v1.z + v1.w * v1.w;
#pragma unroll
  for (int m = 1; m < 64; m <<= 1) { s += __shfl_xor(s, m); ss += __shfl_xor(ss, m); }
  const float mu  = s * (1.f / kH);
  const float var = ss * (1.f / kH) - mu * mu;
  const float rs  = 1.f / sqrtf(var + 1e-5f);
  const float4 g0 = *(const float4*)(g + lane * 8);
  const float4 g1 = *(const float4*)(g + lane * 8 + 4);
  const float4 b0 = *(const float4*)(bta + lane * 8);
  const float4 b1 = *(const float4*)(bta + lane * 8 + 4);
  const float vv[8] = {v0.x, v0.y, v0.z, v0.w, v1.x, v1.y, v1.z, v1.w};
  const float gg[8] = {g0.x, g0.y, g0.z, g0.w, g1.x, g1.y, g1.z, g1.w};
  const float bb[8] = {b0.x, b0.y, b0.z, b0.w, b1.x, b1.y, b1.z, b1.w};
  union { _Float16 h[8]; uint4 u; } ph;
#pragma unroll
  for (int i = 0; i < 8; ++i) {
    const float o = (vv[i] - mu) * rs * gg[i] + bb[i];
    ph.h[i] = (_Float16)o;
  }
  *(uint4*)(hh + (size_t)ltok * kH + lane * 8) = ph.u;
}

// ---------------- T precompute: T = (I + diag(aS)*tril_strict(K K^T))^{-1}
__global__ __launch_bounds__(64) void tinv_kernel(
    const _Float16* __restrict__ khs, const _Float16* __restrict__ kls,
    const _Float16* __restrict__ khe, const _Float16* __restrict__ kle,
    const float* __restrict__ ssqP, const float* __restrict__ wts,
    _Float16* __restrict__ Tgh, _Float16* __restrict__ Tgl)
{
  __shared__ float Gs[64][68];
  const int lane = threadIdx.x;
  const int l15  = lane & 15;
  const int quad = lane >> 4;
  const int wg   = blockIdx.x;
  const int ck   = wg & 15;
  const int mat  = (wg >> 4) & 1;
  const int b    = wg >> 5;
  const _Float16* Kh = (mat ? khe : khs) + (size_t)b * (1024 * 256) + (size_t)ck * 64 * 256;
  const _Float16* Kl = (mat ? kle : kls) + (size_t)b * (1024 * 256) + (size_t)ck * 64 * 256;

  const float4 sq = *(const float4*)(ssqP + ((size_t)mat * kTok + (size_t)b * 1024 + ck * 64 + lane) * 4);
  const float w  = mat ? wts[ck * 64 + lane] : 1.f;
  const float aS = w / (sq.x + sq.y + sq.z + sq.w + 1e-6f);

  // G = K K^T via split-fp16 MFMA
  f32x4 D[16];
#pragma unroll
  for (int i = 0; i < 16; ++i) D[i] = {0.f, 0.f, 0.f, 0.f};
#pragma unroll
  for (int kit = 0; kit < 8; ++kit) {
    f16x8 fh[4], fl[4];
#pragma unroll
    for (int mi = 0; mi < 4; ++mi) {
      fh[mi] = *(const f16x8*)(Kh + (size_t)(mi * 16 + l15) * 256 + kit * 32 + quad * 8);
      fl[mi] = *(const f16x8*)(Kl + (size_t)(mi * 16 + l15) * 256 + kit * 32 + quad * 8);
    }
#pragma unroll
    for (int mi = 0; mi < 4; ++mi)
#pragma unroll
      for (int ni = 0; ni < 4; ++ni) {
        f32x4 d = D[mi * 4 + ni];
        d = __builtin_amdgcn_mfma_f32_16x16x32_f16(fh[mi], fh[ni], d, 0, 0, 0);
        d = __builtin_amdgcn_mfma_f32_16x16x32_f16(fh[mi], fl[ni], d, 0, 0, 0);
        d = __builtin_amdgcn_mfma_f32_16x16x32_f16(fl[mi], fh[ni], d, 0, 0, 0);
        D[mi * 4 + ni] = d;
      }
  }
#pragma unroll
  for (int mi = 0; mi < 4; ++mi)
#pragma unroll
    for (int ni = 0; ni < 4; ++ni)
#pragma unroll
      for (int r = 0; r < 4; ++r) {
        const int row = mi * 16 + quad * 4 + r;
        const float as_r = __shfl(aS, row);
        Gs[row][ni * 16 + l15] = as_r * D[mi * 4 + ni][r];
      }
  __syncthreads();

  float x[64];
#pragma unroll
  for (int t = 0; t < 64; ++t) x[t] = (t == lane) ? 1.f : 0.f;
#pragma unroll
  for (int t = 1; t < 64; ++t) {
    float acc = 0.f;
    const int n4 = t >> 2;
#pragma unroll
    for (int q4 = 0; q4 < 16; ++q4) {
      if (q4 >= n4) break;
      const float4 g = *(const float4*)&Gs[t][q4 * 4];
      acc += g.x * x[q4 * 4] + g.y * x[q4 * 4 + 1] + g.z * x[q4 * 4 + 2] + g.w * x[q4 * 4 + 3];
    }
#pragma unroll
    for (int tp = 0; tp < 4; ++tp) {
      const int ti = n4 * 4 + tp;
      if (ti >= t) break;
      acc += Gs[t][ti] * x[ti];
    }
    x[t] -= acc;
  }
  if (ck == 15) x[63] = 0.f;   // token L-1 is the query only: U row 63 = 0

  const size_t base = (size_t)wg * 4096;
#pragma unroll
  for (int t = 0; t < 64; ++t) {
    _Float16 h, l;
    fsplit(x[t], h, l);
    Tgh[base + t * 64 + lane] = h;
    Tgl[base + t * 64 + lane] = l;
  }
}

// ---------------- chunked WY delta-rule scan (v9 structure, unchanged).
struct HTile { _Float16 h[4608], l[4608]; };   // [64][72] halves hi/lo, 18432 B

__global__ __launch_bounds__(256) void scan_chunked(
    const _Float16* __restrict__ khs, const _Float16* __restrict__ kls,
    const _Float16* __restrict__ khe, const _Float16* __restrict__ kle,
    const float* __restrict__ ssqP, const float* __restrict__ wts,
    const _Float16* __restrict__ Tgh, const _Float16* __restrict__ Tgl,
    float* __restrict__ c_out)
{
  __shared__ HTile Sb[2];                                   // S^T dbuf 36864 B
  __shared__ union { HTile t; float cred[4][64]; } Yb;      // Y^T      18432 B
  __shared__ HTile Ub;                                      // U^T      18432 B

  const int tid  = threadIdx.x;
  const int lane = tid & 63;
  const int wv   = tid >> 6;
  const int l15  = lane & 15;
  const int quad = lane >> 4;
  const int wg   = blockIdx.x;
  const int grp  = (wg & 7) + ((wg >> 5) << 3);   // 0..127
  const int q    = (wg >> 3) & 3;
  const int b    = grp >> 1;
  const int mat  = grp & 1;
  const int j0   = q * 64;
  const _Float16* Kh = (mat ? khe : khs) + (size_t)b * (1024 * 256);
  const _Float16* Kl = (mat ? kle : kls) + (size_t)b * (1024 * 256);
  const _Float16* Tbh = Tgh + (size_t)((b * 2 + mat) * 16) * 4096;
  const _Float16* Tbl = Tgl + (size_t)((b * 2 + mat) * 16) * 4096;

  f32x4 S[16];
#pragma unroll
  for (int i = 0; i < 16; ++i) S[i] = {0.f, 0.f, 0.f, 0.f};

  for (int ck = 0; ck < 16; ++ck) {
    const int tok0 = ck * 64;

    float myw[4], mya[4], kvv[4][4];
#pragma unroll
    for (int r = 0; r < 4; ++r) {
      const int t = tok0 + wv * 16 + quad * 4 + r;
      const float4 sq = *(const float4*)(ssqP + ((size_t)mat * kTok + (size_t)b * 1024 + t) * 4);
      const float w = mat ? wts[t] : 1.f;
      myw[r] = w;
      mya[r] = w / (sq.x + sq.y + sq.z + sq.w + 1e-6f);
#pragma unroll
      for (int nt = 0; nt < 4; ++nt) {
        const size_t go = (size_t)t * 256 + j0 + nt * 16 + l15;
        kvv[r][nt] = (float)Kh[go] + (float)Kl[go];
      }
    }
    f16x8 tah[2], tal[2];
#pragma unroll
    for (int kit = 0; kit < 2; ++kit) {
      const size_t to = (size_t)ck * 4096 + (size_t)(wv * 16 + l15) * 64 + kit * 32 + quad * 8;
      tah[kit] = *(const f16x8*)(Tbh + to);
      tal[kit] = *(const f16x8*)(Tbl + to);
    }
    const _Float16* arow_h = Kh + (size_t)(tok0 + wv * 16 + l15) * 256 + quad * 8;
    const _Float16* arow_l = Kl + (size_t)(tok0 + wv * 16 + l15) * 256 + quad * 8;
    f16x8 a0h = *(const f16x8*)(arow_h);
    f16x8 a1h = *(const f16x8*)(arow_h + 32);
    f16x8 a0l = *(const f16x8*)(arow_l);
    f16x8 a1l = *(const f16x8*)(arow_l + 32);

#pragma unroll
    for (int nt = 0; nt < 4; ++nt) {
      const f32x4 v = S[0 * 4 + nt];
      union { _Float16 h[4]; uint2 u; } qh, ql;
#pragma unroll
      for (int r = 0; r < 4; ++r) fsplit(v[r], qh.h[r], ql.h[r]);
      const int ix = (nt * 16 + l15) * 72 + wv * 16 + quad * 4;
      *(uint2*)&Sb[0].h[ix] = qh.u;
      *(uint2*)&Sb[0].l[ix] = ql.u;
    }
    __syncthreads();   // BP0

    f32x4 Qa[4];
#pragma unroll
    for (int i = 0; i < 4; ++i) Qa[i] = {0.f, 0.f, 0.f, 0.f};
#pragma unroll
    for (int p = 0; p < 4; ++p) {
      const int cur = p & 1;
      f16x8 n0h, n1h, n0l, n1l;
      if (p < 3) {
        n0h = *(const f16x8*)(arow_h + (p + 1) * 64);
        n1h = *(const f16x8*)(arow_h + (p + 1) * 64 + 32);
        n0l = *(const f16x8*)(arow_l + (p + 1) * 64);
        n1l = *(const f16x8*)(arow_l + (p + 1) * 64 + 32);
#pragma unroll
        for (int nt = 0; nt < 4; ++nt) {
          const f32x4 v = S[(p + 1) * 4 + nt];
          union { _Float16 h[4]; uint2 u; } sh2, sl2;
#pragma unroll
          for (int r = 0; r < 4; ++r) fsplit(v[r], sh2.h[r], sl2.h[r]);
          const int ix = (nt * 16 + l15) * 72 + wv * 16 + quad * 4;
          *(uint2*)&Sb[1 - cur].h[ix] = sh2.u;
          *(uint2*)&Sb[1 - cur].l[ix] = sl2.u;
        }
      }
#pragma unroll
      for (int kit = 0; kit < 2; ++kit) {
        const f16x8 ah = kit ? a1h : a0h;
        const f16x8 al = kit ? a1l : a0l;
#pragma unroll
        for (int nt = 0; nt < 4; ++nt) {
          const int ix = (nt * 16 + l15) * 72 + kit * 32 + quad * 8;
          const f16x8 bh = *(const f16x8*)&Sb[cur].h[ix];
          const f16x8 bl = *(const f16x8*)&Sb[cur].l[ix];
          Qa[nt] = __builtin_amdgcn_mfma_f32_16x16x32_f16(ah, bh, Qa[nt], 0, 0, 0);
          Qa[nt] = __builtin_amdgcn_mfma_f32_16x16x32_f16(ah, bl, Qa[nt], 0, 0, 0);
          Qa[nt] = __builtin_amdgcn_mfma_f32_16x16x32_f16(al, bh, Qa[nt], 0, 0, 0);
        }
      }
      if (p < 3) { a0h = n0h; a1h = n1h; a0l = n0l; a1l = n1l; }
      __syncthreads();   // end of panel p
    }

#pragma unroll
    for (int nt = 0; nt < 4; ++nt) {
      union { _Float16 h[4]; uint2 u; } yh, yl;
#pragma unroll
      for (int r = 0; r < 4; ++r) {
        const float y = myw[r] * kvv[r][nt] - mya[r] * Qa[nt][r];
        fsplit(y, yh.h[r], yl.h[r]);
      }
      const int ix = (nt * 16 + l15) * 72 + wv * 16 + quad * 4;
      *(uint2*)&Yb.t.h[ix] = yh.u;
      *(uint2*)&Yb.t.l[ix] = yl.u;
    }
    __syncthreads();   // BY

    f32x4 Ua[4];
#pragma unroll
    for (int i = 0; i < 4; ++i) Ua[i] = {0.f, 0.f, 0.f, 0.f};
#pragma unroll
    for (int kit = 0; kit < 2; ++kit)
#pragma unroll
      for (int nt = 0; nt < 4; ++nt) {
        const int ix = (nt * 16 + l15) * 72 + kit * 32 + quad * 8;
        const f16x8 yh = *(const f16x8*)&Yb.t.h[ix];
        const f16x8 yl = *(const f16x8*)&Yb.t.l[ix];
        Ua[nt] = __builtin_amdgcn_mfma_f32_16x16x32_f16(tah[kit], yh, Ua[nt], 0, 0, 0);
        Ua[nt] = __builtin_amdgcn_mfma_f32_16x16x32_f16(tah[kit], yl, Ua[nt], 0, 0, 0);
        Ua[nt] = __builtin_amdgcn_mfma_f32_16x16x32_f16(tal[kit], yh, Ua[nt], 0, 0, 0);
      }
#pragma unroll
    for (int nt = 0; nt < 4; ++nt) {
      union { _Float16 h[4]; uint2 u; } uh, ul;
#pragma unroll
      for (int r = 0; r < 4; ++r) fsplit(Ua[nt][r], uh.h[r], ul.h[r]);
      const int ix = (nt * 16 + l15) * 72 + wv * 16 + quad * 4;
      *(uint2*)&Ub.h[ix] = uh.u;
      *(uint2*)&Ub.l[ix] = ul.u;
    }
    __syncthreads();   // BU

#pragma unroll
    for (int p = 0; p < 4; ++p) {
      union { _Float16 e[8]; f16x8 v; } kah[2], kal[2];
#pragma unroll
      for (int kit = 0; kit < 2; ++kit)
#pragma unroll
        for (int jj = 0; jj < 8; ++jj) {
          const size_t gko = (size_t)(tok0 + kit * 32 + quad * 8 + jj) * 256
                           + p * 64 + wv * 16 + l15;
          kah[kit].e[jj] = Kh[gko];
          kal[kit].e[jj] = Kl[gko];
        }
#pragma unroll
      for (int kit = 0; kit < 2; ++kit)
#pragma unroll
        for (int nt = 0; nt < 4; ++nt) {
          const int ix = (nt * 16 + l15) * 72 + kit * 32 + quad * 8;
          const f16x8 ubh = *(const f16x8*)&Ub.h[ix];
          const f16x8 ubl = *(const f16x8*)&Ub.l[ix];
          f32x4 s = S[p * 4 + nt];
          s = __builtin_amdgcn_mfma_f32_16x16x32_f16(kah[kit].v, ubh, s, 0, 0, 0);
          s = __builtin_amdgcn_mfma_f32_16x16x32_f16(kah[kit].v, ubl, s, 0, 0, 0);
          s = __builtin_amdgcn_mfma_f32_16x16x32_f16(kal[kit].v, ubh, s, 0, 0, 0);
          S[p * 4 + nt] = s;
        }
    }
  }

  float part[4] = {0.f, 0.f, 0.f, 0.f};
  const size_t lastoff = (size_t)(kL - 1) * 256;
#pragma unroll
  for (int p = 0; p < 4; ++p) {
    float klr[4];
#pragma unroll
    for (int r = 0; r < 4; ++r) {
      const int row = p * 64 + wv * 16 + quad * 4 + r;
      klr[r] = (float)Kh[lastoff + row] + (float)Kl[lastoff + row];
    }
#pragma unroll
    for (int nt = 0; nt < 4; ++nt)
#pragma unroll
      for (int r = 0; r < 4; ++r) part[nt] += S[p * 4 + nt][r] * klr[r];
  }
#pragma unroll
  for (int nt = 0; nt < 4; ++nt) {
    part[nt] += __shfl_xor(part[nt], 16);
    part[nt] += __shfl_xor(part[nt], 32);
  }
  __syncthreads();
  if (lane < 16) {
#pragma unroll
    for (int nt = 0; nt < 4; ++nt) Yb.cred[wv][nt * 16 + l15] = part[nt];
  }
  __syncthreads();
  if (tid < 64) {
    const float c = Yb.cred[0][tid] + Yb.cred[1][tid] + Yb.cred[2][tid] + Yb.cred[3][tid];
    c_out[(size_t)b * 512 + mat * 256 + j0 + tid] = c;
  }
}

// ---------------- output GEMM: (64 x 512) @ (512 x 32000) + out_b -> fp32
__global__ __launch_bounds__(256) void out_gemm(
    const float* __restrict__ A, const float* __restrict__ Bm,
    const float* __restrict__ bias, float* __restrict__ C)
{
  __shared__ float As[16][64];
  __shared__ float Bs[16][128];
  const int tid = threadIdx.x;
  const int bn0 = blockIdx.x * 128;
  const int tm = tid >> 4, tn = tid & 15;
  float acc[4][8];
#pragma unroll
  for (int i = 0; i < 4; ++i)
#pragma unroll
    for (int j = 0; j < 8; ++j) acc[i][j] = 0.f;

  const int am  = tid & 63;
  const int ak  = (tid >> 6) * 4;
  const int bkr = tid >> 5;
  const int bcg = (tid & 31) * 4;

  for (int k0 = 0; k0 < kH; k0 += 16) {
    const float4 a0 = *(const float4*)(A + (size_t)am * kH + k0 + ak);
    const float4 b0 = *(const float4*)(Bm + (size_t)(k0 + bkr) * kV + bn0 + bcg);
    const float4 b1 = *(const float4*)(Bm + (size_t)(k0 + bkr + 8) * kV + bn0 + bcg);
    __syncthreads();
    As[ak + 0][am] = a0.x; As[ak + 1][am] = a0.y;
    As[ak + 2][am] = a0.z; As[ak + 3][am] = a0.w;
    *(float4*)&Bs[bkr][bcg]     = b0;
    *(float4*)&Bs[bkr + 8][bcg] = b1;
    __syncthreads();
#pragma unroll
    for (int kk = 0; kk < 16; ++kk) {
      const float4 aA = *(const float4*)&As[kk][tm * 4];
      const float4 bA = *(const float4*)&Bs[kk][tn * 4];
      const float4 bB = *(const float4*)&Bs[kk][64 + tn * 4];
      const float av[4] = {aA.x, aA.y, aA.z, aA.w};
      const float bv[8] = {bA.x, bA.y, bA.z, bA.w, bB.x, bB.y, bB.z, bB.w};
#pragma unroll
      for (int i = 0; i < 4; ++i)
#pragma unroll
        for (int j = 0; j < 8; ++j) acc[i][j] += av[i] * bv[j];
    }
  }

#pragma unroll
  for (int i = 0; i < 4; ++i) {
    const int row = tm * 4 + i;
#pragma unroll
    for (int hh = 0; hh < 2; ++hh) {
      const int n0 = bn0 + tn * 4 + hh * 64;
      const float4 bb = *(const float4*)(bias + n0);
      float4 o;
      o.x = acc[i][hh * 4 + 0] + bb.x;
      o.y = acc[i][hh * 4 + 1] + bb.y;
      o.z = acc[i][hh * 4 + 2] + bb.z;
      o.w = acc[i][hh * 4 + 3] + bb.w;
      *(float4*)(C + (size_t)row * kV + n0) = o;
    }
  }
}

}  // namespace

extern "C" void kernel_launch(void* const* d_in, const int* in_sizes, int n_in,
                              void* d_out, int out_size, void* d_ws, size_t ws_size,
                              hipStream_t stream)
{
  const int*   seq     = (const int*)  d_in[0];
  const float* embed   = (const float*)d_in[1];
  const float* w1      = (const float*)d_in[2];
  const float* b1      = (const float*)d_in[3];
  const float* w2      = (const float*)d_in[4];
  const float* b2      = (const float*)d_in[5];
  const float* ln_g    = (const float*)d_in[6];
  const float* ln_b    = (const float*)d_in[7];
  const float* sem_w   = (const float*)d_in[8];
  const float* sem_b   = (const float*)d_in[9];
  const float* epi_w   = (const float*)d_in[10];
  const float* epi_b   = (const float*)d_in[11];
  const float* out_w   = (const float*)d_in[12];
  const float* out_b   = (const float*)d_in[13];
  const float* pos_emb = (const float*)d_in[14];
  const float* pos_w   = (const float*)d_in[15];
  const float* pos_b   = (const float*)d_in[16];
  float* out = (float*)d_out;

  const int chunkN = (ws_size >= (size_t)240500000) ? 16384 : 8192;
  const int nch    = kTok / chunkN;

  char* p = (char*)d_ws;
  _Float16* w1th = (_Float16*)p; p += (size_t)1024 * 512 * 2;
  _Float16* w1tl = (_Float16*)p; p += (size_t)1024 * 512 * 2;   // unused (PROD=1)
  _Float16* w2th = (_Float16*)p; p += (size_t)512 * 1024 * 2;
  _Float16* w2tl = (_Float16*)p; p += (size_t)512 * 1024 * 2;   // unused (PROD=1)
  _Float16* wseh = (_Float16*)p; p += (size_t)512 * 512 * 2;
  _Float16* wsel = (_Float16*)p; p += (size_t)512 * 512 * 2;
  _Float16* t1h  = (_Float16*)p; p += (size_t)chunkN * 1024 * 2;
  _Float16* t1l  = (_Float16*)p; p += (size_t)chunkN * 1024 * 2;   // (spare; T-lo alias)
  float*    x    = (float*)p;    p += (size_t)chunkN * kH * 4;
  _Float16* khs  = (_Float16*)p; p += (size_t)kTok * kHalf * 2;   // K hi/lo fp16
  _Float16* kls  = (_Float16*)p; p += (size_t)kTok * kHalf * 2;
  _Float16* khe  = (_Float16*)p; p += (size_t)kTok * kHalf * 2;
  _Float16* kle  = (_Float16*)p; p += (size_t)kTok * kHalf * 2;
  float*    wts  = (float*)p;    p += (size_t)kL * 4;
  float*    cout_= (float*)p;    p += (size_t)kB * 512 * 4;
  float*    ssqp = (float*)p;    p += (size_t)2 * kTok * 4 * 4;   // [mat][tok][4] partials
  _Float16* hh   = t1h;          // alias: t1 dead once x is written
  _Float16* Tgh = t1h;           // T aliases t1 (dead after chunk loop)
  _Float16* Tgl = t1l;

  pos_kernel<<<dim3((kL + 255) / 256), dim3(256), 0, stream>>>(pos_emb, pos_w, pos_b, wts);
  transpose_split<<<dim3(1024 * 512 / 256), dim3(256), 0, stream>>>(w1, w1th, w1tl, 1024, 9);
  transpose_split<<<dim3(512 * 1024 / 256), dim3(256), 0, stream>>>(w2, w2th, w2tl, 512, 10);
  transpose_split<<<dim3(256 * 512 / 256), dim3(256), 0, stream>>>(sem_w, wseh, wsel, 256, 9);
  transpose_split<<<dim3(256 * 512 / 256), dim3(256), 0, stream>>>(
      epi_w, wseh + (size_t)256 * 512, wsel + (size_t)256 * 512, 256, 9);

  for (int c = 0; c < nch; ++c) {
    const int tok0 = c * chunkN;
    hgemm<0, 1><<<dim3(1024 / 128, chunkN / 128), dim3(256), 0, stream>>>(
        seq, embed, nullptr, w1th, nullptr, b1, nullptr,
        nullptr, t1h, nullptr, nullptr, nullptr, 512, 1024, tok0);
    hgemm<1, 1><<<dim3(512 / 128, chunkN / 128), dim3(256), 0, stream>>>(
        seq, embed, t1h, w2th, nullptr, b2, nullptr,
        x, nullptr, nullptr, nullptr, nullptr, 1024, 512, tok0);
    ln_split<<<dim3(chunkN / 4), dim3(256), 0, stream>>>(x, ln_g, ln_b, hh);
    hgemm<2, 2><<<dim3(512 / 128, chunkN / 128), dim3(256), 0, stream>>>(
        seq, embed, hh, wseh, wsel, sem_b, epi_b,
        ssqp, kls, kle, (float*)khs, (float*)khe,
        512, 512, tok0);
  }

  tinv_kernel<<<dim3(2048), dim3(64), 0, stream>>>(
      khs, kls, khe, kle, ssqp, wts, Tgh, Tgl);
  scan_chunked<<<dim3(512), dim3(256), 0, stream>>>(
      khs, kls, khe, kle, ssqp, wts, Tgh, Tgl, cout_);
  out_gemm<<<dim3(kV / 128), dim3(256), 0, stream>>>(cout_, out_w, out_b, out);

  (void)in_sizes; (void)n_in; (void)out_size;
}

// Round 10
// 909.255 us; speedup vs baseline: 1.9578x; 1.0690x over previous
//
#include <hip/hip_runtime.h>
#include <hip/hip_bf16.h>
#include <math.h>

namespace {

constexpr int kH     = 512;
constexpr int kL     = 1024;
constexpr int kB     = 64;
constexpr int kHalf  = 256;
constexpr int kV     = 32000;
constexpr int kTok   = kB * kL;     // 65536

using f32x4 = __attribute__((ext_vector_type(4))) float;
using f16x8 = __attribute__((ext_vector_type(8))) _Float16;

__device__ inline void fsplit(float v, _Float16& h, _Float16& l) {
  h = (_Float16)v;
  l = (_Float16)(v - (float)h);
}

// async 16B global->LDS (gfx950). dst must be wave-uniform base; lane l
// receives bytes [l*16, l*16+16).
typedef __attribute__((address_space(3))) void lds_vp;
typedef const __attribute__((address_space(1))) void glb_vp;
__device__ inline void gload16(const void* g, void* l) {
  __builtin_amdgcn_global_load_lds((glb_vp*)g, (lds_vp*)l, 16, 0, 0);
}

// Row-PAIR swizzled half-tile index for [128][32]-half tiles stored flat.
__device__ inline int hswz(int row, int col) {
  const int sr = row >> 1;
  const int g  = ((row & 1) << 2) | (col >> 3);
  return sr * 64 + (((g ^ (sr & 7)) << 3) | (col & 7));
}

// ---------------- positional weights
__global__ void pos_kernel(const float* __restrict__ pos_emb,
                           const float* __restrict__ pos_w,
                           const float* __restrict__ pos_b,
                           float* __restrict__ wts)
{
  int t = blockIdx.x * blockDim.x + threadIdx.x;
  if (t >= kL) return;
  float z = pos_b[0];
#pragma unroll
  for (int p = 0; p < 16; ++p) z += pos_emb[t * 16 + p] * pos_w[p];
  wts[t] = 1.f / (1.f + expf(-z));
}

// ---------------- transpose + hi/lo fp16 split: W[K][N] fp32 -> Th/Tl[N][K]
__global__ __launch_bounds__(256) void transpose_split(
    const float* __restrict__ W, _Float16* __restrict__ Th,
    _Float16* __restrict__ Tl, int N, int kshift)
{
  const int idx = blockIdx.x * 256 + threadIdx.x;
  const int K = 1 << kshift;
  const int k = idx & (K - 1);
  const int n = idx >> kshift;
  const float w = W[(size_t)k * N + n];
  const _Float16 h = (_Float16)w;
  Th[idx] = h;
  Tl[idx] = (_Float16)(w - (float)h);
}

// ---------------- mixed-precision MFMA GEMM: C = A(fp16) @ B[N,K]^T
// v14: 1D XCD-BANDED grid. Round-robin workgroup->XCD dispatch means the
// decode (xcd=id&7, y'=xcd*(Ny/8)+(id>>3)%(Ny/8), x'=(id>>3)/(Ny/8)) pins
// all Nx tiles of one A-panel (and one token band across ALL chunk kernels)
// to a single XCD -> A-panels and the t1h/x/hh producer->consumer hops
// become L2-hits; the 2-phase window (~310cy MFMA) then covers the load
// latency. v13's mapping re-fetched activations from HBM (900cy) Nx times.
template <int EPI, int PROD>
__global__ __launch_bounds__(256) void hgemm(
    const int* __restrict__ seq, const float* __restrict__ embed,
    const _Float16* __restrict__ Ah,
    const _Float16* __restrict__ Bh, const _Float16* __restrict__ Bl,
    const float* __restrict__ bias, const float* __restrict__ bias2,
    float* __restrict__ Xout, _Float16* __restrict__ Oh, _Float16* __restrict__ Ol,
    float* __restrict__ ks, float* __restrict__ ke,
    int K, int N, int tok0c, int nyb)   // nyb = Ny/8 (token-band rows per XCD)
{
  constexpr int TILES = 1 + PROD;              // A, Bh (, Bl)
  __shared__ __align__(16) _Float16 lds[2 * TILES * 4096];  // dbuf
  const int tid  = threadIdx.x;
  const int lane = tid & 63;
  const int wv   = tid >> 6;
  const int wm   = (wv >> 1) * 64;
  const int wn   = (wv & 1) * 64;
  // XCD-banded decode (bijective for Ny%8==0)
  const int idb  = blockIdx.x;
  const int xcd  = idb & 7;
  const int j    = idb >> 3;
  const int x_   = j / nyb;
  const int yb   = j - x_ * nyb;
  const int bm0  = (xcd * nyb + yb) * 128;
  const int bn0  = x_ * 128;

  f32x4 acc[4][4];
#pragma unroll
  for (int i = 0; i < 4; ++i)
#pragma unroll
    for (int j2 = 0; j2 < 4; ++j2) acc[i][j2] = {0.f, 0.f, 0.f, 0.f};

  // async staging geometry: lane l writes phys 16B granule (super-row l>>3,
  // slot l&7); inverse-swizzled global source:
  const int sl   = lane >> 3;                 // local super-row 0..7
  const int gg   = (lane & 7) ^ sl;           // logical granule
  const int trow = wv * 16 + sl * 2 + (gg >> 2);
  const int tcol = (gg & 3) * 8;              // halves within the 32-half k-step
  const size_t brow0 = (size_t)(bn0 + trow) * K + tcol;
  const size_t brow1 = (size_t)(bn0 + trow + 64) * K + tcol;
  size_t arow0 = 0, arow1 = 0;
  const float* gAe = nullptr;
  if constexpr (EPI == 0) {
    const int sr = tid >> 1;
    const int tokrow = seq[tok0c + bm0 + sr];
    gAe = embed + (size_t)tokrow * kH + ((tid & 1) << 4);
  } else {
    arow0 = (size_t)(bm0 + trow) * K + tcol;
    arow1 = (size_t)(bm0 + trow + 64) * K + tcol;
  }
  // wave-uniform LDS bases (halves)
  const int lb0 = wv * 512;
  const int lb1 = 2048 + wv * 512;

  const int lrow = lane & 15;
  const int lk   = (lane >> 4) * 8;
  const int NT   = K >> 5;

  for (int t = 0; t <= NT; ++t) {
    const int kc = t << 5;
    float4 a0, a1, a2, a3;
    if (t < NT) {                       // issue tile-t loads (latency hides
      if constexpr (EPI == 0) {         //  under tile t-1's compute below)
        a0 = *(const float4*)(gAe + kc);
        a1 = *(const float4*)(gAe + kc + 4);
        a2 = *(const float4*)(gAe + kc + 8);
        a3 = *(const float4*)(gAe + kc + 12);
      }
      const int bo = (t & 1) * TILES * 4096;
      if constexpr (EPI != 0) {
        gload16(Ah + arow0 + kc, &lds[bo + lb0]);
        gload16(Ah + arow1 + kc, &lds[bo + lb1]);
      }
      gload16(Bh + brow0 + kc, &lds[bo + 4096 + lb0]);
      gload16(Bh + brow1 + kc, &lds[bo + 4096 + lb1]);
      if constexpr (PROD == 2) {
        gload16(Bl + brow0 + kc, &lds[bo + 8192 + lb0]);
        gload16(Bl + brow1 + kc, &lds[bo + 8192 + lb1]);
      }
    }
    if (t > 0) {                        // compute tile t-1
      const int po = ((t - 1) & 1) * TILES * 4096;
      f16x8 fBh[4], fBl[4];
#pragma unroll
      for (int ni = 0; ni < 4; ++ni) {
        fBh[ni] = *(const f16x8*)&lds[po + 4096 + hswz(wn + ni * 16 + lrow, lk)];
        if constexpr (PROD == 2)
          fBl[ni] = *(const f16x8*)&lds[po + 8192 + hswz(wn + ni * 16 + lrow, lk)];
      }
#pragma unroll
      for (int mi = 0; mi < 4; ++mi) {
        const f16x8 ah = *(const f16x8*)&lds[po + hswz(wm + mi * 16 + lrow, lk)];
#pragma unroll
        for (int ni = 0; ni < 4; ++ni) {
          acc[mi][ni] = __builtin_amdgcn_mfma_f32_16x16x32_f16(ah, fBh[ni], acc[mi][ni], 0, 0, 0);
          if constexpr (PROD == 2)
            acc[mi][ni] = __builtin_amdgcn_mfma_f32_16x16x32_f16(ah, fBl[ni], acc[mi][ni], 0, 0, 0);
        }
      }
    }
    if (t < NT) {
      if constexpr (EPI == 0) {         // manual A stage (embed gather)
        const float vv[16] = {a0.x,a0.y,a0.z,a0.w, a1.x,a1.y,a1.z,a1.w,
                              a2.x,a2.y,a2.z,a2.w, a3.x,a3.y,a3.z,a3.w};
        union { _Float16 h[16]; uint4 u[2]; } ph;
#pragma unroll
        for (int i = 0; i < 16; ++i) ph.h[i] = (_Float16)vv[i];
        const int sr = tid >> 1;
        const int sc = (tid & 1) << 4;
        const int bo = (t & 1) * TILES * 4096;
        *(uint4*)&lds[bo + hswz(sr, sc)]     = ph.u[0];
        *(uint4*)&lds[bo + hswz(sr, sc + 8)] = ph.u[1];
      }
    }
    __syncthreads();   // drains tile-t vmcnt (hidden under tile t-1 MFMA) + lgkm
  }

  const int erow0 = (lane >> 4) * 4;
  if constexpr (EPI == 0) {
#pragma unroll
    for (int mi = 0; mi < 4; ++mi)
#pragma unroll
      for (int ni = 0; ni < 4; ++ni) {
        const int gn = bn0 + wn + ni * 16 + (lane & 15);
        const float bv = bias[gn];
#pragma unroll
        for (int r = 0; r < 4; ++r) {
          const int gm = bm0 + wm + mi * 16 + erow0 + r;
          float v = fmaxf(acc[mi][ni][r] + bv, 0.f);
          Oh[(size_t)gm * N + gn] = (_Float16)v;
        }
      }
  } else if constexpr (EPI == 1) {
#pragma unroll
    for (int mi = 0; mi < 4; ++mi)
#pragma unroll
      for (int r = 0; r < 4; ++r) {
        const int gm = bm0 + wm + mi * 16 + erow0 + r;
        const int tok = seq[tok0c + gm];
        const float* er = embed + (size_t)tok * kH;
#pragma unroll
        for (int ni = 0; ni < 4; ++ni) {
          const int gn = bn0 + wn + ni * 16 + (lane & 15);
          Xout[(size_t)gm * N + gn] = acc[mi][ni][r] + bias[gn] + er[gn];
        }
      }
  } else {
    // EPI==2: write K as fp16 hi/lo pairs + per-quarter ssq partials (Xout).
    _Float16* kh_s = (_Float16*)ks;
    _Float16* kh_e = (_Float16*)ke;
    float s2[4][4];
#pragma unroll
    for (int mi = 0; mi < 4; ++mi)
#pragma unroll
      for (int r = 0; r < 4; ++r) s2[mi][r] = 0.f;
#pragma unroll
    for (int mi = 0; mi < 4; ++mi)
#pragma unroll
      for (int ni = 0; ni < 4; ++ni) {
        const int gn = bn0 + wn + ni * 16 + (lane & 15);
        const float bv = (gn < 256) ? bias[gn] : bias2[gn - 256];
        _Float16* Dh = (gn < 256) ? kh_s : kh_e;
        _Float16* Dl = (gn < 256) ? Oh : Ol;
        const int col = gn & 255;
#pragma unroll
        for (int r = 0; r < 4; ++r) {
          const int gm = bm0 + wm + mi * 16 + erow0 + r;
          const float v = acc[mi][ni][r] + bv;
          s2[mi][r] += v * v;
          _Float16 h, l;
          fsplit(v, h, l);
          Dh[(size_t)(tok0c + gm) * 256 + col] = h;
          Dl[(size_t)(tok0c + gm) * 256 + col] = l;
        }
      }
    // deterministic per-quarter partial sums: ssqPart[mat][tok][half*2 + (wv&1)]
    const int matq  = bn0 >> 8;
    const int halfq = (bn0 >> 7) & 1;
#pragma unroll
    for (int mi = 0; mi < 4; ++mi)
#pragma unroll
      for (int r = 0; r < 4; ++r) {
        float s2v = s2[mi][r];
        s2v += __shfl_xor(s2v, 1);
        s2v += __shfl_xor(s2v, 2);
        s2v += __shfl_xor(s2v, 4);
        s2v += __shfl_xor(s2v, 8);
        if ((lane & 15) == 0) {
          const int gm = bm0 + wm + mi * 16 + erow0 + r;
          Xout[((size_t)matq * kTok + (size_t)(tok0c + gm)) * 4 + halfq * 2 + (wv & 1)] = s2v;
        }
      }
  }
}

// ---------------- LayerNorm: x fp32 -> fp16 (hi only), XCD-banded tokens
__global__ __launch_bounds__(256) void ln_split(
    const float* __restrict__ x, const float* __restrict__ g,
    const float* __restrict__ bta, _Float16* __restrict__ hh, int tband)
{
  const int wid  = threadIdx.x >> 6;
  const int lane = threadIdx.x & 63;
  // banded decode: same token->XCD mapping as hgemm (tband = chunkN/8)
  const int id   = blockIdx.x;
  const int ltok = (id & 7) * tband + (id >> 3) * 4 + wid;
  const float* xp = x + (size_t)ltok * kH;
  const float4 v0 = *(const float4*)(xp + lane * 8);
  const float4 v1 = *(const float4*)(xp + lane * 8 + 4);
  float s  = v0.x + v0.y + v0.z + v0.w + v1.x + v1.y + v1.z + v1.w;
  float ss = v0.x * v0.x + v0.y * v0.y + v0.z * v0.z + v0.w * v0.w +
             v1.x * v1.x + v1.y * v1.y + v1.z * v1.z + v1.w * v1.w;
#pragma unroll
  for (int m = 1; m < 64; m <<= 1) { s += __shfl_xor(s, m); ss += __shfl_xor(ss, m); }
  const float mu  = s * (1.f / kH);
  const float var = ss * (1.f / kH) - mu * mu;
  const float rs  = 1.f / sqrtf(var + 1e-5f);
  const float4 g0 = *(const float4*)(g + lane * 8);
  const float4 g1 = *(const float4*)(g + lane * 8 + 4);
  const float4 b0 = *(const float4*)(bta + lane * 8);
  const float4 b1 = *(const float4*)(bta + lane * 8 + 4);
  const float vv[8] = {v0.x, v0.y, v0.z, v0.w, v1.x, v1.y, v1.z, v1.w};
  const float gg[8] = {g0.x, g0.y, g0.z, g0.w, g1.x, g1.y, g1.z, g1.w};
  const float bb[8] = {b0.x, b0.y, b0.z, b0.w, b1.x, b1.y, b1.z, b1.w};
  union { _Float16 h[8]; uint4 u; } ph;
#pragma unroll
  for (int i = 0; i < 8; ++i) {
    const float o = (vv[i] - mu) * rs * gg[i] + bb[i];
    ph.h[i] = (_Float16)o;
  }
  *(uint4*)(hh + (size_t)ltok * kH + lane * 8) = ph.u;
}

// ---------------- T precompute: T = (I + diag(aS)*tril_strict(K K^T))^{-1}
__global__ __launch_bounds__(64) void tinv_kernel(
    const _Float16* __restrict__ khs, const _Float16* __restrict__ kls,
    const _Float16* __restrict__ khe, const _Float16* __restrict__ kle,
    const float* __restrict__ ssqP, const float* __restrict__ wts,
    _Float16* __restrict__ Tgh, _Float16* __restrict__ Tgl)
{
  __shared__ float Gs[64][68];
  const int lane = threadIdx.x;
  const int l15  = lane & 15;
  const int quad = lane >> 4;
  const int wg   = blockIdx.x;
  const int ck   = wg & 15;
  const int mat  = (wg >> 4) & 1;
  const int b    = wg >> 5;
  const _Float16* Kh = (mat ? khe : khs) + (size_t)b * (1024 * 256) + (size_t)ck * 64 * 256;
  const _Float16* Kl = (mat ? kle : kls) + (size_t)b * (1024 * 256) + (size_t)ck * 64 * 256;

  const float4 sq = *(const float4*)(ssqP + ((size_t)mat * kTok + (size_t)b * 1024 + ck * 64 + lane) * 4);
  const float w  = mat ? wts[ck * 64 + lane] : 1.f;
  const float aS = w / (sq.x + sq.y + sq.z + sq.w + 1e-6f);

  // G = K K^T via split-fp16 MFMA
  f32x4 D[16];
#pragma unroll
  for (int i = 0; i < 16; ++i) D[i] = {0.f, 0.f, 0.f, 0.f};
#pragma unroll
  for (int kit = 0; kit < 8; ++kit) {
    f16x8 fh[4], fl[4];
#pragma unroll
    for (int mi = 0; mi < 4; ++mi) {
      fh[mi] = *(const f16x8*)(Kh + (size_t)(mi * 16 + l15) * 256 + kit * 32 + quad * 8);
      fl[mi] = *(const f16x8*)(Kl + (size_t)(mi * 16 + l15) * 256 + kit * 32 + quad * 8);
    }
#pragma unroll
    for (int mi = 0; mi < 4; ++mi)
#pragma unroll
      for (int ni = 0; ni < 4; ++ni) {
        f32x4 d = D[mi * 4 + ni];
        d = __builtin_amdgcn_mfma_f32_16x16x32_f16(fh[mi], fh[ni], d, 0, 0, 0);
        d = __builtin_amdgcn_mfma_f32_16x16x32_f16(fh[mi], fl[ni], d, 0, 0, 0);
        d = __builtin_amdgcn_mfma_f32_16x16x32_f16(fl[mi], fh[ni], d, 0, 0, 0);
        D[mi * 4 + ni] = d;
      }
  }
#pragma unroll
  for (int mi = 0; mi < 4; ++mi)
#pragma unroll
    for (int ni = 0; ni < 4; ++ni)
#pragma unroll
      for (int r = 0; r < 4; ++r) {
        const int row = mi * 16 + quad * 4 + r;
        const float as_r = __shfl(aS, row);
        Gs[row][ni * 16 + l15] = as_r * D[mi * 4 + ni][r];
      }
  __syncthreads();

  float x[64];
#pragma unroll
  for (int t = 0; t < 64; ++t) x[t] = (t == lane) ? 1.f : 0.f;
#pragma unroll
  for (int t = 1; t < 64; ++t) {
    float acc = 0.f;
    const int n4 = t >> 2;
#pragma unroll
    for (int q4 = 0; q4 < 16; ++q4) {
      if (q4 >= n4) break;
      const float4 g = *(const float4*)&Gs[t][q4 * 4];
      acc += g.x * x[q4 * 4] + g.y * x[q4 * 4 + 1] + g.z * x[q4 * 4 + 2] + g.w * x[q4 * 4 + 3];
    }
#pragma unroll
    for (int tp = 0; tp < 4; ++tp) {
      const int ti = n4 * 4 + tp;
      if (ti >= t) break;
      acc += Gs[t][ti] * x[ti];
    }
    x[t] -= acc;
  }
  if (ck == 15) x[63] = 0.f;   // token L-1 is the query only: U row 63 = 0

  const size_t base = (size_t)wg * 4096;
#pragma unroll
  for (int t = 0; t < 64; ++t) {
    _Float16 h, l;
    fsplit(x[t], h, l);
    Tgh[base + t * 64 + lane] = h;
    Tgl[base + t * 64 + lane] = l;
  }
}

// ---------------- chunked WY delta-rule scan (v9 structure, unchanged).
struct HTile { _Float16 h[4608], l[4608]; };   // [64][72] halves hi/lo, 18432 B

__global__ __launch_bounds__(256) void scan_chunked(
    const _Float16* __restrict__ khs, const _Float16* __restrict__ kls,
    const _Float16* __restrict__ khe, const _Float16* __restrict__ kle,
    const float* __restrict__ ssqP, const float* __restrict__ wts,
    const _Float16* __restrict__ Tgh, const _Float16* __restrict__ Tgl,
    float* __restrict__ c_out)
{
  __shared__ HTile Sb[2];                                   // S^T dbuf 36864 B
  __shared__ union { HTile t; float cred[4][64]; } Yb;      // Y^T      18432 B
  __shared__ HTile Ub;                                      // U^T      18432 B

  const int tid  = threadIdx.x;
  const int lane = tid & 63;
  const int wv   = tid >> 6;
  const int l15  = lane & 15;
  const int quad = lane >> 4;
  const int wg   = blockIdx.x;
  const int grp  = (wg & 7) + ((wg >> 5) << 3);   // 0..127
  const int q    = (wg >> 3) & 3;
  const int b    = grp >> 1;
  const int mat  = grp & 1;
  const int j0   = q * 64;
  const _Float16* Kh = (mat ? khe : khs) + (size_t)b * (1024 * 256);
  const _Float16* Kl = (mat ? kle : kls) + (size_t)b * (1024 * 256);
  const _Float16* Tbh = Tgh + (size_t)((b * 2 + mat) * 16) * 4096;
  const _Float16* Tbl = Tgl + (size_t)((b * 2 + mat) * 16) * 4096;

  f32x4 S[16];
#pragma unroll
  for (int i = 0; i < 16; ++i) S[i] = {0.f, 0.f, 0.f, 0.f};

  for (int ck = 0; ck < 16; ++ck) {
    const int tok0 = ck * 64;

    float myw[4], mya[4], kvv[4][4];
#pragma unroll
    for (int r = 0; r < 4; ++r) {
      const int t = tok0 + wv * 16 + quad * 4 + r;
      const float4 sq = *(const float4*)(ssqP + ((size_t)mat * kTok + (size_t)b * 1024 + t) * 4);
      const float w = mat ? wts[t] : 1.f;
      myw[r] = w;
      mya[r] = w / (sq.x + sq.y + sq.z + sq.w + 1e-6f);
#pragma unroll
      for (int nt = 0; nt < 4; ++nt) {
        const size_t go = (size_t)t * 256 + j0 + nt * 16 + l15;
        kvv[r][nt] = (float)Kh[go] + (float)Kl[go];
      }
    }
    f16x8 tah[2], tal[2];
#pragma unroll
    for (int kit = 0; kit < 2; ++kit) {
      const size_t to = (size_t)ck * 4096 + (size_t)(wv * 16 + l15) * 64 + kit * 32 + quad * 8;
      tah[kit] = *(const f16x8*)(Tbh + to);
      tal[kit] = *(const f16x8*)(Tbl + to);
    }
    const _Float16* arow_h = Kh + (size_t)(tok0 + wv * 16 + l15) * 256 + quad * 8;
    const _Float16* arow_l = Kl + (size_t)(tok0 + wv * 16 + l15) * 256 + quad * 8;
    f16x8 a0h = *(const f16x8*)(arow_h);
    f16x8 a1h = *(const f16x8*)(arow_h + 32);
    f16x8 a0l = *(const f16x8*)(arow_l);
    f16x8 a1l = *(const f16x8*)(arow_l + 32);

#pragma unroll
    for (int nt = 0; nt < 4; ++nt) {
      const f32x4 v = S[0 * 4 + nt];
      union { _Float16 h[4]; uint2 u; } qh, ql;
#pragma unroll
      for (int r = 0; r < 4; ++r) fsplit(v[r], qh.h[r], ql.h[r]);
      const int ix = (nt * 16 + l15) * 72 + wv * 16 + quad * 4;
      *(uint2*)&Sb[0].h[ix] = qh.u;
      *(uint2*)&Sb[0].l[ix] = ql.u;
    }
    __syncthreads();   // BP0

    f32x4 Qa[4];
#pragma unroll
    for (int i = 0; i < 4; ++i) Qa[i] = {0.f, 0.f, 0.f, 0.f};
#pragma unroll
    for (int p = 0; p < 4; ++p) {
      const int cur = p & 1;
      f16x8 n0h, n1h, n0l, n1l;
      if (p < 3) {
        n0h = *(const f16x8*)(arow_h + (p + 1) * 64);
        n1h = *(const f16x8*)(arow_h + (p + 1) * 64 + 32);
        n0l = *(const f16x8*)(arow_l + (p + 1) * 64);
        n1l = *(const f16x8*)(arow_l + (p + 1) * 64 + 32);
#pragma unroll
        for (int nt = 0; nt < 4; ++nt) {
          const f32x4 v = S[(p + 1) * 4 + nt];
          union { _Float16 h[4]; uint2 u; } sh2, sl2;
#pragma unroll
          for (int r = 0; r < 4; ++r) fsplit(v[r], sh2.h[r], sl2.h[r]);
          const int ix = (nt * 16 + l15) * 72 + wv * 16 + quad * 4;
          *(uint2*)&Sb[1 - cur].h[ix] = sh2.u;
          *(uint2*)&Sb[1 - cur].l[ix] = sl2.u;
        }
      }
#pragma unroll
      for (int kit = 0; kit < 2; ++kit) {
        const f16x8 ah = kit ? a1h : a0h;
        const f16x8 al = kit ? a1l : a0l;
#pragma unroll
        for (int nt = 0; nt < 4; ++nt) {
          const int ix = (nt * 16 + l15) * 72 + kit * 32 + quad * 8;
          const f16x8 bh = *(const f16x8*)&Sb[cur].h[ix];
          const f16x8 bl = *(const f16x8*)&Sb[cur].l[ix];
          Qa[nt] = __builtin_amdgcn_mfma_f32_16x16x32_f16(ah, bh, Qa[nt], 0, 0, 0);
          Qa[nt] = __builtin_amdgcn_mfma_f32_16x16x32_f16(ah, bl, Qa[nt], 0, 0, 0);
          Qa[nt] = __builtin_amdgcn_mfma_f32_16x16x32_f16(al, bh, Qa[nt], 0, 0, 0);
        }
      }
      if (p < 3) { a0h = n0h; a1h = n1h; a0l = n0l; a1l = n1l; }
      __syncthreads();   // end of panel p
    }

#pragma unroll
    for (int nt = 0; nt < 4; ++nt) {
      union { _Float16 h[4]; uint2 u; } yh, yl;
#pragma unroll
      for (int r = 0; r < 4; ++r) {
        const float y = myw[r] * kvv[r][nt] - mya[r] * Qa[nt][r];
        fsplit(y, yh.h[r], yl.h[r]);
      }
      const int ix = (nt * 16 + l15) * 72 + wv * 16 + quad * 4;
      *(uint2*)&Yb.t.h[ix] = yh.u;
      *(uint2*)&Yb.t.l[ix] = yl.u;
    }
    __syncthreads();   // BY

    f32x4 Ua[4];
#pragma unroll
    for (int i = 0; i < 4; ++i) Ua[i] = {0.f, 0.f, 0.f, 0.f};
#pragma unroll
    for (int kit = 0; kit < 2; ++kit)
#pragma unroll
      for (int nt = 0; nt < 4; ++nt) {
        const int ix = (nt * 16 + l15) * 72 + kit * 32 + quad * 8;
        const f16x8 yh = *(const f16x8*)&Yb.t.h[ix];
        const f16x8 yl = *(const f16x8*)&Yb.t.l[ix];
        Ua[nt] = __builtin_amdgcn_mfma_f32_16x16x32_f16(tah[kit], yh, Ua[nt], 0, 0, 0);
        Ua[nt] = __builtin_amdgcn_mfma_f32_16x16x32_f16(tah[kit], yl, Ua[nt], 0, 0, 0);
        Ua[nt] = __builtin_amdgcn_mfma_f32_16x16x32_f16(tal[kit], yh, Ua[nt], 0, 0, 0);
      }
#pragma unroll
    for (int nt = 0; nt < 4; ++nt) {
      union { _Float16 h[4]; uint2 u; } uh, ul;
#pragma unroll
      for (int r = 0; r < 4; ++r) fsplit(Ua[nt][r], uh.h[r], ul.h[r]);
      const int ix = (nt * 16 + l15) * 72 + wv * 16 + quad * 4;
      *(uint2*)&Ub.h[ix] = uh.u;
      *(uint2*)&Ub.l[ix] = ul.u;
    }
    __syncthreads();   // BU

#pragma unroll
    for (int p = 0; p < 4; ++p) {
      union { _Float16 e[8]; f16x8 v; } kah[2], kal[2];
#pragma unroll
      for (int kit = 0; kit < 2; ++kit)
#pragma unroll
        for (int jj = 0; jj < 8; ++jj) {
          const size_t gko = (size_t)(tok0 + kit * 32 + quad * 8 + jj) * 256
                           + p * 64 + wv * 16 + l15;
          kah[kit].e[jj] = Kh[gko];
          kal[kit].e[jj] = Kl[gko];
        }
#pragma unroll
      for (int kit = 0; kit < 2; ++kit)
#pragma unroll
        for (int nt = 0; nt < 4; ++nt) {
          const int ix = (nt * 16 + l15) * 72 + kit * 32 + quad * 8;
          const f16x8 ubh = *(const f16x8*)&Ub.h[ix];
          const f16x8 ubl = *(const f16x8*)&Ub.l[ix];
          f32x4 s = S[p * 4 + nt];
          s = __builtin_amdgcn_mfma_f32_16x16x32_f16(kah[kit].v, ubh, s, 0, 0, 0);
          s = __builtin_amdgcn_mfma_f32_16x16x32_f16(kah[kit].v, ubl, s, 0, 0, 0);
          s = __builtin_amdgcn_mfma_f32_16x16x32_f16(kal[kit].v, ubh, s, 0, 0, 0);
          S[p * 4 + nt] = s;
        }
    }
  }

  float part[4] = {0.f, 0.f, 0.f, 0.f};
  const size_t lastoff = (size_t)(kL - 1) * 256;
#pragma unroll
  for (int p = 0; p < 4; ++p) {
    float klr[4];
#pragma unroll
    for (int r = 0; r < 4; ++r) {
      const int row = p * 64 + wv * 16 + quad * 4 + r;
      klr[r] = (float)Kh[lastoff + row] + (float)Kl[lastoff + row];
    }
#pragma unroll
    for (int nt = 0; nt < 4; ++nt)
#pragma unroll
      for (int r = 0; r < 4; ++r) part[nt] += S[p * 4 + nt][r] * klr[r];
  }
#pragma unroll
  for (int nt = 0; nt < 4; ++nt) {
    part[nt] += __shfl_xor(part[nt], 16);
    part[nt] += __shfl_xor(part[nt], 32);
  }
  __syncthreads();
  if (lane < 16) {
#pragma unroll
    for (int nt = 0; nt < 4; ++nt) Yb.cred[wv][nt * 16 + l15] = part[nt];
  }
  __syncthreads();
  if (tid < 64) {
    const float c = Yb.cred[0][tid] + Yb.cred[1][tid] + Yb.cred[2][tid] + Yb.cred[3][tid];
    c_out[(size_t)b * 512 + mat * 256 + j0 + tid] = c;
  }
}

// ---------------- output GEMM: (64 x 512) @ (512 x 32000) + out_b -> fp32
__global__ __launch_bounds__(256) void out_gemm(
    const float* __restrict__ A, const float* __restrict__ Bm,
    const float* __restrict__ bias, float* __restrict__ C)
{
  __shared__ float As[16][64];
  __shared__ float Bs[16][128];
  const int tid = threadIdx.x;
  const int bn0 = blockIdx.x * 128;
  const int tm = tid >> 4, tn = tid & 15;
  float acc[4][8];
#pragma unroll
  for (int i = 0; i < 4; ++i)
#pragma unroll
    for (int j = 0; j < 8; ++j) acc[i][j] = 0.f;

  const int am  = tid & 63;
  const int ak  = (tid >> 6) * 4;
  const int bkr = tid >> 5;
  const int bcg = (tid & 31) * 4;

  for (int k0 = 0; k0 < kH; k0 += 16) {
    const float4 a0 = *(const float4*)(A + (size_t)am * kH + k0 + ak);
    const float4 b0 = *(const float4*)(Bm + (size_t)(k0 + bkr) * kV + bn0 + bcg);
    const float4 b1 = *(const float4*)(Bm + (size_t)(k0 + bkr + 8) * kV + bn0 + bcg);
    __syncthreads();
    As[ak + 0][am] = a0.x; As[ak + 1][am] = a0.y;
    As[ak + 2][am] = a0.z; As[ak + 3][am] = a0.w;
    *(float4*)&Bs[bkr][bcg]     = b0;
    *(float4*)&Bs[bkr + 8][bcg] = b1;
    __syncthreads();
#pragma unroll
    for (int kk = 0; kk < 16; ++kk) {
      const float4 aA = *(const float4*)&As[kk][tm * 4];
      const float4 bA = *(const float4*)&Bs[kk][tn * 4];
      const float4 bB = *(const float4*)&Bs[kk][64 + tn * 4];
      const float av[4] = {aA.x, aA.y, aA.z, aA.w};
      const float bv[8] = {bA.x, bA.y, bA.z, bA.w, bB.x, bB.y, bB.z, bB.w};
#pragma unroll
      for (int i = 0; i < 4; ++i)
#pragma unroll
        for (int j = 0; j < 8; ++j) acc[i][j] += av[i] * bv[j];
    }
  }

#pragma unroll
  for (int i = 0; i < 4; ++i) {
    const int row = tm * 4 + i;
#pragma unroll
    for (int hh = 0; hh < 2; ++hh) {
      const int n0 = bn0 + tn * 4 + hh * 64;
      const float4 bb = *(const float4*)(bias + n0);
      float4 o;
      o.x = acc[i][hh * 4 + 0] + bb.x;
      o.y = acc[i][hh * 4 + 1] + bb.y;
      o.z = acc[i][hh * 4 + 2] + bb.z;
      o.w = acc[i][hh * 4 + 3] + bb.w;
      *(float4*)(C + (size_t)row * kV + n0) = o;
    }
  }
}

}  // namespace

extern "C" void kernel_launch(void* const* d_in, const int* in_sizes, int n_in,
                              void* d_out, int out_size, void* d_ws, size_t ws_size,
                              hipStream_t stream)
{
  const int*   seq     = (const int*)  d_in[0];
  const float* embed   = (const float*)d_in[1];
  const float* w1      = (const float*)d_in[2];
  const float* b1      = (const float*)d_in[3];
  const float* w2      = (const float*)d_in[4];
  const float* b2      = (const float*)d_in[5];
  const float* ln_g    = (const float*)d_in[6];
  const float* ln_b    = (const float*)d_in[7];
  const float* sem_w   = (const float*)d_in[8];
  const float* sem_b   = (const float*)d_in[9];
  const float* epi_w   = (const float*)d_in[10];
  const float* epi_b   = (const float*)d_in[11];
  const float* out_w   = (const float*)d_in[12];
  const float* out_b   = (const float*)d_in[13];
  const float* pos_emb = (const float*)d_in[14];
  const float* pos_w   = (const float*)d_in[15];
  const float* pos_b   = (const float*)d_in[16];
  float* out = (float*)d_out;

  const int chunkN = (ws_size >= (size_t)240500000) ? 16384 : 8192;
  const int nch    = kTok / chunkN;
  const int nyb    = chunkN / 1024;   // Ny/8 = (chunkN/128)/8
  const int tband  = chunkN / 8;

  char* p = (char*)d_ws;
  _Float16* w1th = (_Float16*)p; p += (size_t)1024 * 512 * 2;
  _Float16* w1tl = (_Float16*)p; p += (size_t)1024 * 512 * 2;   // unused (PROD=1)
  _Float16* w2th = (_Float16*)p; p += (size_t)512 * 1024 * 2;
  _Float16* w2tl = (_Float16*)p; p += (size_t)512 * 1024 * 2;   // unused (PROD=1)
  _Float16* wseh = (_Float16*)p; p += (size_t)512 * 512 * 2;
  _Float16* wsel = (_Float16*)p; p += (size_t)512 * 512 * 2;
  _Float16* t1h  = (_Float16*)p; p += (size_t)chunkN * 1024 * 2;
  _Float16* t1l  = (_Float16*)p; p += (size_t)chunkN * 1024 * 2;   // (spare; T-lo alias)
  float*    x    = (float*)p;    p += (size_t)chunkN * kH * 4;
  _Float16* khs  = (_Float16*)p; p += (size_t)kTok * kHalf * 2;   // K hi/lo fp16
  _Float16* kls  = (_Float16*)p; p += (size_t)kTok * kHalf * 2;
  _Float16* khe  = (_Float16*)p; p += (size_t)kTok * kHalf * 2;
  _Float16* kle  = (_Float16*)p; p += (size_t)kTok * kHalf * 2;
  float*    wts  = (float*)p;    p += (size_t)kL * 4;
  float*    cout_= (float*)p;    p += (size_t)kB * 512 * 4;
  float*    ssqp = (float*)p;    p += (size_t)2 * kTok * 4 * 4;   // [mat][tok][4] partials
  _Float16* hh   = t1h;          // alias: t1 dead once x is written
  _Float16* Tgh = t1h;           // T aliases t1 (dead after chunk loop)
  _Float16* Tgl = t1l;

  pos_kernel<<<dim3((kL + 255) / 256), dim3(256), 0, stream>>>(pos_emb, pos_w, pos_b, wts);
  transpose_split<<<dim3(1024 * 512 / 256), dim3(256), 0, stream>>>(w1, w1th, w1tl, 1024, 9);
  transpose_split<<<dim3(512 * 1024 / 256), dim3(256), 0, stream>>>(w2, w2th, w2tl, 512, 10);
  transpose_split<<<dim3(256 * 512 / 256), dim3(256), 0, stream>>>(sem_w, wseh, wsel, 256, 9);
  transpose_split<<<dim3(256 * 512 / 256), dim3(256), 0, stream>>>(
      epi_w, wseh + (size_t)256 * 512, wsel + (size_t)256 * 512, 256, 9);

  for (int c = 0; c < nch; ++c) {
    const int tok0 = c * chunkN;
    hgemm<0, 1><<<dim3((1024 / 128) * (chunkN / 128)), dim3(256), 0, stream>>>(
        seq, embed, nullptr, w1th, nullptr, b1, nullptr,
        nullptr, t1h, nullptr, nullptr, nullptr, 512, 1024, tok0, nyb);
    hgemm<1, 1><<<dim3((512 / 128) * (chunkN / 128)), dim3(256), 0, stream>>>(
        seq, embed, t1h, w2th, nullptr, b2, nullptr,
        x, nullptr, nullptr, nullptr, nullptr, 1024, 512, tok0, nyb);
    ln_split<<<dim3(chunkN / 4), dim3(256), 0, stream>>>(x, ln_g, ln_b, hh, tband);
    hgemm<2, 2><<<dim3((512 / 128) * (chunkN / 128)), dim3(256), 0, stream>>>(
        seq, embed, hh, wseh, wsel, sem_b, epi_b,
        ssqp, kls, kle, (float*)khs, (float*)khe,
        512, 512, tok0, nyb);
  }

  tinv_kernel<<<dim3(2048), dim3(64), 0, stream>>>(
      khs, kls, khe, kle, ssqp, wts, Tgh, Tgl);
  scan_chunked<<<dim3(512), dim3(256), 0, stream>>>(
      khs, kls, khe, kle, ssqp, wts, Tgh, Tgl, cout_);
  out_gemm<<<dim3(kV / 128), dim3(256), 0, stream>>>(cout_, out_w, out_b, out);

  (void)in_sizes; (void)n_in; (void)out_size;
}